// Round 7
// baseline (627.165 us; speedup 1.0000x reference)
//
#include <hip/hip_runtime.h>
#include <math.h>

#define NEG 0.01f
__device__ __forceinline__ float lrelu(float v){ return v > 0.f ? v : NEG*v; }
__device__ __forceinline__ float frelu(float v){ return v > 0.f ? v : 0.f; }

typedef __attribute__((ext_vector_type(8))) short bf16x8;
typedef __attribute__((ext_vector_type(4))) float f32x4;

__device__ __forceinline__ unsigned short f2bf(float x){
    unsigned int u = __float_as_uint(x);
    unsigned int r = (u + 0x7FFFu + ((u>>16)&1u)) >> 16;
    return (unsigned short)r;
}
__device__ __forceinline__ float bf2f(unsigned short h){
    return __uint_as_float(((unsigned int)h) << 16);
}

// ============ K0: weight repack (frag-ready layouts, bf16) ============
__global__ __launch_bounds__(256) void k_prep(const float* __restrict__ w2, const float* __restrict__ w3,
    const float* __restrict__ m2w,
    unsigned short* __restrict__ w2s, unsigned short* __restrict__ w3s, unsigned short* __restrict__ m2wbT)
{
    int gid = blockIdx.x*256 + threadIdx.x;
    if (gid < 73728) {
        int j = gid / 576, f = gid % 576;
        m2wbT[gid] = f2bf(m2w[f*128 + j]);
    }
    if (gid < 65536) {
        int jj = gid & 7, q = (gid>>3)&3, o = (gid>>5)&127, ks = (gid>>12)&1, k = gid>>13;
        int c = ks*32 + q*8 + jj;
        w2s[gid] = f2bf(w2[o*512 + c*8 + k]);
    }
    if (gid < 32768) {
        int jj = gid & 7, q = (gid>>3)&3, o = (gid>>5)&31, ks = (gid>>10)&3, k = gid>>12;
        int c = ks*32 + q*8 + jj;
        w3s[gid] = f2bf(w3[o*1024 + c*8 + k]);
    }
}

// ============ K1: fused conv stack, MFMA conv2/conv3, sliding-window conv1 ============
__global__ __launch_bounds__(256) void k_conv(
    const float* __restrict__ xenc,
    const float* __restrict__ w1, const float* __restrict__ g1, const float* __restrict__ b1,
    const unsigned short* __restrict__ w2s, const float* __restrict__ g2, const float* __restrict__ b2,
    const unsigned short* __restrict__ w3s, const float* __restrict__ g3, const float* __restrict__ b3,
    unsigned short* __restrict__ aflatG)
{
    __shared__ __align__(16) unsigned char smraw[38464];
    float* sigp = (float*)smraw;                            // [144] (zero-padded)
    unsigned short* p1T = (unsigned short*)(smraw + 576);
    unsigned short* p2T = (unsigned short*)(smraw + 10304);
    unsigned short* c2o = (unsigned short*)(smraw + 21056);
    float* c3o = (float*)(smraw + 21056);

    const int t = threadIdx.x;
    const int s = blockIdx.x;

    {
        unsigned int* zz = (unsigned int*)(smraw + 576);
        for (int i = t; i < 5120; i += 256) zz[i] = 0u;
        if (t < 144) sigp[t] = 0.f;
    }
    __syncthreads();
    if (t < 128) sigp[4 + t] = xenc[(size_t)s*128 + t];
    __syncthreads();

    {   // conv1 f32 (sliding window) + bn + relu + pool -> p1T (bf16, swizzled)
        const int c = t & 63, qg = t >> 6;
        float wr[8];
        #pragma unroll
        for (int k = 0; k < 8; ++k) wr[k] = w1[c*8 + k];
        const float g = g1[c], b = b1[c];
        const int qs = qg*17;                 // 0,17,34,51
        float win[9];                         // win[x] = sigp[2q-1+x]
        {
            int base = 2*qs - 1;
            #pragma unroll
            for (int x = 0; x < 9; ++x) win[x] = (base + x >= 0) ? sigp[base + x] : 0.f;
        }
        #pragma unroll
        for (int j = 0; j < 17; ++j) {
            int q = qs + j;
            float s0 = 0.f, s1 = 0.f;
            #pragma unroll
            for (int k = 0; k < 8; ++k) { s0 += win[k]*wr[k]; s1 += win[k+1]*wr[k]; }
            float v = frelu(s1*g + b);
            if (q > 0) v = fmaxf(v, frelu(s0*g + b));
            if (q < 65) {
                int row = q + 4;
                p1T[row*64 + (((c>>3) ^ (row&7))<<3) + (c&7)] = f2bf(v);
            }
            #pragma unroll
            for (int x = 0; x < 7; ++x) win[x] = win[x+2];
            win[7] = sigp[2*q + 8];
            win[8] = sigp[2*q + 9];
        }
    }
    __syncthreads();

    {   // conv2 MFMA (validated r2)
        const int wv = t >> 6, l = t & 63, lg = l >> 4, lr = l & 15;
        f32x4 acc[2][5] = {};
        for (int k = 0; k < 8; ++k) {
            for (int ks = 0; ks < 2; ++ks) {
                bf16x8 af[2];
                #pragma unroll
                for (int oi = 0; oi < 2; ++oi) {
                    int o = (wv*2 + oi)*16 + lr;
                    af[oi] = *(const bf16x8*)(w2s + ((((k*2 + ks)*128 + o)*4 + lg)<<3));
                }
                #pragma unroll
                for (int nt = 0; nt < 5; ++nt) {
                    int row = nt*16 + lr + k; row = row > 75 ? 75 : row;
                    int q = ks*4 + lg;
                    bf16x8 bfv = *(const bf16x8*)(p1T + row*64 + ((q ^ (row&7))<<3));
                    acc[0][nt] = __builtin_amdgcn_mfma_f32_16x16x32_bf16(af[0], bfv, acc[0][nt], 0,0,0);
                    acc[1][nt] = __builtin_amdgcn_mfma_f32_16x16x32_bf16(af[1], bfv, acc[1][nt], 0,0,0);
                }
            }
        }
        #pragma unroll
        for (int oi = 0; oi < 2; ++oi)
            #pragma unroll
            for (int nt = 0; nt < 5; ++nt)
                #pragma unroll
                for (int r = 0; r < 4; ++r) {
                    int o = (wv*2 + oi)*16 + lg*4 + r;
                    int p = nt*16 + lr;
                    if (p < 66) c2o[o*68 + p] = f2bf(frelu(acc[oi][nt][r] * g2[o] + b2[o]));
                }
    }
    __syncthreads();

    for (int idx = t; idx < 4352; idx += 256) {   // pool2
        int o = idx & 127, q = idx >> 7;
        unsigned short v = (q <= 32) ? c2o[o*68 + 2*q] : (unsigned short)0;
        if (q > 0) { unsigned short v2 = c2o[o*68 + 2*q - 1]; v = (v2 > v) ? v2 : v; }
        int row = q + 4;
        p2T[row*128 + (((o>>3) ^ (row&15))<<3) + (o&7)] = v;
    }
    __syncthreads();

    {   // conv3 MFMA (validated r2)
        const int wv = t >> 6, l = t & 63, lg = l >> 4, lr = l & 15;
        const int ot = wv & 1, ntb = (wv >> 1) * 2;
        const int ncnt = (wv < 2) ? 2 : 1;
        f32x4 acc[2] = {};
        for (int k = 0; k < 8; ++k) {
            for (int ks = 0; ks < 4; ++ks) {
                int o = ot*16 + lr;
                bf16x8 af = *(const bf16x8*)(w3s + ((((k*4 + ks)*32 + o)*4 + lg)<<3));
                int q = ks*4 + lg;
                #pragma unroll
                for (int ni = 0; ni < 2; ++ni) {
                    if (ni < ncnt) {
                        int row = (ntb + ni)*16 + lr + k; row = row > 41 ? 41 : row;
                        bf16x8 bfv = *(const bf16x8*)(p2T + row*128 + ((q ^ (row&15))<<3));
                        acc[ni] = __builtin_amdgcn_mfma_f32_16x16x32_bf16(af, bfv, acc[ni], 0,0,0);
                    }
                }
            }
        }
        #pragma unroll
        for (int ni = 0; ni < 2; ++ni) if (ni < ncnt)
            #pragma unroll
            for (int r = 0; r < 4; ++r) {
                int o = ot*16 + lg*4 + r;
                int p = (ntb + ni)*16 + lr;
                if (p < 35) c3o[o*36 + p] = frelu(acc[ni][r] * g3[o] + b3[o]);
            }
    }
    __syncthreads();

    for (int idx = t; idx < 576; idx += 256) {   // pool3 -> global
        int o = idx / 18, q = idx % 18;
        float v = c3o[o*36 + 2*q];
        if (q > 0) v = fmaxf(v, c3o[o*36 + 2*q - 1]);
        aflatG[(size_t)s*576 + idx] = f2bf(v);
    }
}

// ============ K1b: map2 GEMM (validated r2) ============
__global__ __launch_bounds__(256) void k_map2(const unsigned short* __restrict__ aflatG,
    const unsigned short* __restrict__ m2wbT,
    const float* __restrict__ m2b, const float* __restrict__ m2g, const float* __restrict__ m2bb,
    float* __restrict__ a2)
{
    const int t = threadIdx.x, wv = t>>6, l = t&63, lg = l>>4, lr = l&15;
    const int s0 = blockIdx.x*64;
    f32x4 acc[8] = {};
    for (int ks = 0; ks < 18; ++ks) {
        bf16x8 a = *(const bf16x8*)(aflatG + (size_t)(s0 + wv*16 + lr)*576 + ks*32 + lg*8);
        #pragma unroll
        for (int nt = 0; nt < 8; ++nt) {
            bf16x8 b = *(const bf16x8*)(m2wbT + (size_t)(nt*16 + lr)*576 + ks*32 + lg*8);
            acc[nt] = __builtin_amdgcn_mfma_f32_16x16x32_bf16(a, b, acc[nt], 0,0,0);
        }
    }
    #pragma unroll
    for (int nt = 0; nt < 8; ++nt)
        #pragma unroll
        for (int r = 0; r < 4; ++r) {
            int s2 = s0 + wv*16 + lg*4 + r;
            int j = nt*16 + lr;
            a2[(size_t)s2*128 + j] = (acc[nt][r] + m2b[j]) * m2g[j] + m2bb[j];
        }
}

// ===== K2: build X + PE (f64 table + range-reduce + HW f32 trig) =====
__global__ __launch_bounds__(256) void k_buildx(const float* __restrict__ a2, float* __restrict__ X)
{
    __shared__ double dvt[64];
    const int t = threadIdx.x;
    if (t < 64) dvt[t] = exp((double)(2*t) * (-9.210340371976184/128.0));  // ln(1e4)
    __syncthreads();
    int e = blockIdx.x*256 + t;
    int b = e >> 17;
    int r = e & 131071;
    int i = r >> 7, d = r & 127;
    int row = b*1024 + (d & 7)*128 + (i >> 3);
    int col = (i & 7)*16 + (d >> 3);
    float v = a2[row*128 + col];
    int per = b*1024 + (i & 7)*128 + d;
    int pc  = i >> 3;
    double ang = (double)per * dvt[pc >> 1];
    const double TWO_PI = 6.283185307179586476925287;
    double kk = floor(ang * (1.0/TWO_PI) + 0.5);
    float red = (float)(ang - kk * TWO_PI);        // in [-pi, pi]
    float pe = (pc & 1) ? __cosf(red) : __sinf(red);
    X[e] = v + pe;
}

// ===== K3: H = X @ gw + gb (f32, both branches) -> bf16 hi/lo =====
__global__ __launch_bounds__(256) void k_hmat(const float* __restrict__ X,
    const float* __restrict__ g1w, const float* __restrict__ g1b,
    const float* __restrict__ g2w, const float* __restrict__ g2b,
    unsigned short* __restrict__ Hbhi1, unsigned short* __restrict__ Hblo1,
    unsigned short* __restrict__ Hbhi2, unsigned short* __restrict__ Hblo2)
{
    const int br = blockIdx.y;
    const float* gw = br ? g2w : g1w;
    const float* gb = br ? g2b : g1b;
    unsigned short* Hh = br ? Hbhi2 : Hbhi1;
    unsigned short* Hl = br ? Hblo2 : Hblo1;
    int e = blockIdx.x*256 + threadIdx.x;
    int srow = e >> 7, j = e & 127;
    const float* xr = X + (size_t)srow*128;
    float acc = gb[j];
    for (int k = 0; k < 128; ++k) acc += xr[k] * gw[k*128 + j];
    unsigned short hh = f2bf(acc);
    Hh[e] = hh;
    Hl[e] = f2bf(acc - bf2f(hh));
}

// ===== K4: S = lrelu(H H^T - 1e8*I) via bf16 hi/lo MFMA (validated r6) =====
__global__ __launch_bounds__(256) void k_scores(
    const unsigned short* __restrict__ Hbhi, const unsigned short* __restrict__ Hblo,
    float* __restrict__ S)
{
    __shared__ __align__(16) unsigned short HiH[64*64];
    __shared__ __align__(16) unsigned short HiL[64*64];
    __shared__ __align__(16) unsigned short HjH[64*64];
    __shared__ __align__(16) unsigned short HjL[64*64];
    const int b = blockIdx.z;
    const int i0 = blockIdx.y * 64, j0 = blockIdx.x * 64;
    const int t = threadIdx.x;
    const int w = t >> 6, l = t & 63, lr = l & 15, h = l >> 4;
    const size_t hb = (size_t)b * 1024 * 128;

    f32x4 acc[4] = {};
    for (int kh = 0; kh < 2; ++kh) {
        __syncthreads();
        #pragma unroll
        for (int it = 0; it < 4; ++it) {
            int g = it*256 + t;
            int mat = g >> 9;
            int gg = g & 511;
            int row = gg >> 3, ch = gg & 7;
            int base0 = mat ? j0 : i0;
            size_t src = hb + (size_t)(base0 + row)*128 + kh*64 + ch*8;
            uint4 vh = *(const uint4*)(Hbhi + src);
            uint4 vl = *(const uint4*)(Hblo + src);
            int sw = ch ^ (row & 7);
            unsigned short* dh = (mat ? HjH : HiH) + row*64 + sw*8;
            unsigned short* dl = (mat ? HjL : HiL) + row*64 + sw*8;
            *(uint4*)dh = vh;
            *(uint4*)dl = vl;
        }
        __syncthreads();
        #pragma unroll
        for (int kc = 0; kc < 2; ++kc) {
            int swA = (((kc*4 + h) ^ (lr & 7)) << 3);
            bf16x8 ah = *(const bf16x8*)&HiH[(w*16 + lr)*64 + swA];
            bf16x8 al = *(const bf16x8*)&HiL[(w*16 + lr)*64 + swA];
            #pragma unroll
            for (int jt = 0; jt < 4; ++jt) {
                bf16x8 bh = *(const bf16x8*)&HjH[(jt*16 + lr)*64 + swA];
                bf16x8 bl = *(const bf16x8*)&HjL[(jt*16 + lr)*64 + swA];
                acc[jt] = __builtin_amdgcn_mfma_f32_16x16x32_bf16(ah, bh, acc[jt], 0,0,0);
                acc[jt] = __builtin_amdgcn_mfma_f32_16x16x32_bf16(ah, bl, acc[jt], 0,0,0);
                acc[jt] = __builtin_amdgcn_mfma_f32_16x16x32_bf16(al, bh, acc[jt], 0,0,0);
            }
        }
    }
    float* Sb = S + (size_t)b*1024*1024;
    #pragma unroll
    for (int jt = 0; jt < 4; ++jt) {
        #pragma unroll
        for (int r = 0; r < 4; ++r) {
            int i = i0 + w*16 + h*4 + r;
            int j = j0 + jt*16 + lr;
            float x = acc[jt][r];
            if (i == j) x -= 1e8f;
            Sb[(size_t)i*1024 + j] = lrelu(x);
        }
    }
}

// ===== K6: fused softmax + P = (softmax(S)+I) @ (X*bng+bnb) =====
__global__ __launch_bounds__(256) void k_pvsm(const float* __restrict__ S, const float* __restrict__ X,
                                              const float* __restrict__ bng, const float* __restrict__ bnb,
                                              float* __restrict__ P)
{
    __shared__ __align__(16) float Sl[16*65];
    __shared__ __align__(16) float Xl[64*132];
    __shared__ float mrow[16], linv[16];
    const int b = blockIdx.y, i0 = blockIdx.x*16, t = threadIdx.x;
    const float* Sb = S + (size_t)b*1024*1024;
    const float* Xb = X + (size_t)b*1024*128;

    {   // phase 1: per-row max and exp-sum (row held in 64 VGPRs)
        int r = t >> 4;
        int seg = t & 15;
        const float* row = Sb + (size_t)(i0 + r)*1024;
        float4 v[16];
        float mx = -3.0e38f;
        #pragma unroll
        for (int i = 0; i < 16; ++i) {
            v[i] = *(const float4*)&row[i*64 + seg*4];
            mx = fmaxf(mx, fmaxf(fmaxf(v[i].x, v[i].y), fmaxf(v[i].z, v[i].w)));
        }
        mx = fmaxf(mx, __shfl_xor(mx, 1));
        mx = fmaxf(mx, __shfl_xor(mx, 2));
        mx = fmaxf(mx, __shfl_xor(mx, 4));
        mx = fmaxf(mx, __shfl_xor(mx, 8));
        float sum = 0.f;
        #pragma unroll
        for (int i = 0; i < 16; ++i)
            sum += (__expf(v[i].x - mx) + __expf(v[i].y - mx))
                 + (__expf(v[i].z - mx) + __expf(v[i].w - mx));
        sum += __shfl_xor(sum, 1);
        sum += __shfl_xor(sum, 2);
        sum += __shfl_xor(sum, 4);
        sum += __shfl_xor(sum, 8);
        if (seg == 0) { mrow[r] = mx; linv[r] = 1.f / sum; }
    }

    const int il = t >> 4, dg = t & 15;
    const int sj = t & 63, sil = t >> 6;
    const int xd = t & 127, xj = t >> 7;
    const float bg = bng[xd], bb = bnb[xd];
    float acc[8] = {};
    for (int c = 0; c < 16; ++c) {
        int jb = c*64;
        __syncthreads();   // also separates phase-1 mrow/linv writes
        #pragma unroll
        for (int m2 = 0; m2 < 4; ++m2) {
            int r2 = sil*4 + m2;
            Sl[r2*65 + sj] = __expf(Sb[(size_t)(i0+r2)*1024 + jb + sj] - mrow[r2]);
        }
        #pragma unroll
        for (int m2 = 0; m2 < 32; ++m2) {
            int jc = xj + 2*m2;
            Xl[jc*132 + xd] = Xb[(size_t)(jb+jc)*128 + xd] * bg + bb;
        }
        __syncthreads();
        for (int jc = 0; jc < 64; ++jc) {
            float sv = Sl[il*65 + jc];
            float4 x0 = *(const float4*)&Xl[jc*132 + dg*8];
            float4 x1 = *(const float4*)&Xl[jc*132 + dg*8 + 4];
            acc[0] += sv*x0.x; acc[1] += sv*x0.y; acc[2] += sv*x0.z; acc[3] += sv*x0.w;
            acc[4] += sv*x1.x; acc[5] += sv*x1.y; acc[6] += sv*x1.z; acc[7] += sv*x1.w;
        }
    }
    int i = i0 + il;
    float inv = linv[il];
    const float* xr = Xb + (size_t)i*128 + dg*8;
    float* pr = P + (size_t)(b*1024 + i)*128 + dg*8;
    #pragma unroll
    for (int z = 0; z < 8; ++z) {
        float xv = xr[z] * bng[dg*8+z] + bnb[dg*8+z];
        pr[z] = acc[z]*inv + xv;
    }
}

// ================= K7: O = lrelu(P @ tw + tb) (validated r2) =================
__global__ __launch_bounds__(256) void k_tproj(const float* __restrict__ P, const float* __restrict__ tw,
                                               const float* __restrict__ tb, float* __restrict__ O)
{
    int idx = blockIdx.x*256 + threadIdx.x;   // 4096*64
    int srow = idx >> 6, e = idx & 63;
    const float* pr = P + (size_t)srow*128;
    float acc = tb[e];
    for (int d = 0; d < 128; ++d) acc += pr[d] * tw[d*64 + e];
    O[idx] = lrelu(acc);
}

// ================= K8: fc1 partial sums (validated r2) =================
__global__ __launch_bounds__(256) void k_fc1(const float* __restrict__ O1, const float* __restrict__ O2,
                                             const float* __restrict__ w, float* __restrict__ pbuf)
{
    __shared__ float red[4*512];
    const int t = threadIdx.x;
    const int wv = t >> 6, l = t & 63;
    const int gwid = blockIdx.x*4 + wv;   // 0..2047
    float acc[4][2] = {};
    int base = gwid*64;
    for (int tt = 0; tt < 64; ++tt) {
        int row = base + tt;
        float2 wvv = *(const float2*)&w[(size_t)row*128 + l*2];
        #pragma unroll
        for (int b = 0; b < 4; ++b) {
            float fb = (row < 65536) ? O1[b*65536 + row] : O2[b*65536 + row - 65536];
            acc[b][0] += fb * wvv.x;
            acc[b][1] += fb * wvv.y;
        }
    }
    #pragma unroll
    for (int b = 0; b < 4; ++b) {
        red[wv*512 + b*128 + l*2]   = acc[b][0];
        red[wv*512 + b*128 + l*2+1] = acc[b][1];
    }
    __syncthreads();
    for (int rep = 0; rep < 2; ++rep) {
        int col = rep*256 + t;
        pbuf[(size_t)blockIdx.x*512 + col] = red[col] + red[512+col] + red[1024+col] + red[1536+col];
    }
}

// ============ K8b: parallel reduce of fc1 partials ============
__global__ __launch_bounds__(256) void k_red(const float* __restrict__ pbuf, float* __restrict__ pbuf2)
{
    int col = blockIdx.x*8 + (threadIdx.x >> 5);
    int lane = threadIdx.x & 31;
    float acc = 0.f;
    for (int it = 0; it < 16; ++it)
        acc += pbuf[(size_t)(lane + it*32)*512 + col];
    #pragma unroll
    for (int s2 = 16; s2 >= 1; s2 >>= 1) acc += __shfl_xor(acc, s2, 32);
    if (lane == 0) pbuf2[col] = acc;
}

// ============ K9: MLP head ============
__global__ __launch_bounds__(256) void k_head2(const float* __restrict__ pbuf2,
    const float* __restrict__ fc1b, const float* __restrict__ fc2w, const float* __restrict__ fc2b,
    const float* __restrict__ fc3w, const float* __restrict__ fc3b,
    const float* __restrict__ fc4w, const float* __restrict__ fc4b,
    float* __restrict__ out)
{
    __shared__ float r1[512], r2[512], r3[256];
    const int t = threadIdx.x;
    for (int rep = 0; rep < 2; ++rep) {
        int idx = rep*256 + t;
        r1[idx] = frelu(pbuf2[idx] + fc1b[idx & 127]);
    }
    __syncthreads();
    for (int rep = 0; rep < 2; ++rep) {
        int idx = rep*256 + t;
        int b = idx >> 7, j = idx & 127;
        float acc = fc2b[j];
        for (int k = 0; k < 128; ++k) acc += r1[b*128+k]*fc2w[k*128+j];
        r2[idx] = frelu(acc);
    }
    __syncthreads();
    {
        int b = t >> 6, e2 = t & 63;
        float acc = fc3b[e2];
        for (int k = 0; k < 128; ++k) acc += r2[b*128+k]*fc3w[k*64+e2];
        r3[t] = frelu(acc);
    }
    __syncthreads();
    if (t < 24) {
        int b = t/6, c = t%6;
        float acc = fc4b[c];
        for (int k = 0; k < 64; ++k) acc += r3[b*64+k]*fc4w[k*6+c];
        out[b*6+c] = acc;
    }
}

extern "C" void kernel_launch(void* const* d_in, const int* in_sizes, int n_in,
                              void* d_out, int out_size, void* d_ws, size_t ws_size,
                              hipStream_t stream)
{
    (void)in_sizes; (void)n_in; (void)out_size; (void)ws_size;
    const float* xenc = (const float*)d_in[0];
    const float* w1   = (const float*)d_in[4];
    const float* g1   = (const float*)d_in[5];
    const float* b1   = (const float*)d_in[6];
    const float* w2   = (const float*)d_in[7];
    const float* g2   = (const float*)d_in[8];
    const float* b2   = (const float*)d_in[9];
    const float* w3   = (const float*)d_in[10];
    const float* g3   = (const float*)d_in[11];
    const float* b3   = (const float*)d_in[12];
    const float* m2w  = (const float*)d_in[13];
    const float* m2b  = (const float*)d_in[14];
    const float* m2g  = (const float*)d_in[15];
    const float* m2bb = (const float*)d_in[16];
    const float* g1w  = (const float*)d_in[17];
    const float* g1b  = (const float*)d_in[18];
    const float* m1g  = (const float*)d_in[19];
    const float* m1b  = (const float*)d_in[20];
    const float* t1w  = (const float*)d_in[21];
    const float* t1b  = (const float*)d_in[22];
    const float* g2w  = (const float*)d_in[23];
    const float* g2bv = (const float*)d_in[24];
    const float* mm2g = (const float*)d_in[25];
    const float* mm2b = (const float*)d_in[26];
    const float* t2w  = (const float*)d_in[27];
    const float* t2b  = (const float*)d_in[28];
    const float* fc1w = (const float*)d_in[29];
    const float* fc1b = (const float*)d_in[30];
    const float* fc2w = (const float*)d_in[31];
    const float* fc2b = (const float*)d_in[32];
    const float* fc3w = (const float*)d_in[33];
    const float* fc3b = (const float*)d_in[34];
    const float* fc4w = (const float*)d_in[35];
    const float* fc4b = (const float*)d_in[36];

    char* ws = (char*)d_ws;
    float* a2   = (float*)(ws);                 // 2 MB (dead after buildx)
    float* X    = (float*)(ws + (2u<<20));      // 2 MB
    unsigned short* Hbhi1 = (unsigned short*)(ws + (4u<<20)); // 1 MB
    unsigned short* Hblo1 = (unsigned short*)(ws + (5u<<20)); // 1 MB
    unsigned short* Hbhi2 = (unsigned short*)(ws);            // 1 MB (aliases dead a2)
    unsigned short* Hblo2 = (unsigned short*)(ws + (1u<<20)); // 1 MB (aliases dead a2)
    float* S    = (float*)(ws + (6u<<20));      // 16 MB
    float* P    = (float*)(ws + (22u<<20));     // 2 MB
    float* O1   = (float*)(ws + (24u<<20));     // 1 MB
    float* O2   = (float*)(ws + (25u<<20));     // 1 MB
    float* pbuf = (float*)(ws + (26u<<20));     // 1 MB
    // transient buffers overlaid on S's region (dead before k_scores writes S)
    unsigned short* aflatG = (unsigned short*)(ws + (6u<<20));             // 4.72 MB
    unsigned short* w2s    = (unsigned short*)(ws + (6u<<20) + 5242880);   // 128 KB
    unsigned short* w3s    = (unsigned short*)(ws + (6u<<20) + 5242880 + 131072);  // 64 KB
    unsigned short* m2wbT  = (unsigned short*)(ws + (6u<<20) + 5242880 + 196608);  // 144 KB
    // pbuf2 aliases the S region (S dead after last k_pvsm; rewritten every replay)
    float* pbuf2 = (float*)(ws + (6u<<20));     // 2 KB

    k_prep<<<288, 256, 0, stream>>>(w2, w3, m2w, w2s, w3s, m2wbT);
    k_conv<<<4096, 256, 0, stream>>>(xenc, w1,g1,b1, w2s,g2,b2, w3s,g3,b3, aflatG);
    k_map2<<<64, 256, 0, stream>>>(aflatG, m2wbT, m2b, m2g, m2bb, a2);
    k_buildx<<<2048, 256, 0, stream>>>(a2, X);
    k_hmat<<<dim3(2048,2), 256, 0, stream>>>(X, g1w, g1b, g2w, g2bv,
                                             Hbhi1, Hblo1, Hbhi2, Hblo2);
    // branch 1
    k_scores<<<dim3(16,16,4), 256, 0, stream>>>(Hbhi1, Hblo1, S);
    k_pvsm  <<<dim3(64,4), 256, 0, stream>>>(S, X, m1g, m1b, P);
    k_tproj <<<1024, 256, 0, stream>>>(P, t1w, t1b, O1);
    // branch 2
    k_scores<<<dim3(16,16,4), 256, 0, stream>>>(Hbhi2, Hblo2, S);
    k_pvsm  <<<dim3(64,4), 256, 0, stream>>>(S, X, mm2g, mm2b, P);
    k_tproj <<<1024, 256, 0, stream>>>(P, t2w, t2b, O2);
    // head
    k_fc1 <<<512, 256, 0, stream>>>(O1, O2, fc1w, pbuf);
    k_red <<<64, 256, 0, stream>>>(pbuf, pbuf2);
    k_head2<<<1, 256, 0, stream>>>(pbuf2, fc1b, fc2w, fc2b, fc3w, fc3b, fc4w, fc4b, (float*)d_out);
}

// Round 8
// 346.174 us; speedup vs baseline: 1.8117x; 1.8117x over previous
//
#include <hip/hip_runtime.h>
#include <math.h>

#define NEG 0.01f
__device__ __forceinline__ float lrelu(float v){ return v > 0.f ? v : NEG*v; }
__device__ __forceinline__ float frelu(float v){ return v > 0.f ? v : 0.f; }

typedef __attribute__((ext_vector_type(8))) short bf16x8;
typedef __attribute__((ext_vector_type(4))) float f32x4;

__device__ __forceinline__ unsigned short f2bf(float x){
    unsigned int u = __float_as_uint(x);
    unsigned int r = (u + 0x7FFFu + ((u>>16)&1u)) >> 16;
    return (unsigned short)r;
}
__device__ __forceinline__ float bf2f(unsigned short h){
    return __uint_as_float(((unsigned int)h) << 16);
}

// ============ K0: weight repack (frag-ready layouts, bf16) ============
__global__ __launch_bounds__(256) void k_prep(const float* __restrict__ w2, const float* __restrict__ w3,
    const float* __restrict__ m2w,
    unsigned short* __restrict__ w2s, unsigned short* __restrict__ w3s, unsigned short* __restrict__ m2wbT)
{
    int gid = blockIdx.x*256 + threadIdx.x;
    if (gid < 73728) {
        int j = gid / 576, f = gid % 576;
        m2wbT[gid] = f2bf(m2w[f*128 + j]);
    }
    if (gid < 65536) {
        int jj = gid & 7, q = (gid>>3)&3, o = (gid>>5)&127, ks = (gid>>12)&1, k = gid>>13;
        int c = ks*32 + q*8 + jj;
        w2s[gid] = f2bf(w2[o*512 + c*8 + k]);
    }
    if (gid < 32768) {
        int jj = gid & 7, q = (gid>>3)&3, o = (gid>>5)&31, ks = (gid>>10)&3, k = gid>>12;
        int c = ks*32 + q*8 + jj;
        w3s[gid] = f2bf(w3[o*1024 + c*8 + k]);
    }
}

// ============ K1: fused conv stack, MFMA conv2/conv3, sliding-window conv1 ============
__global__ __launch_bounds__(256) void k_conv(
    const float* __restrict__ xenc,
    const float* __restrict__ w1, const float* __restrict__ g1, const float* __restrict__ b1,
    const unsigned short* __restrict__ w2s, const float* __restrict__ g2, const float* __restrict__ b2,
    const unsigned short* __restrict__ w3s, const float* __restrict__ g3, const float* __restrict__ b3,
    unsigned short* __restrict__ aflatG)
{
    __shared__ __align__(16) unsigned char smraw[38464];
    float* sigp = (float*)smraw;                            // [144] (zero-padded)
    unsigned short* p1T = (unsigned short*)(smraw + 576);
    unsigned short* p2T = (unsigned short*)(smraw + 10304);
    unsigned short* c2o = (unsigned short*)(smraw + 21056);
    float* c3o = (float*)(smraw + 21056);

    const int t = threadIdx.x;
    const int s = blockIdx.x;

    {
        unsigned int* zz = (unsigned int*)(smraw + 576);
        for (int i = t; i < 5120; i += 256) zz[i] = 0u;
        if (t < 144) sigp[t] = 0.f;
    }
    __syncthreads();
    if (t < 128) sigp[4 + t] = xenc[(size_t)s*128 + t];
    __syncthreads();

    {   // conv1 f32 (sliding window) + bn + relu + pool -> p1T (bf16, swizzled)
        const int c = t & 63, qg = t >> 6;
        float wr[8];
        #pragma unroll
        for (int k = 0; k < 8; ++k) wr[k] = w1[c*8 + k];
        const float g = g1[c], b = b1[c];
        const int qs = qg*17;                 // 0,17,34,51
        float win[9];                         // win[x] = sigp[2q-1+x]
        {
            int base = 2*qs - 1;
            #pragma unroll
            for (int x = 0; x < 9; ++x) win[x] = (base + x >= 0) ? sigp[base + x] : 0.f;
        }
        #pragma unroll
        for (int j = 0; j < 17; ++j) {
            int q = qs + j;
            float s0 = 0.f, s1 = 0.f;
            #pragma unroll
            for (int k = 0; k < 8; ++k) { s0 += win[k]*wr[k]; s1 += win[k+1]*wr[k]; }
            float v = frelu(s1*g + b);
            if (q > 0) v = fmaxf(v, frelu(s0*g + b));
            if (q < 65) {
                int row = q + 4;
                p1T[row*64 + (((c>>3) ^ (row&7))<<3) + (c&7)] = f2bf(v);
            }
            #pragma unroll
            for (int x = 0; x < 7; ++x) win[x] = win[x+2];
            win[7] = sigp[2*q + 8];
            win[8] = sigp[2*q + 9];
        }
    }
    __syncthreads();

    {   // conv2 MFMA (validated r2)
        const int wv = t >> 6, l = t & 63, lg = l >> 4, lr = l & 15;
        f32x4 acc[2][5] = {};
        for (int k = 0; k < 8; ++k) {
            for (int ks = 0; ks < 2; ++ks) {
                bf16x8 af[2];
                #pragma unroll
                for (int oi = 0; oi < 2; ++oi) {
                    int o = (wv*2 + oi)*16 + lr;
                    af[oi] = *(const bf16x8*)(w2s + ((((k*2 + ks)*128 + o)*4 + lg)<<3));
                }
                #pragma unroll
                for (int nt = 0; nt < 5; ++nt) {
                    int row = nt*16 + lr + k; row = row > 75 ? 75 : row;
                    int q = ks*4 + lg;
                    bf16x8 bfv = *(const bf16x8*)(p1T + row*64 + ((q ^ (row&7))<<3));
                    acc[0][nt] = __builtin_amdgcn_mfma_f32_16x16x32_bf16(af[0], bfv, acc[0][nt], 0,0,0);
                    acc[1][nt] = __builtin_amdgcn_mfma_f32_16x16x32_bf16(af[1], bfv, acc[1][nt], 0,0,0);
                }
            }
        }
        #pragma unroll
        for (int oi = 0; oi < 2; ++oi)
            #pragma unroll
            for (int nt = 0; nt < 5; ++nt)
                #pragma unroll
                for (int r = 0; r < 4; ++r) {
                    int o = (wv*2 + oi)*16 + lg*4 + r;
                    int p = nt*16 + lr;
                    if (p < 66) c2o[o*68 + p] = f2bf(frelu(acc[oi][nt][r] * g2[o] + b2[o]));
                }
    }
    __syncthreads();

    for (int idx = t; idx < 4352; idx += 256) {   // pool2
        int o = idx & 127, q = idx >> 7;
        unsigned short v = (q <= 32) ? c2o[o*68 + 2*q] : (unsigned short)0;
        if (q > 0) { unsigned short v2 = c2o[o*68 + 2*q - 1]; v = (v2 > v) ? v2 : v; }
        int row = q + 4;
        p2T[row*128 + (((o>>3) ^ (row&15))<<3) + (o&7)] = v;
    }
    __syncthreads();

    {   // conv3 MFMA (validated r2)
        const int wv = t >> 6, l = t & 63, lg = l >> 4, lr = l & 15;
        const int ot = wv & 1, ntb = (wv >> 1) * 2;
        const int ncnt = (wv < 2) ? 2 : 1;
        f32x4 acc[2] = {};
        for (int k = 0; k < 8; ++k) {
            for (int ks = 0; ks < 4; ++ks) {
                int o = ot*16 + lr;
                bf16x8 af = *(const bf16x8*)(w3s + ((((k*4 + ks)*32 + o)*4 + lg)<<3));
                int q = ks*4 + lg;
                #pragma unroll
                for (int ni = 0; ni < 2; ++ni) {
                    if (ni < ncnt) {
                        int row = (ntb + ni)*16 + lr + k; row = row > 41 ? 41 : row;
                        bf16x8 bfv = *(const bf16x8*)(p2T + row*128 + ((q ^ (row&15))<<3));
                        acc[ni] = __builtin_amdgcn_mfma_f32_16x16x32_bf16(af, bfv, acc[ni], 0,0,0);
                    }
                }
            }
        }
        #pragma unroll
        for (int ni = 0; ni < 2; ++ni) if (ni < ncnt)
            #pragma unroll
            for (int r = 0; r < 4; ++r) {
                int o = ot*16 + lg*4 + r;
                int p = (ntb + ni)*16 + lr;
                if (p < 35) c3o[o*36 + p] = frelu(acc[ni][r] * g3[o] + b3[o]);
            }
    }
    __syncthreads();

    for (int idx = t; idx < 576; idx += 256) {   // pool3 -> global
        int o = idx / 18, q = idx % 18;
        float v = c3o[o*36 + 2*q];
        if (q > 0) v = fmaxf(v, c3o[o*36 + 2*q - 1]);
        aflatG[(size_t)s*576 + idx] = f2bf(v);
    }
}

// ============ K1b: map2 GEMM (validated r2) ============
__global__ __launch_bounds__(256) void k_map2(const unsigned short* __restrict__ aflatG,
    const unsigned short* __restrict__ m2wbT,
    const float* __restrict__ m2b, const float* __restrict__ m2g, const float* __restrict__ m2bb,
    float* __restrict__ a2)
{
    const int t = threadIdx.x, wv = t>>6, l = t&63, lg = l>>4, lr = l&15;
    const int s0 = blockIdx.x*64;
    f32x4 acc[8] = {};
    for (int ks = 0; ks < 18; ++ks) {
        bf16x8 a = *(const bf16x8*)(aflatG + (size_t)(s0 + wv*16 + lr)*576 + ks*32 + lg*8);
        #pragma unroll
        for (int nt = 0; nt < 8; ++nt) {
            bf16x8 b = *(const bf16x8*)(m2wbT + (size_t)(nt*16 + lr)*576 + ks*32 + lg*8);
            acc[nt] = __builtin_amdgcn_mfma_f32_16x16x32_bf16(a, b, acc[nt], 0,0,0);
        }
    }
    #pragma unroll
    for (int nt = 0; nt < 8; ++nt)
        #pragma unroll
        for (int r = 0; r < 4; ++r) {
            int s2 = s0 + wv*16 + lg*4 + r;
            int j = nt*16 + lr;
            a2[(size_t)s2*128 + j] = (acc[nt][r] + m2b[j]) * m2g[j] + m2bb[j];
        }
}

// ===== K2: build X + PE (f64 table + range-reduce + HW f32 trig) =====
__global__ __launch_bounds__(256) void k_buildx(const float* __restrict__ a2, float* __restrict__ X)
{
    __shared__ double dvt[64];
    const int t = threadIdx.x;
    if (t < 64) dvt[t] = exp((double)(2*t) * (-9.210340371976184/128.0));  // ln(1e4)
    __syncthreads();
    int e = blockIdx.x*256 + t;
    int b = e >> 17;
    int r = e & 131071;
    int i = r >> 7, d = r & 127;
    int row = b*1024 + (d & 7)*128 + (i >> 3);
    int col = (i & 7)*16 + (d >> 3);
    float v = a2[row*128 + col];
    int per = b*1024 + (i & 7)*128 + d;
    int pc  = i >> 3;
    double ang = (double)per * dvt[pc >> 1];
    const double TWO_PI = 6.283185307179586476925287;
    double kk = floor(ang * (1.0/TWO_PI) + 0.5);
    float red = (float)(ang - kk * TWO_PI);        // in [-pi, pi]
    float pe = (pc & 1) ? __cosf(red) : __sinf(red);
    X[e] = v + pe;
}

// ===== K3: H = X @ gw + gb (f32, both branches) -> bf16 hi/lo =====
__global__ __launch_bounds__(256) void k_hmat(const float* __restrict__ X,
    const float* __restrict__ g1w, const float* __restrict__ g1b,
    const float* __restrict__ g2w, const float* __restrict__ g2b,
    unsigned short* __restrict__ Hbhi1, unsigned short* __restrict__ Hblo1,
    unsigned short* __restrict__ Hbhi2, unsigned short* __restrict__ Hblo2)
{
    const int br = blockIdx.y;
    const float* gw = br ? g2w : g1w;
    const float* gb = br ? g2b : g1b;
    unsigned short* Hh = br ? Hbhi2 : Hbhi1;
    unsigned short* Hl = br ? Hblo2 : Hblo1;
    int e = blockIdx.x*256 + threadIdx.x;
    int srow = e >> 7, j = e & 127;
    const float* xr = X + (size_t)srow*128;
    float acc = gb[j];
    for (int k = 0; k < 128; ++k) acc += xr[k] * gw[k*128 + j];
    unsigned short hh = f2bf(acc);
    Hh[e] = hh;
    Hl[e] = f2bf(acc - bf2f(hh));
}

// ===== K4: S = lrelu(H H^T - 1e8*I) via bf16 hi/lo MFMA (validated r6) =====
__global__ __launch_bounds__(256) void k_scores(
    const unsigned short* __restrict__ Hbhi, const unsigned short* __restrict__ Hblo,
    float* __restrict__ S)
{
    __shared__ __align__(16) unsigned short HiH[64*64];
    __shared__ __align__(16) unsigned short HiL[64*64];
    __shared__ __align__(16) unsigned short HjH[64*64];
    __shared__ __align__(16) unsigned short HjL[64*64];
    const int b = blockIdx.z;
    const int i0 = blockIdx.y * 64, j0 = blockIdx.x * 64;
    const int t = threadIdx.x;
    const int w = t >> 6, l = t & 63, lr = l & 15, h = l >> 4;
    const size_t hb = (size_t)b * 1024 * 128;

    f32x4 acc[4] = {};
    for (int kh = 0; kh < 2; ++kh) {
        __syncthreads();
        #pragma unroll
        for (int it = 0; it < 4; ++it) {
            int g = it*256 + t;
            int mat = g >> 9;
            int gg = g & 511;
            int row = gg >> 3, ch = gg & 7;
            int base0 = mat ? j0 : i0;
            size_t src = hb + (size_t)(base0 + row)*128 + kh*64 + ch*8;
            uint4 vh = *(const uint4*)(Hbhi + src);
            uint4 vl = *(const uint4*)(Hblo + src);
            int sw = ch ^ (row & 7);
            unsigned short* dh = (mat ? HjH : HiH) + row*64 + sw*8;
            unsigned short* dl = (mat ? HjL : HiL) + row*64 + sw*8;
            *(uint4*)dh = vh;
            *(uint4*)dl = vl;
        }
        __syncthreads();
        #pragma unroll
        for (int kc = 0; kc < 2; ++kc) {
            int swA = (((kc*4 + h) ^ (lr & 7)) << 3);
            bf16x8 ah = *(const bf16x8*)&HiH[(w*16 + lr)*64 + swA];
            bf16x8 al = *(const bf16x8*)&HiL[(w*16 + lr)*64 + swA];
            #pragma unroll
            for (int jt = 0; jt < 4; ++jt) {
                bf16x8 bh = *(const bf16x8*)&HjH[(jt*16 + lr)*64 + swA];
                bf16x8 bl = *(const bf16x8*)&HjL[(jt*16 + lr)*64 + swA];
                acc[jt] = __builtin_amdgcn_mfma_f32_16x16x32_bf16(ah, bh, acc[jt], 0,0,0);
                acc[jt] = __builtin_amdgcn_mfma_f32_16x16x32_bf16(ah, bl, acc[jt], 0,0,0);
                acc[jt] = __builtin_amdgcn_mfma_f32_16x16x32_bf16(al, bh, acc[jt], 0,0,0);
            }
        }
    }
    float* Sb = S + (size_t)b*1024*1024;
    #pragma unroll
    for (int jt = 0; jt < 4; ++jt) {
        #pragma unroll
        for (int r = 0; r < 4; ++r) {
            int i = i0 + w*16 + h*4 + r;
            int j = j0 + jt*16 + lr;
            float x = acc[jt][r];
            if (i == j) x -= 1e8f;
            Sb[(size_t)i*1024 + j] = lrelu(x);
        }
    }
}

// ===== K5: row stats (max + 1/sum of exp) — read-only, high occupancy =====
__global__ __launch_bounds__(256) void k_rowstat(const float* __restrict__ S,
                                                 float* __restrict__ mrow, float* __restrict__ linv)
{
    __shared__ float red[256];
    const int b = blockIdx.y, i = blockIdx.x, t = threadIdx.x;
    const float* row = S + (size_t)b*1024*1024 + (size_t)i*1024;
    float4 v = *(const float4*)&row[t*4];
    float mx = fmaxf(fmaxf(v.x,v.y), fmaxf(v.z,v.w));
    red[t] = mx; __syncthreads();
    for (int s2 = 128; s2 > 0; s2 >>= 1) { if (t < s2) red[t] = fmaxf(red[t], red[t+s2]); __syncthreads(); }
    mx = red[0]; __syncthreads();
    float e = (__expf(v.x-mx) + __expf(v.y-mx)) + (__expf(v.z-mx) + __expf(v.w-mx));
    red[t] = e; __syncthreads();
    for (int s2 = 128; s2 > 0; s2 >>= 1) { if (t < s2) red[t] += red[t+s2]; __syncthreads(); }
    if (t == 0) { mrow[b*1024 + i] = mx; linv[b*1024 + i] = 1.f / red[0]; }
}

// ===== K6: P = (softmax(S)+I) @ (X*bng+bnb), exp applied at staging (r7-validated) =====
__global__ __launch_bounds__(256) void k_pv(const float* __restrict__ S, const float* __restrict__ X,
                                            const float* __restrict__ bng, const float* __restrict__ bnb,
                                            const float* __restrict__ mrowG, const float* __restrict__ linvG,
                                            float* __restrict__ P)
{
    __shared__ __align__(16) float Sl[16*65];
    __shared__ __align__(16) float Xl[64*132];
    const int b = blockIdx.y, i0 = blockIdx.x*16, t = threadIdx.x;
    const int il = t >> 4, dg = t & 15;
    const int sj = t & 63, sil = t >> 6;
    const int xd = t & 127, xj = t >> 7;
    const float bg = bng[xd], bb = bnb[xd];
    float mr[4];
    #pragma unroll
    for (int m2 = 0; m2 < 4; ++m2) mr[m2] = mrowG[b*1024 + i0 + sil*4 + m2];
    float acc[8] = {};
    const float* Sb = S + (size_t)b*1024*1024;
    const float* Xb = X + (size_t)b*1024*128;
    for (int c = 0; c < 16; ++c) {
        int jb = c*64;
        __syncthreads();
        #pragma unroll
        for (int m2 = 0; m2 < 4; ++m2) {
            int r2 = sil*4 + m2;
            Sl[r2*65 + sj] = __expf(Sb[(size_t)(i0+r2)*1024 + jb + sj] - mr[m2]);
        }
        #pragma unroll
        for (int m2 = 0; m2 < 32; ++m2) {
            int jc = xj + 2*m2;
            Xl[jc*132 + xd] = Xb[(size_t)(jb+jc)*128 + xd] * bg + bb;
        }
        __syncthreads();
        for (int jc = 0; jc < 64; ++jc) {
            float sv = Sl[il*65 + jc];
            float4 x0 = *(const float4*)&Xl[jc*132 + dg*8];
            float4 x1 = *(const float4*)&Xl[jc*132 + dg*8 + 4];
            acc[0] += sv*x0.x; acc[1] += sv*x0.y; acc[2] += sv*x0.z; acc[3] += sv*x0.w;
            acc[4] += sv*x1.x; acc[5] += sv*x1.y; acc[6] += sv*x1.z; acc[7] += sv*x1.w;
        }
    }
    int i = i0 + il;
    float inv = linvG[b*1024 + i];
    const float* xr = Xb + (size_t)i*128 + dg*8;
    float* pr = P + (size_t)(b*1024 + i)*128 + dg*8;
    #pragma unroll
    for (int z = 0; z < 8; ++z) {
        float xv = xr[z] * bng[dg*8+z] + bnb[dg*8+z];
        pr[z] = acc[z]*inv + xv;
    }
}

// ================= K7: O = lrelu(P @ tw + tb) (validated r2) =================
__global__ __launch_bounds__(256) void k_tproj(const float* __restrict__ P, const float* __restrict__ tw,
                                               const float* __restrict__ tb, float* __restrict__ O)
{
    int idx = blockIdx.x*256 + threadIdx.x;   // 4096*64
    int srow = idx >> 6, e = idx & 63;
    const float* pr = P + (size_t)srow*128;
    float acc = tb[e];
    for (int d = 0; d < 128; ++d) acc += pr[d] * tw[d*64 + e];
    O[idx] = lrelu(acc);
}

// ================= K8: fc1 partial sums (validated r2) =================
__global__ __launch_bounds__(256) void k_fc1(const float* __restrict__ O1, const float* __restrict__ O2,
                                             const float* __restrict__ w, float* __restrict__ pbuf)
{
    __shared__ float red[4*512];
    const int t = threadIdx.x;
    const int wv = t >> 6, l = t & 63;
    const int gwid = blockIdx.x*4 + wv;   // 0..2047
    float acc[4][2] = {};
    int base = gwid*64;
    for (int tt = 0; tt < 64; ++tt) {
        int row = base + tt;
        float2 wvv = *(const float2*)&w[(size_t)row*128 + l*2];
        #pragma unroll
        for (int b = 0; b < 4; ++b) {
            float fb = (row < 65536) ? O1[b*65536 + row] : O2[b*65536 + row - 65536];
            acc[b][0] += fb * wvv.x;
            acc[b][1] += fb * wvv.y;
        }
    }
    #pragma unroll
    for (int b = 0; b < 4; ++b) {
        red[wv*512 + b*128 + l*2]   = acc[b][0];
        red[wv*512 + b*128 + l*2+1] = acc[b][1];
    }
    __syncthreads();
    for (int rep = 0; rep < 2; ++rep) {
        int col = rep*256 + t;
        pbuf[(size_t)blockIdx.x*512 + col] = red[col] + red[512+col] + red[1024+col] + red[1536+col];
    }
}

// ============ K8b: parallel reduce of fc1 partials ============
__global__ __launch_bounds__(256) void k_red(const float* __restrict__ pbuf, float* __restrict__ pbuf2)
{
    int col = blockIdx.x*8 + (threadIdx.x >> 5);
    int lane = threadIdx.x & 31;
    float acc = 0.f;
    for (int it = 0; it < 16; ++it)
        acc += pbuf[(size_t)(lane + it*32)*512 + col];
    #pragma unroll
    for (int s2 = 16; s2 >= 1; s2 >>= 1) acc += __shfl_xor(acc, s2, 32);
    if (lane == 0) pbuf2[col] = acc;
}

// ============ K9: MLP head ============
__global__ __launch_bounds__(256) void k_head2(const float* __restrict__ pbuf2,
    const float* __restrict__ fc1b, const float* __restrict__ fc2w, const float* __restrict__ fc2b,
    const float* __restrict__ fc3w, const float* __restrict__ fc3b,
    const float* __restrict__ fc4w, const float* __restrict__ fc4b,
    float* __restrict__ out)
{
    __shared__ float r1[512], r2[512], r3[256];
    const int t = threadIdx.x;
    for (int rep = 0; rep < 2; ++rep) {
        int idx = rep*256 + t;
        r1[idx] = frelu(pbuf2[idx] + fc1b[idx & 127]);
    }
    __syncthreads();
    for (int rep = 0; rep < 2; ++rep) {
        int idx = rep*256 + t;
        int b = idx >> 7, j = idx & 127;
        float acc = fc2b[j];
        for (int k = 0; k < 128; ++k) acc += r1[b*128+k]*fc2w[k*128+j];
        r2[idx] = frelu(acc);
    }
    __syncthreads();
    {
        int b = t >> 6, e2 = t & 63;
        float acc = fc3b[e2];
        for (int k = 0; k < 128; ++k) acc += r2[b*128+k]*fc3w[k*64+e2];
        r3[t] = frelu(acc);
    }
    __syncthreads();
    if (t < 24) {
        int b = t/6, c = t%6;
        float acc = fc4b[c];
        for (int k = 0; k < 64; ++k) acc += r3[b*64+k]*fc4w[k*6+c];
        out[b*6+c] = acc;
    }
}

extern "C" void kernel_launch(void* const* d_in, const int* in_sizes, int n_in,
                              void* d_out, int out_size, void* d_ws, size_t ws_size,
                              hipStream_t stream)
{
    (void)in_sizes; (void)n_in; (void)out_size; (void)ws_size;
    const float* xenc = (const float*)d_in[0];
    const float* w1   = (const float*)d_in[4];
    const float* g1   = (const float*)d_in[5];
    const float* b1   = (const float*)d_in[6];
    const float* w2   = (const float*)d_in[7];
    const float* g2   = (const float*)d_in[8];
    const float* b2   = (const float*)d_in[9];
    const float* w3   = (const float*)d_in[10];
    const float* g3   = (const float*)d_in[11];
    const float* b3   = (const float*)d_in[12];
    const float* m2w  = (const float*)d_in[13];
    const float* m2b  = (const float*)d_in[14];
    const float* m2g  = (const float*)d_in[15];
    const float* m2bb = (const float*)d_in[16];
    const float* g1w  = (const float*)d_in[17];
    const float* g1b  = (const float*)d_in[18];
    const float* m1g  = (const float*)d_in[19];
    const float* m1b  = (const float*)d_in[20];
    const float* t1w  = (const float*)d_in[21];
    const float* t1b  = (const float*)d_in[22];
    const float* g2w  = (const float*)d_in[23];
    const float* g2bv = (const float*)d_in[24];
    const float* mm2g = (const float*)d_in[25];
    const float* mm2b = (const float*)d_in[26];
    const float* t2w  = (const float*)d_in[27];
    const float* t2b  = (const float*)d_in[28];
    const float* fc1w = (const float*)d_in[29];
    const float* fc1b = (const float*)d_in[30];
    const float* fc2w = (const float*)d_in[31];
    const float* fc2b = (const float*)d_in[32];
    const float* fc3w = (const float*)d_in[33];
    const float* fc3b = (const float*)d_in[34];
    const float* fc4w = (const float*)d_in[35];
    const float* fc4b = (const float*)d_in[36];

    char* ws = (char*)d_ws;
    float* a2   = (float*)(ws);                 // 2 MB (dead after buildx)
    float* X    = (float*)(ws + (2u<<20));      // 2 MB
    unsigned short* Hbhi1 = (unsigned short*)(ws + (4u<<20)); // 1 MB
    unsigned short* Hblo1 = (unsigned short*)(ws + (5u<<20)); // 1 MB
    unsigned short* Hbhi2 = (unsigned short*)(ws);            // 1 MB (aliases dead a2)
    unsigned short* Hblo2 = (unsigned short*)(ws + (1u<<20)); // 1 MB (aliases dead a2)
    float* S    = (float*)(ws + (6u<<20));      // 16 MB
    float* P    = (float*)(ws + (22u<<20));     // 2 MB
    float* O1   = (float*)(ws + (24u<<20));     // 1 MB
    float* O2   = (float*)(ws + (25u<<20));     // 1 MB
    float* pbuf = (float*)(ws + (26u<<20));     // 1 MB (written only by k_fc1 at the end)
    // transient buffers overlaid on S's region (dead before k_scores writes S)
    unsigned short* aflatG = (unsigned short*)(ws + (6u<<20));             // 4.72 MB
    unsigned short* w2s    = (unsigned short*)(ws + (6u<<20) + 5242880);   // 128 KB
    unsigned short* w3s    = (unsigned short*)(ws + (6u<<20) + 5242880 + 131072);  // 64 KB
    unsigned short* m2wbT  = (unsigned short*)(ws + (6u<<20) + 5242880 + 196608);  // 144 KB
    // mrow/linv alias pbuf's 1 MB (pbuf written only after all k_pv reads; each
    // replay rewrites mrow/linv via k_rowstat before k_pv reads — deterministic)
    float* mrow  = (float*)(ws + (26u<<20));            // 16 KB
    float* linv  = (float*)(ws + (26u<<20) + 65536);    // 16 KB
    // pbuf2 aliases the S region (S dead after last k_pv; rewritten every replay)
    float* pbuf2 = (float*)(ws + (6u<<20));     // 2 KB

    k_prep<<<288, 256, 0, stream>>>(w2, w3, m2w, w2s, w3s, m2wbT);
    k_conv<<<4096, 256, 0, stream>>>(xenc, w1,g1,b1, w2s,g2,b2, w3s,g3,b3, aflatG);
    k_map2<<<64, 256, 0, stream>>>(aflatG, m2wbT, m2b, m2g, m2bb, a2);
    k_buildx<<<2048, 256, 0, stream>>>(a2, X);
    k_hmat<<<dim3(2048,2), 256, 0, stream>>>(X, g1w, g1b, g2w, g2bv,
                                             Hbhi1, Hblo1, Hbhi2, Hblo2);
    // branch 1
    k_scores <<<dim3(16,16,4), 256, 0, stream>>>(Hbhi1, Hblo1, S);
    k_rowstat<<<dim3(1024,4), 256, 0, stream>>>(S, mrow, linv);
    k_pv     <<<dim3(64,4), 256, 0, stream>>>(S, X, m1g, m1b, mrow, linv, P);
    k_tproj  <<<1024, 256, 0, stream>>>(P, t1w, t1b, O1);
    // branch 2
    k_scores <<<dim3(16,16,4), 256, 0, stream>>>(Hbhi2, Hblo2, S);
    k_rowstat<<<dim3(1024,4), 256, 0, stream>>>(S, mrow, linv);
    k_pv     <<<dim3(64,4), 256, 0, stream>>>(S, X, mm2g, mm2b, mrow, linv, P);
    k_tproj  <<<1024, 256, 0, stream>>>(P, t2w, t2b, O2);
    // head
    k_fc1 <<<512, 256, 0, stream>>>(O1, O2, fc1w, pbuf);
    k_red <<<64, 256, 0, stream>>>(pbuf, pbuf2);
    k_head2<<<1, 256, 0, stream>>>(pbuf2, fc1b, fc2w, fc2b, fc3w, fc3b, fc4w, fc4b, (float*)d_out);
}

// Round 9
// 288.760 us; speedup vs baseline: 2.1719x; 1.1988x over previous
//
#include <hip/hip_runtime.h>
#include <math.h>

#define NEG 0.01f
__device__ __forceinline__ float lrelu(float v){ return v > 0.f ? v : NEG*v; }
__device__ __forceinline__ float frelu(float v){ return v > 0.f ? v : 0.f; }

typedef __attribute__((ext_vector_type(8))) short bf16x8;
typedef __attribute__((ext_vector_type(4))) float f32x4;

__device__ __forceinline__ unsigned short f2bf(float x){
    unsigned int u = __float_as_uint(x);
    unsigned int r = (u + 0x7FFFu + ((u>>16)&1u)) >> 16;
    return (unsigned short)r;
}
__device__ __forceinline__ float bf2f(unsigned short h){
    return __uint_as_float(((unsigned int)h) << 16);
}

// ============ K0: weight repack (validated) ============
__global__ __launch_bounds__(256) void k_prep(const float* __restrict__ w2, const float* __restrict__ w3,
    const float* __restrict__ m2w,
    unsigned short* __restrict__ w2s, unsigned short* __restrict__ w3s, unsigned short* __restrict__ m2wbT)
{
    int gid = blockIdx.x*256 + threadIdx.x;
    if (gid < 73728) {
        int j = gid / 576, f = gid % 576;
        m2wbT[gid] = f2bf(m2w[f*128 + j]);
    }
    if (gid < 65536) {
        int jj = gid & 7, q = (gid>>3)&3, o = (gid>>5)&127, ks = (gid>>12)&1, k = gid>>13;
        int c = ks*32 + q*8 + jj;
        w2s[gid] = f2bf(w2[o*512 + c*8 + k]);
    }
    if (gid < 32768) {
        int jj = gid & 7, q = (gid>>3)&3, o = (gid>>5)&31, ks = (gid>>10)&3, k = gid>>12;
        int c = ks*32 + q*8 + jj;
        w3s[gid] = f2bf(w3[o*1024 + c*8 + k]);
    }
}

// ============ K1: fused conv stack (validated r8, unchanged) ============
__global__ __launch_bounds__(256) void k_conv(
    const float* __restrict__ xenc,
    const float* __restrict__ w1, const float* __restrict__ g1, const float* __restrict__ b1,
    const unsigned short* __restrict__ w2s, const float* __restrict__ g2, const float* __restrict__ b2,
    const unsigned short* __restrict__ w3s, const float* __restrict__ g3, const float* __restrict__ b3,
    unsigned short* __restrict__ aflatG)
{
    __shared__ __align__(16) unsigned char smraw[38464];
    float* sigp = (float*)smraw;
    unsigned short* p1T = (unsigned short*)(smraw + 576);
    unsigned short* p2T = (unsigned short*)(smraw + 10304);
    unsigned short* c2o = (unsigned short*)(smraw + 21056);
    float* c3o = (float*)(smraw + 21056);

    const int t = threadIdx.x;
    const int s = blockIdx.x;

    {
        unsigned int* zz = (unsigned int*)(smraw + 576);
        for (int i = t; i < 5120; i += 256) zz[i] = 0u;
        if (t < 144) sigp[t] = 0.f;
    }
    __syncthreads();
    if (t < 128) sigp[4 + t] = xenc[(size_t)s*128 + t];
    __syncthreads();

    {   // conv1 f32 sliding window
        const int c = t & 63, qg = t >> 6;
        float wr[8];
        #pragma unroll
        for (int k = 0; k < 8; ++k) wr[k] = w1[c*8 + k];
        const float g = g1[c], b = b1[c];
        const int qs = qg*17;
        float win[9];
        {
            int base = 2*qs - 1;
            #pragma unroll
            for (int x = 0; x < 9; ++x) win[x] = (base + x >= 0) ? sigp[base + x] : 0.f;
        }
        #pragma unroll
        for (int j = 0; j < 17; ++j) {
            int q = qs + j;
            float s0 = 0.f, s1 = 0.f;
            #pragma unroll
            for (int k = 0; k < 8; ++k) { s0 += win[k]*wr[k]; s1 += win[k+1]*wr[k]; }
            float v = frelu(s1*g + b);
            if (q > 0) v = fmaxf(v, frelu(s0*g + b));
            if (q < 65) {
                int row = q + 4;
                p1T[row*64 + (((c>>3) ^ (row&7))<<3) + (c&7)] = f2bf(v);
            }
            #pragma unroll
            for (int x = 0; x < 7; ++x) win[x] = win[x+2];
            win[7] = sigp[2*q + 8];
            win[8] = sigp[2*q + 9];
        }
    }
    __syncthreads();

    {   // conv2 MFMA
        const int wv = t >> 6, l = t & 63, lg = l >> 4, lr = l & 15;
        f32x4 acc[2][5] = {};
        for (int k = 0; k < 8; ++k) {
            for (int ks = 0; ks < 2; ++ks) {
                bf16x8 af[2];
                #pragma unroll
                for (int oi = 0; oi < 2; ++oi) {
                    int o = (wv*2 + oi)*16 + lr;
                    af[oi] = *(const bf16x8*)(w2s + ((((k*2 + ks)*128 + o)*4 + lg)<<3));
                }
                #pragma unroll
                for (int nt = 0; nt < 5; ++nt) {
                    int row = nt*16 + lr + k; row = row > 75 ? 75 : row;
                    int q = ks*4 + lg;
                    bf16x8 bfv = *(const bf16x8*)(p1T + row*64 + ((q ^ (row&7))<<3));
                    acc[0][nt] = __builtin_amdgcn_mfma_f32_16x16x32_bf16(af[0], bfv, acc[0][nt], 0,0,0);
                    acc[1][nt] = __builtin_amdgcn_mfma_f32_16x16x32_bf16(af[1], bfv, acc[1][nt], 0,0,0);
                }
            }
        }
        #pragma unroll
        for (int oi = 0; oi < 2; ++oi)
            #pragma unroll
            for (int nt = 0; nt < 5; ++nt)
                #pragma unroll
                for (int r = 0; r < 4; ++r) {
                    int o = (wv*2 + oi)*16 + lg*4 + r;
                    int p = nt*16 + lr;
                    if (p < 66) c2o[o*68 + p] = f2bf(frelu(acc[oi][nt][r] * g2[o] + b2[o]));
                }
    }
    __syncthreads();

    for (int idx = t; idx < 4352; idx += 256) {   // pool2
        int o = idx & 127, q = idx >> 7;
        unsigned short v = (q <= 32) ? c2o[o*68 + 2*q] : (unsigned short)0;
        if (q > 0) { unsigned short v2 = c2o[o*68 + 2*q - 1]; v = (v2 > v) ? v2 : v; }
        int row = q + 4;
        p2T[row*128 + (((o>>3) ^ (row&15))<<3) + (o&7)] = v;
    }
    __syncthreads();

    {   // conv3 MFMA
        const int wv = t >> 6, l = t & 63, lg = l >> 4, lr = l & 15;
        const int ot = wv & 1, ntb = (wv >> 1) * 2;
        const int ncnt = (wv < 2) ? 2 : 1;
        f32x4 acc[2] = {};
        for (int k = 0; k < 8; ++k) {
            for (int ks = 0; ks < 4; ++ks) {
                int o = ot*16 + lr;
                bf16x8 af = *(const bf16x8*)(w3s + ((((k*4 + ks)*32 + o)*4 + lg)<<3));
                int q = ks*4 + lg;
                #pragma unroll
                for (int ni = 0; ni < 2; ++ni) {
                    if (ni < ncnt) {
                        int row = (ntb + ni)*16 + lr + k; row = row > 41 ? 41 : row;
                        bf16x8 bfv = *(const bf16x8*)(p2T + row*128 + ((q ^ (row&15))<<3));
                        acc[ni] = __builtin_amdgcn_mfma_f32_16x16x32_bf16(af, bfv, acc[ni], 0,0,0);
                    }
                }
            }
        }
        #pragma unroll
        for (int ni = 0; ni < 2; ++ni) if (ni < ncnt)
            #pragma unroll
            for (int r = 0; r < 4; ++r) {
                int o = ot*16 + lg*4 + r;
                int p = (ntb + ni)*16 + lr;
                if (p < 35) c3o[o*36 + p] = frelu(acc[ni][r] * g3[o] + b3[o]);
            }
    }
    __syncthreads();

    for (int idx = t; idx < 576; idx += 256) {   // pool3 -> global
        int o = idx / 18, q = idx % 18;
        float v = c3o[o*36 + 2*q];
        if (q > 0) v = fmaxf(v, c3o[o*36 + 2*q - 1]);
        aflatG[(size_t)s*576 + idx] = f2bf(v);
    }
}

// ============ K1b: map2 GEMM (validated) ============
__global__ __launch_bounds__(256) void k_map2(const unsigned short* __restrict__ aflatG,
    const unsigned short* __restrict__ m2wbT,
    const float* __restrict__ m2b, const float* __restrict__ m2g, const float* __restrict__ m2bb,
    float* __restrict__ a2)
{
    const int t = threadIdx.x, wv = t>>6, l = t&63, lg = l>>4, lr = l&15;
    const int s0 = blockIdx.x*64;
    f32x4 acc[8] = {};
    for (int ks = 0; ks < 18; ++ks) {
        bf16x8 a = *(const bf16x8*)(aflatG + (size_t)(s0 + wv*16 + lr)*576 + ks*32 + lg*8);
        #pragma unroll
        for (int nt = 0; nt < 8; ++nt) {
            bf16x8 b = *(const bf16x8*)(m2wbT + (size_t)(nt*16 + lr)*576 + ks*32 + lg*8);
            acc[nt] = __builtin_amdgcn_mfma_f32_16x16x32_bf16(a, b, acc[nt], 0,0,0);
        }
    }
    #pragma unroll
    for (int nt = 0; nt < 8; ++nt)
        #pragma unroll
        for (int r = 0; r < 4; ++r) {
            int s2 = s0 + wv*16 + lg*4 + r;
            int j = nt*16 + lr;
            a2[(size_t)s2*128 + j] = (acc[nt][r] + m2b[j]) * m2g[j] + m2bb[j];
        }
}

// ===== K2: build X + PE (validated r6) =====
__global__ __launch_bounds__(256) void k_buildx(const float* __restrict__ a2, float* __restrict__ X)
{
    __shared__ double dvt[64];
    const int t = threadIdx.x;
    if (t < 64) dvt[t] = exp((double)(2*t) * (-9.210340371976184/128.0));
    __syncthreads();
    int e = blockIdx.x*256 + t;
    int b = e >> 17;
    int r = e & 131071;
    int i = r >> 7, d = r & 127;
    int row = b*1024 + (d & 7)*128 + (i >> 3);
    int col = (i & 7)*16 + (d >> 3);
    float v = a2[row*128 + col];
    int per = b*1024 + (i & 7)*128 + d;
    int pc  = i >> 3;
    double ang = (double)per * dvt[pc >> 1];
    const double TWO_PI = 6.283185307179586476925287;
    double kk = floor(ang * (1.0/TWO_PI) + 0.5);
    float red = (float)(ang - kk * TWO_PI);
    float pe = (pc & 1) ? __cosf(red) : __sinf(red);
    X[e] = v + pe;
}

// ===== K3: H = X @ gw + gb -> bf16 hi/lo (validated) =====
__global__ __launch_bounds__(256) void k_hmat(const float* __restrict__ X,
    const float* __restrict__ g1w, const float* __restrict__ g1b,
    const float* __restrict__ g2w, const float* __restrict__ g2b,
    unsigned short* __restrict__ Hbhi1, unsigned short* __restrict__ Hblo1,
    unsigned short* __restrict__ Hbhi2, unsigned short* __restrict__ Hblo2)
{
    const int br = blockIdx.y;
    const float* gw = br ? g2w : g1w;
    const float* gb = br ? g2b : g1b;
    unsigned short* Hh = br ? Hbhi2 : Hbhi1;
    unsigned short* Hl = br ? Hblo2 : Hblo1;
    int e = blockIdx.x*256 + threadIdx.x;
    int srow = e >> 7, j = e & 127;
    const float* xr = X + (size_t)srow*128;
    float acc = gb[j];
    for (int k = 0; k < 128; ++k) acc += xr[k] * gw[k*128 + j];
    unsigned short hh = f2bf(acc);
    Hh[e] = hh;
    Hl[e] = f2bf(acc - bf2f(hh));
}

// ===== K4: S = lrelu(H H^T - 1e8*I) via bf16 hi/lo MFMA (validated r6) =====
__global__ __launch_bounds__(256) void k_scores(
    const unsigned short* __restrict__ Hbhi, const unsigned short* __restrict__ Hblo,
    float* __restrict__ S)
{
    __shared__ __align__(16) unsigned short HiH[64*64];
    __shared__ __align__(16) unsigned short HiL[64*64];
    __shared__ __align__(16) unsigned short HjH[64*64];
    __shared__ __align__(16) unsigned short HjL[64*64];
    const int b = blockIdx.z;
    const int i0 = blockIdx.y * 64, j0 = blockIdx.x * 64;
    const int t = threadIdx.x;
    const int w = t >> 6, l = t & 63, lr = l & 15, h = l >> 4;
    const size_t hb = (size_t)b * 1024 * 128;

    f32x4 acc[4] = {};
    for (int kh = 0; kh < 2; ++kh) {
        __syncthreads();
        #pragma unroll
        for (int it = 0; it < 4; ++it) {
            int g = it*256 + t;
            int mat = g >> 9;
            int gg = g & 511;
            int row = gg >> 3, ch = gg & 7;
            int base0 = mat ? j0 : i0;
            size_t src = hb + (size_t)(base0 + row)*128 + kh*64 + ch*8;
            uint4 vh = *(const uint4*)(Hbhi + src);
            uint4 vl = *(const uint4*)(Hblo + src);
            int sw = ch ^ (row & 7);
            unsigned short* dh = (mat ? HjH : HiH) + row*64 + sw*8;
            unsigned short* dl = (mat ? HjL : HiL) + row*64 + sw*8;
            *(uint4*)dh = vh;
            *(uint4*)dl = vl;
        }
        __syncthreads();
        #pragma unroll
        for (int kc = 0; kc < 2; ++kc) {
            int swA = (((kc*4 + h) ^ (lr & 7)) << 3);
            bf16x8 ah = *(const bf16x8*)&HiH[(w*16 + lr)*64 + swA];
            bf16x8 al = *(const bf16x8*)&HiL[(w*16 + lr)*64 + swA];
            #pragma unroll
            for (int jt = 0; jt < 4; ++jt) {
                bf16x8 bh = *(const bf16x8*)&HjH[(jt*16 + lr)*64 + swA];
                bf16x8 bl = *(const bf16x8*)&HjL[(jt*16 + lr)*64 + swA];
                acc[jt] = __builtin_amdgcn_mfma_f32_16x16x32_bf16(ah, bh, acc[jt], 0,0,0);
                acc[jt] = __builtin_amdgcn_mfma_f32_16x16x32_bf16(ah, bl, acc[jt], 0,0,0);
                acc[jt] = __builtin_amdgcn_mfma_f32_16x16x32_bf16(al, bh, acc[jt], 0,0,0);
            }
        }
    }
    float* Sb = S + (size_t)b*1024*1024;
    #pragma unroll
    for (int jt = 0; jt < 4; ++jt) {
        #pragma unroll
        for (int r = 0; r < 4; ++r) {
            int i = i0 + w*16 + h*4 + r;
            int j = j0 + jt*16 + lr;
            float x = acc[jt][r];
            if (i == j) x -= 1e8f;
            Sb[(size_t)i*1024 + j] = lrelu(x);
        }
    }
}

// ===== K5: row stats (validated r8) =====
__global__ __launch_bounds__(256) void k_rowstat(const float* __restrict__ S,
                                                 float* __restrict__ mrow, float* __restrict__ linv)
{
    __shared__ float red[256];
    const int b = blockIdx.y, i = blockIdx.x, t = threadIdx.x;
    const float* row = S + (size_t)b*1024*1024 + (size_t)i*1024;
    float4 v = *(const float4*)&row[t*4];
    float mx = fmaxf(fmaxf(v.x,v.y), fmaxf(v.z,v.w));
    red[t] = mx; __syncthreads();
    for (int s2 = 128; s2 > 0; s2 >>= 1) { if (t < s2) red[t] = fmaxf(red[t], red[t+s2]); __syncthreads(); }
    mx = red[0]; __syncthreads();
    float e = (__expf(v.x-mx) + __expf(v.y-mx)) + (__expf(v.z-mx) + __expf(v.w-mx));
    red[t] = e; __syncthreads();
    for (int s2 = 128; s2 > 0; s2 >>= 1) { if (t < s2) red[t] += red[t+s2]; __syncthreads(); }
    if (t == 0) { mrow[b*1024 + i] = mx; linv[b*1024 + i] = 1.f / red[0]; }
}

// ===== K5b: Xbb transpose -> XbbT[br][b][d][j] bf16 hi/lo (simple, inspectable) =====
__global__ __launch_bounds__(256) void k_xbbt(const float* __restrict__ X,
    const float* __restrict__ bng1, const float* __restrict__ bnb1,
    const float* __restrict__ bng2, const float* __restrict__ bnb2,
    unsigned short* __restrict__ XbbThi, unsigned short* __restrict__ XbbTlo)
{
    __shared__ float Xl[64][132];
    const int t = threadIdx.x;
    const int j0 = blockIdx.x*64, b = blockIdx.y, br = blockIdx.z;
    {
        int r2 = t >> 2, dseg = (t & 3)*32;
        const float* src = X + ((size_t)(b*1024 + j0 + r2))*128 + dseg;
        #pragma unroll
        for (int q = 0; q < 8; ++q) {
            float4 v = *(const float4*)(src + q*4);
            Xl[r2][dseg + q*4 + 0] = v.x;
            Xl[r2][dseg + q*4 + 1] = v.y;
            Xl[r2][dseg + q*4 + 2] = v.z;
            Xl[r2][dseg + q*4 + 3] = v.w;
        }
    }
    __syncthreads();
    const int d = t >> 1, seg = t & 1;
    const float g  = (br ? bng2 : bng1)[d];
    const float bb = (br ? bnb2 : bnb1)[d];
    unsigned short* dsth = XbbThi + (size_t)br*524288 + ((size_t)(b*128 + d))*1024 + j0 + seg*32;
    unsigned short* dstl = XbbTlo + (size_t)br*524288 + ((size_t)(b*128 + d))*1024 + j0 + seg*32;
    #pragma unroll
    for (int g8 = 0; g8 < 4; ++g8) {
        unsigned int hu[4], lu[4];
        #pragma unroll
        for (int q = 0; q < 4; ++q) {
            float v0 = Xl[seg*32 + g8*8 + 2*q    ][d]*g + bb;
            float v1 = Xl[seg*32 + g8*8 + 2*q + 1][d]*g + bb;
            unsigned short h0 = f2bf(v0), h1 = f2bf(v1);
            hu[q] = (unsigned int)h0 | ((unsigned int)h1 << 16);
            lu[q] = (unsigned int)f2bf(v0 - bf2f(h0)) | ((unsigned int)f2bf(v1 - bf2f(h1)) << 16);
        }
        *(uint4*)(dsth + g8*8) = make_uint4(hu[0],hu[1],hu[2],hu[3]);
        *(uint4*)(dstl + g8*8) = make_uint4(lu[0],lu[1],lu[2],lu[3]);
    }
}

// ===== K6-MFMA: P = (softmax(S)+I) @ Xbb via hi/lo MFMA (k_map2 convention) =====
__global__ __launch_bounds__(256) void k_pvmm(
    const float* __restrict__ S1, const float* __restrict__ S2, const float* __restrict__ X,
    const float* __restrict__ bng1, const float* __restrict__ bnb1,
    const float* __restrict__ bng2, const float* __restrict__ bnb2,
    const float* __restrict__ mrow, const float* __restrict__ linv,
    const unsigned short* __restrict__ XbbThi, const unsigned short* __restrict__ XbbTlo,
    float* __restrict__ P)
{
    __shared__ __align__(16) unsigned short ElH[16*64];
    __shared__ __align__(16) unsigned short ElL[16*64];
    const int t = threadIdx.x;
    const int w = t >> 6, l = t & 63, lr = l & 15, h = l >> 4;
    const int i0 = blockIdx.x * 16;
    const int b = blockIdx.y;
    const int br = blockIdx.z;
    const float* S = br ? S2 : S1;
    const float* bng = br ? bng2 : bng1;
    const float* bnb = br ? bnb2 : bnb1;
    const float* mr = mrow + br*4096 + b*1024;
    const float* lv = linv + br*4096 + b*1024;
    const unsigned short* Bh = XbbThi + (size_t)br*524288 + (size_t)b*131072;
    const unsigned short* Bl = XbbTlo + (size_t)br*524288 + (size_t)b*131072;

    const int srow = t >> 4, jseg = t & 15;   // staging: row 0..15, 4 j per thread
    const float mi = mr[i0 + srow];
    const int j0s = jseg*4;
    const int eoff = srow*64 + (((j0s>>3) ^ (srow&7))<<3) + (j0s&7);

    f32x4 acc[2] = {};
    for (int ch = 0; ch < 16; ++ch) {
        const int jb = ch*64;
        __syncthreads();
        {
            float4 sv = *(const float4*)(S + ((size_t)(b*1024 + i0 + srow))*1024 + jb + j0s);
            float e0 = __expf(sv.x - mi), e1 = __expf(sv.y - mi);
            float e2 = __expf(sv.z - mi), e3 = __expf(sv.w - mi);
            unsigned short h0 = f2bf(e0), h1 = f2bf(e1), h2 = f2bf(e2), h3 = f2bf(e3);
            uint2 vh, vl;
            vh.x = (unsigned int)h0 | ((unsigned int)h1 << 16);
            vh.y = (unsigned int)h2 | ((unsigned int)h3 << 16);
            vl.x = (unsigned int)f2bf(e0 - bf2f(h0)) | ((unsigned int)f2bf(e1 - bf2f(h1)) << 16);
            vl.y = (unsigned int)f2bf(e2 - bf2f(h2)) | ((unsigned int)f2bf(e3 - bf2f(h3)) << 16);
            *(uint2*)(ElH + eoff) = vh;
            *(uint2*)(ElL + eoff) = vl;
        }
        __syncthreads();
        #pragma unroll
        for (int kc = 0; kc < 2; ++kc) {
            int swA = (((kc*4 + h) ^ (lr & 7)) << 3);
            bf16x8 ah = *(const bf16x8*)&ElH[lr*64 + swA];
            bf16x8 al = *(const bf16x8*)&ElL[lr*64 + swA];
            #pragma unroll
            for (int n2 = 0; n2 < 2; ++n2) {
                int nt = w*2 + n2;
                size_t boff = (size_t)(nt*16 + lr)*1024 + jb + kc*32 + h*8;
                bf16x8 bh = *(const bf16x8*)(Bh + boff);
                bf16x8 bl = *(const bf16x8*)(Bl + boff);
                acc[n2] = __builtin_amdgcn_mfma_f32_16x16x32_bf16(ah, bh, acc[n2], 0,0,0);
                acc[n2] = __builtin_amdgcn_mfma_f32_16x16x32_bf16(ah, bl, acc[n2], 0,0,0);
                acc[n2] = __builtin_amdgcn_mfma_f32_16x16x32_bf16(al, bh, acc[n2], 0,0,0);
            }
        }
    }
    #pragma unroll
    for (int r = 0; r < 4; ++r) {
        int i = i0 + h*4 + r;
        float inv = lv[i];
        #pragma unroll
        for (int n2 = 0; n2 < 2; ++n2) {
            int d = (w*2 + n2)*16 + lr;
            float xv = X[((size_t)(b*1024 + i))*128 + d] * bng[d] + bnb[d];
            P[((size_t)(br*4096 + b*1024 + i))*128 + d] = acc[n2][r]*inv + xv;
        }
    }
}

// ===== K6-fallback: P = (softmax(S)+I) @ Xbb, f32 (validated r8) =====
__global__ __launch_bounds__(256) void k_pv(const float* __restrict__ S, const float* __restrict__ X,
                                            const float* __restrict__ bng, const float* __restrict__ bnb,
                                            const float* __restrict__ mrowG, const float* __restrict__ linvG,
                                            float* __restrict__ P)
{
    __shared__ __align__(16) float Sl[16*65];
    __shared__ __align__(16) float Xl[64*132];
    const int b = blockIdx.y, i0 = blockIdx.x*16, t = threadIdx.x;
    const int il = t >> 4, dg = t & 15;
    const int sj = t & 63, sil = t >> 6;
    const int xd = t & 127, xj = t >> 7;
    const float bg = bng[xd], bb = bnb[xd];
    float mr[4];
    #pragma unroll
    for (int m2 = 0; m2 < 4; ++m2) mr[m2] = mrowG[b*1024 + i0 + sil*4 + m2];
    float acc[8] = {};
    const float* Sb = S + (size_t)b*1024*1024;
    const float* Xb = X + (size_t)b*1024*128;
    for (int c = 0; c < 16; ++c) {
        int jb = c*64;
        __syncthreads();
        #pragma unroll
        for (int m2 = 0; m2 < 4; ++m2) {
            int r2 = sil*4 + m2;
            Sl[r2*65 + sj] = __expf(Sb[(size_t)(i0+r2)*1024 + jb + sj] - mr[m2]);
        }
        #pragma unroll
        for (int m2 = 0; m2 < 32; ++m2) {
            int jc = xj + 2*m2;
            Xl[jc*132 + xd] = Xb[(size_t)(jb+jc)*128 + xd] * bg + bb;
        }
        __syncthreads();
        for (int jc = 0; jc < 64; ++jc) {
            float sv = Sl[il*65 + jc];
            float4 x0 = *(const float4*)&Xl[jc*132 + dg*8];
            float4 x1 = *(const float4*)&Xl[jc*132 + dg*8 + 4];
            acc[0] += sv*x0.x; acc[1] += sv*x0.y; acc[2] += sv*x0.z; acc[3] += sv*x0.w;
            acc[4] += sv*x1.x; acc[5] += sv*x1.y; acc[6] += sv*x1.z; acc[7] += sv*x1.w;
        }
    }
    int i = i0 + il;
    float inv = linvG[b*1024 + i];
    const float* xr = Xb + (size_t)i*128 + dg*8;
    float* pr = P + (size_t)(b*1024 + i)*128 + dg*8;
    #pragma unroll
    for (int z = 0; z < 8; ++z) {
        float xv = xr[z] * bng[dg*8+z] + bnb[dg*8+z];
        pr[z] = acc[z]*inv + xv;
    }
}

// ===== K7: tproj single-branch (validated) =====
__global__ __launch_bounds__(256) void k_tproj(const float* __restrict__ P, const float* __restrict__ tw,
                                               const float* __restrict__ tb, float* __restrict__ O)
{
    int idx = blockIdx.x*256 + threadIdx.x;
    int srow = idx >> 6, e = idx & 63;
    const float* pr = P + (size_t)srow*128;
    float acc = tb[e];
    for (int d = 0; d < 128; ++d) acc += pr[d] * tw[d*64 + e];
    O[idx] = lrelu(acc);
}

// ===== K7b: tproj dual-branch =====
__global__ __launch_bounds__(256) void k_tproj2(const float* __restrict__ P,
    const float* __restrict__ t1w, const float* __restrict__ t1b,
    const float* __restrict__ t2w, const float* __restrict__ t2b,
    float* __restrict__ O)
{
    int idx = blockIdx.x*256 + threadIdx.x;   // 2*4096*64
    int srow = idx >> 6, e = idx & 63;
    int br = srow >> 12;
    const float* tw = br ? t2w : t1w;
    const float* tb = br ? t2b : t1b;
    const float* pr = P + (size_t)srow*128;
    float acc = tb[e];
    for (int d = 0; d < 128; ++d) acc += pr[d] * tw[d*64 + e];
    O[idx] = lrelu(acc);
}

// ===== K8: fc1 partial sums (validated) =====
__global__ __launch_bounds__(256) void k_fc1(const float* __restrict__ O1, const float* __restrict__ O2,
                                             const float* __restrict__ w, float* __restrict__ pbuf)
{
    __shared__ float red[4*512];
    const int t = threadIdx.x;
    const int wv = t >> 6, l = t & 63;
    const int gwid = blockIdx.x*4 + wv;
    float acc[4][2] = {};
    int base = gwid*64;
    for (int tt = 0; tt < 64; ++tt) {
        int row = base + tt;
        float2 wvv = *(const float2*)&w[(size_t)row*128 + l*2];
        #pragma unroll
        for (int b = 0; b < 4; ++b) {
            float fb = (row < 65536) ? O1[b*65536 + row] : O2[b*65536 + row - 65536];
            acc[b][0] += fb * wvv.x;
            acc[b][1] += fb * wvv.y;
        }
    }
    #pragma unroll
    for (int b = 0; b < 4; ++b) {
        red[wv*512 + b*128 + l*2]   = acc[b][0];
        red[wv*512 + b*128 + l*2+1] = acc[b][1];
    }
    __syncthreads();
    for (int rep = 0; rep < 2; ++rep) {
        int col = rep*256 + t;
        pbuf[(size_t)blockIdx.x*512 + col] = red[col] + red[512+col] + red[1024+col] + red[1536+col];
    }
}

// ===== K8b: reduce fc1 partials (validated) =====
__global__ __launch_bounds__(256) void k_red(const float* __restrict__ pbuf, float* __restrict__ pbuf2)
{
    int col = blockIdx.x*8 + (threadIdx.x >> 5);
    int lane = threadIdx.x & 31;
    float acc = 0.f;
    for (int it = 0; it < 16; ++it)
        acc += pbuf[(size_t)(lane + it*32)*512 + col];
    #pragma unroll
    for (int s2 = 16; s2 >= 1; s2 >>= 1) acc += __shfl_xor(acc, s2, 32);
    if (lane == 0) pbuf2[col] = acc;
}

// ===== K9: MLP head (validated) =====
__global__ __launch_bounds__(256) void k_head2(const float* __restrict__ pbuf2,
    const float* __restrict__ fc1b, const float* __restrict__ fc2w, const float* __restrict__ fc2b,
    const float* __restrict__ fc3w, const float* __restrict__ fc3b,
    const float* __restrict__ fc4w, const float* __restrict__ fc4b,
    float* __restrict__ out)
{
    __shared__ float r1[512], r2[512], r3[256];
    const int t = threadIdx.x;
    for (int rep = 0; rep < 2; ++rep) {
        int idx = rep*256 + t;
        r1[idx] = frelu(pbuf2[idx] + fc1b[idx & 127]);
    }
    __syncthreads();
    for (int rep = 0; rep < 2; ++rep) {
        int idx = rep*256 + t;
        int b = idx >> 7, j = idx & 127;
        float acc = fc2b[j];
        for (int k = 0; k < 128; ++k) acc += r1[b*128+k]*fc2w[k*128+j];
        r2[idx] = frelu(acc);
    }
    __syncthreads();
    {
        int b = t >> 6, e2 = t & 63;
        float acc = fc3b[e2];
        for (int k = 0; k < 128; ++k) acc += r2[b*128+k]*fc3w[k*64+e2];
        r3[t] = frelu(acc);
    }
    __syncthreads();
    if (t < 24) {
        int b = t/6, c = t%6;
        float acc = fc4b[c];
        for (int k = 0; k < 64; ++k) acc += r3[b*64+k]*fc4w[k*6+c];
        out[b*6+c] = acc;
    }
}

extern "C" void kernel_launch(void* const* d_in, const int* in_sizes, int n_in,
                              void* d_out, int out_size, void* d_ws, size_t ws_size,
                              hipStream_t stream)
{
    (void)in_sizes; (void)n_in; (void)out_size;
    const float* xenc = (const float*)d_in[0];
    const float* w1   = (const float*)d_in[4];
    const float* g1   = (const float*)d_in[5];
    const float* b1   = (const float*)d_in[6];
    const float* w2   = (const float*)d_in[7];
    const float* g2   = (const float*)d_in[8];
    const float* b2   = (const float*)d_in[9];
    const float* w3   = (const float*)d_in[10];
    const float* g3   = (const float*)d_in[11];
    const float* b3   = (const float*)d_in[12];
    const float* m2w  = (const float*)d_in[13];
    const float* m2b  = (const float*)d_in[14];
    const float* m2g  = (const float*)d_in[15];
    const float* m2bb = (const float*)d_in[16];
    const float* g1w  = (const float*)d_in[17];
    const float* g1b  = (const float*)d_in[18];
    const float* m1g  = (const float*)d_in[19];
    const float* m1b  = (const float*)d_in[20];
    const float* t1w  = (const float*)d_in[21];
    const float* t1b  = (const float*)d_in[22];
    const float* g2w  = (const float*)d_in[23];
    const float* g2bv = (const float*)d_in[24];
    const float* mm2g = (const float*)d_in[25];
    const float* mm2b = (const float*)d_in[26];
    const float* t2w  = (const float*)d_in[27];
    const float* t2b  = (const float*)d_in[28];
    const float* fc1w = (const float*)d_in[29];
    const float* fc1b = (const float*)d_in[30];
    const float* fc2w = (const float*)d_in[31];
    const float* fc2b = (const float*)d_in[32];
    const float* fc3w = (const float*)d_in[33];
    const float* fc3b = (const float*)d_in[34];
    const float* fc4w = (const float*)d_in[35];
    const float* fc4b = (const float*)d_in[36];

    char* ws = (char*)d_ws;
    // common region (both paths)
    float* a2   = (float*)(ws);                 // 2 MB (dead after buildx)
    float* X    = (float*)(ws + (2u<<20));      // 2 MB
    unsigned short* Hbhi1 = (unsigned short*)(ws + (4u<<20)); // 1 MB
    unsigned short* Hblo1 = (unsigned short*)(ws + (5u<<20)); // 1 MB
    unsigned short* Hbhi2 = (unsigned short*)(ws);            // aliases dead a2
    unsigned short* Hblo2 = (unsigned short*)(ws + (1u<<20));
    float* S1   = (float*)(ws + (6u<<20));      // 16 MB
    // transient aliases on S1 (dead before k_scores writes S1)
    unsigned short* aflatG = (unsigned short*)(ws + (6u<<20));
    unsigned short* w2s    = (unsigned short*)(ws + (6u<<20) + 5242880);
    unsigned short* w3s    = (unsigned short*)(ws + (6u<<20) + 5242880 + 131072);
    unsigned short* m2wbT  = (unsigned short*)(ws + (6u<<20) + 5242880 + 196608);
    float* pbuf2 = (float*)(ws + (6u<<20));     // 2 KB (S1 dead after last PV)

    // common prologue
    k_prep<<<288, 256, 0, stream>>>(w2, w3, m2w, w2s, w3s, m2wbT);
    k_conv<<<4096, 256, 0, stream>>>(xenc, w1,g1,b1, w2s,g2,b2, w3s,g3,b3, aflatG);
    k_map2<<<64, 256, 0, stream>>>(aflatG, m2wbT, m2b, m2g, m2bb, a2);
    k_buildx<<<2048, 256, 0, stream>>>(a2, X);
    k_hmat<<<dim3(2048,2), 256, 0, stream>>>(X, g1w, g1b, g2w, g2bv,
                                             Hbhi1, Hblo1, Hbhi2, Hblo2);

    if (ws_size >= ((size_t)49 << 20)) {
        // ---- big-workspace path: MFMA PV, dual-branch S ----
        float* S2   = (float*)(ws + (22u<<20));             // 16 MB
        float* P    = (float*)(ws + (38u<<20));             // 4 MB [br][4096][128]
        float* O    = (float*)(ws + (42u<<20));             // 2 MB (O1|O2)
        float* pbuf = (float*)(ws + (44u<<20));             // 1 MB
        float* mrow = (float*)(ws + (44u<<20));             // 32 KB (aliases pbuf; fc1 writes after PV reads)
        float* linv = (float*)(ws + (44u<<20) + 65536);     // 32 KB
        unsigned short* XbbThi = (unsigned short*)(ws + (45u<<20)); // 2 MB
        unsigned short* XbbTlo = (unsigned short*)(ws + (47u<<20)); // 2 MB
        float* O1 = O;
        float* O2 = O + 262144;

        k_xbbt<<<dim3(16,4,2), 256, 0, stream>>>(X, m1g, m1b, mm2g, mm2b, XbbThi, XbbTlo);
        k_scores <<<dim3(16,16,4), 256, 0, stream>>>(Hbhi1, Hblo1, S1);
        k_scores <<<dim3(16,16,4), 256, 0, stream>>>(Hbhi2, Hblo2, S2);
        k_rowstat<<<dim3(1024,4), 256, 0, stream>>>(S1, mrow, linv);
        k_rowstat<<<dim3(1024,4), 256, 0, stream>>>(S2, mrow + 4096, linv + 4096);
        k_pvmm<<<dim3(64,4,2), 256, 0, stream>>>(S1, S2, X, m1g, m1b, mm2g, mm2b,
                                                 mrow, linv, XbbThi, XbbTlo, P);
        k_tproj2<<<2048, 256, 0, stream>>>(P, t1w, t1b, t2w, t2b, O);
        k_fc1 <<<512, 256, 0, stream>>>(O1, O2, fc1w, pbuf);
        k_red <<<64, 256, 0, stream>>>(pbuf, pbuf2);
        k_head2<<<1, 256, 0, stream>>>(pbuf2, fc1b, fc2w, fc2b, fc3w, fc3b, fc4w, fc4b, (float*)d_out);
    } else {
        // ---- fallback: exact r8 path (27 MB) ----
        float* P    = (float*)(ws + (22u<<20));
        float* O1   = (float*)(ws + (24u<<20));
        float* O2   = (float*)(ws + (25u<<20));
        float* pbuf = (float*)(ws + (26u<<20));
        float* mrow = (float*)(ws + (26u<<20));
        float* linv = (float*)(ws + (26u<<20) + 65536);

        k_scores <<<dim3(16,16,4), 256, 0, stream>>>(Hbhi1, Hblo1, S1);
        k_rowstat<<<dim3(1024,4), 256, 0, stream>>>(S1, mrow, linv);
        k_pv     <<<dim3(64,4), 256, 0, stream>>>(S1, X, m1g, m1b, mrow, linv, P);
        k_tproj  <<<1024, 256, 0, stream>>>(P, t1w, t1b, O1);
        k_scores <<<dim3(16,16,4), 256, 0, stream>>>(Hbhi2, Hblo2, S1);
        k_rowstat<<<dim3(1024,4), 256, 0, stream>>>(S1, mrow, linv);
        k_pv     <<<dim3(64,4), 256, 0, stream>>>(S1, X, mm2g, mm2b, mrow, linv, P);
        k_tproj  <<<1024, 256, 0, stream>>>(P, t2w, t2b, O2);
        k_fc1 <<<512, 256, 0, stream>>>(O1, O2, fc1w, pbuf);
        k_red <<<64, 256, 0, stream>>>(pbuf, pbuf2);
        k_head2<<<1, 256, 0, stream>>>(pbuf2, fc1b, fc2w, fc2b, fc3w, fc3b, fc4w, fc4b, (float*)d_out);
    }
}

// Round 10
// 279.014 us; speedup vs baseline: 2.2478x; 1.0349x over previous
//
#include <hip/hip_runtime.h>
#include <hip/hip_bf16.h>
#include <math.h>

#define NEG 0.01f
__device__ __forceinline__ float lrelu(float v){ return v > 0.f ? v : NEG*v; }
__device__ __forceinline__ float frelu(float v){ return v > 0.f ? v : 0.f; }

typedef __attribute__((ext_vector_type(8))) short bf16x8;
typedef __attribute__((ext_vector_type(4))) float f32x4;

__device__ __forceinline__ unsigned short f2bf(float x){
    unsigned int u = __float_as_uint(x);
    unsigned int r = (u + 0x7FFFu + ((u>>16)&1u)) >> 16;
    return (unsigned short)r;
}
__device__ __forceinline__ float bf2f(unsigned short h){
    return __uint_as_float(((unsigned int)h) << 16);
}
// native RNE convert (hot paths in k_conv only)
__device__ __forceinline__ unsigned short F2B(float x){
    __hip_bfloat16 h = __float2bfloat16(x);
    return *reinterpret_cast<unsigned short*>(&h);
}

// ============ K0: weight repack (validated) ============
__global__ __launch_bounds__(256) void k_prep(const float* __restrict__ w2, const float* __restrict__ w3,
    const float* __restrict__ m2w,
    unsigned short* __restrict__ w2s, unsigned short* __restrict__ w3s, unsigned short* __restrict__ m2wbT)
{
    int gid = blockIdx.x*256 + threadIdx.x;
    if (gid < 73728) {
        int j = gid / 576, f = gid % 576;
        m2wbT[gid] = f2bf(m2w[f*128 + j]);
    }
    if (gid < 65536) {
        int jj = gid & 7, q = (gid>>3)&3, o = (gid>>5)&127, ks = (gid>>12)&1, k = gid>>13;
        int c = ks*32 + q*8 + jj;
        w2s[gid] = f2bf(w2[o*512 + c*8 + k]);
    }
    if (gid < 32768) {
        int jj = gid & 7, q = (gid>>3)&3, o = (gid>>5)&31, ks = (gid>>10)&3, k = gid>>12;
        int c = ks*32 + q*8 + jj;
        w3s[gid] = f2bf(w3[o*1024 + c*8 + k]);
    }
}

// ============ K1: fused conv stack — fused pools via strided lane map ============
// LDS: sigp f32[144] @0; p1T bf16[76][64] @576; p2T bf16[42][128] @10304;
//      astage bf16[576] @21056  -> total 22208 B (7 blocks/CU)
// position map (conv2/conv3): lane lr -> p = nt*16 + 2*(lr&7) + (lr>>3) - 1
// pool pair (2q-1, 2q) = lanes (lr, lr^8); q = nt*8 + (lr&7)
__global__ __launch_bounds__(256) void k_conv(
    const float* __restrict__ xenc,
    const float* __restrict__ w1, const float* __restrict__ g1, const float* __restrict__ b1,
    const unsigned short* __restrict__ w2s, const float* __restrict__ g2, const float* __restrict__ b2,
    const unsigned short* __restrict__ w3s, const float* __restrict__ g3, const float* __restrict__ b3,
    unsigned short* __restrict__ aflatG)
{
    __shared__ __align__(16) unsigned char smraw[22208];
    float* sigp = (float*)smraw;                              // [144] zero-padded
    unsigned short* p1T = (unsigned short*)(smraw + 576);     // [76][64] swizzled
    unsigned short* p2T = (unsigned short*)(smraw + 10304);   // [42][128] swizzled
    unsigned short* astage = (unsigned short*)(smraw + 21056);// [576]

    const int t = threadIdx.x;
    const int s = blockIdx.x;

    {
        unsigned int* zz = (unsigned int*)(smraw + 576);      // zero p1T+p2T (20480B)
        for (int i = t; i < 5120; i += 256) zz[i] = 0u;
        if (t < 144) sigp[t] = 0.f;
    }
    __syncthreads();
    if (t < 128) sigp[4 + t] = xenc[(size_t)s*128 + t];
    __syncthreads();

    {   // conv1 f32 sliding window + pool -> p1T (validated r8)
        const int c = t & 63, qg = t >> 6;
        float wr[8];
        #pragma unroll
        for (int k = 0; k < 8; ++k) wr[k] = w1[c*8 + k];
        const float g = g1[c], b = b1[c];
        const int qs = qg*17;
        float win[9];
        {
            int base = 2*qs - 1;
            #pragma unroll
            for (int x = 0; x < 9; ++x) win[x] = (base + x >= 0) ? sigp[base + x] : 0.f;
        }
        #pragma unroll
        for (int j = 0; j < 17; ++j) {
            int q = qs + j;
            float s0 = 0.f, s1 = 0.f;
            #pragma unroll
            for (int k = 0; k < 8; ++k) { s0 += win[k]*wr[k]; s1 += win[k+1]*wr[k]; }
            float v = frelu(s1*g + b);
            if (q > 0) v = fmaxf(v, frelu(s0*g + b));
            if (q < 65) {
                int row = q + 4;
                p1T[row*64 + (((c>>3) ^ (row&7))<<3) + (c&7)] = F2B(v);
            }
            #pragma unroll
            for (int x = 0; x < 7; ++x) win[x] = win[x+2];
            win[7] = sigp[2*q + 8];
            win[8] = sigp[2*q + 9];
        }
    }
    __syncthreads();

    {   // conv2 MFMA (strided positions) + fused bn/relu/pool2 -> p2T
        const int wv = t >> 6, l = t & 63, lg = l >> 4, lr = l & 15;
        const int pbase = ((lr & 7) << 1) + (lr >> 3) - 1;   // p = nt*16 + pbase
        f32x4 acc[2][5] = {};
        for (int k = 0; k < 8; ++k) {
            for (int ks = 0; ks < 2; ++ks) {
                bf16x8 af[2];
                #pragma unroll
                for (int oi = 0; oi < 2; ++oi) {
                    int o = (wv*2 + oi)*16 + lr;
                    af[oi] = *(const bf16x8*)(w2s + ((((k*2 + ks)*128 + o)*4 + lg)<<3));
                }
                const int q = ks*4 + lg;
                #pragma unroll
                for (int nt = 0; nt < 5; ++nt) {
                    int row = nt*16 + pbase + k; row = row > 75 ? 75 : row;
                    bf16x8 bfv = *(const bf16x8*)(p1T + row*64 + ((q ^ (row&7))<<3));
                    acc[0][nt] = __builtin_amdgcn_mfma_f32_16x16x32_bf16(af[0], bfv, acc[0][nt], 0,0,0);
                    acc[1][nt] = __builtin_amdgcn_mfma_f32_16x16x32_bf16(af[1], bfv, acc[1][nt], 0,0,0);
                }
            }
        }
        float ga[2][4], ba[2][4];
        #pragma unroll
        for (int oi = 0; oi < 2; ++oi)
            #pragma unroll
            for (int r = 0; r < 4; ++r) {
                int o = (wv*2 + oi)*16 + lg*4 + r;
                ga[oi][r] = g2[o]; ba[oi][r] = b2[o];
            }
        #pragma unroll
        for (int oi = 0; oi < 2; ++oi)
            #pragma unroll
            for (int nt = 0; nt < 5; ++nt) {
                int p = nt*16 + pbase;
                bool valid = (p >= 0) && (p <= 65);
                float vv[4];
                #pragma unroll
                for (int r = 0; r < 4; ++r) {
                    float v = frelu(acc[oi][nt][r]*ga[oi][r] + ba[oi][r]);
                    vv[r] = valid ? v : -3.0e38f;
                }
                float pv[4];
                #pragma unroll
                for (int r = 0; r < 4; ++r) pv[r] = fmaxf(vv[r], __shfl_xor(vv[r], 8));
                int q = nt*8 + (lr & 7);
                if ((lr >> 3) == 0 && q < 34) {
                    int row2 = q + 4;
                    int o0 = (wv*2 + oi)*16 + lg*4;
                    uint2 pk;
                    pk.x = (unsigned int)F2B(pv[0]) | ((unsigned int)F2B(pv[1]) << 16);
                    pk.y = (unsigned int)F2B(pv[2]) | ((unsigned int)F2B(pv[3]) << 16);
                    *(uint2*)&p2T[row2*128 + (((o0>>3) ^ (row2&15))<<3) + (o0&7)] = pk;
                }
            }
    }
    __syncthreads();

    {   // conv3 MFMA (strided positions) + fused bn/relu/pool3 -> astage
        const int wv = t >> 6, l = t & 63, lg = l >> 4, lr = l & 15;
        const int ot = wv & 1, ntb = (wv >> 1) * 2;
        const int ncnt = (wv < 2) ? 2 : 1;
        const int pbase = ((lr & 7) << 1) + (lr >> 3) - 1;
        f32x4 acc[2] = {};
        for (int k = 0; k < 8; ++k) {
            for (int ks = 0; ks < 4; ++ks) {
                int o = ot*16 + lr;
                bf16x8 af = *(const bf16x8*)(w3s + ((((k*4 + ks)*32 + o)*4 + lg)<<3));
                const int q = ks*4 + lg;
                #pragma unroll
                for (int ni = 0; ni < 2; ++ni) {
                    if (ni < ncnt) {
                        int row = (ntb + ni)*16 + pbase + k; row = row > 41 ? 41 : row;
                        bf16x8 bfv = *(const bf16x8*)(p2T + row*128 + ((q ^ (row&15))<<3));
                        acc[ni] = __builtin_amdgcn_mfma_f32_16x16x32_bf16(af, bfv, acc[ni], 0,0,0);
                    }
                }
            }
        }
        float g3v[4], b3v[4];
        #pragma unroll
        for (int r = 0; r < 4; ++r) {
            int o = ot*16 + lg*4 + r;
            g3v[r] = g3[o]; b3v[r] = b3[o];
        }
        #pragma unroll
        for (int ni = 0; ni < 2; ++ni) if (ni < ncnt) {
            int p = (ntb + ni)*16 + pbase;
            bool valid = (p >= 0) && (p <= 34);
            float vv[4];
            #pragma unroll
            for (int r = 0; r < 4; ++r) {
                float v = frelu(acc[ni][r]*g3v[r] + b3v[r]);
                vv[r] = valid ? v : -3.0e38f;
            }
            float pv[4];
            #pragma unroll
            for (int r = 0; r < 4; ++r) pv[r] = fmaxf(vv[r], __shfl_xor(vv[r], 8));
            int q = (ntb + ni)*8 + (lr & 7);
            if ((lr >> 3) == 0 && q < 18) {
                #pragma unroll
                for (int r = 0; r < 4; ++r)
                    astage[(ot*16 + lg*4 + r)*18 + q] = F2B(pv[r]);
            }
        }
    }
    __syncthreads();

    for (int idx = t; idx < 576; idx += 256)
        aflatG[(size_t)s*576 + idx] = astage[idx];
}

// ============ K1b: map2 GEMM (validated) ============
__global__ __launch_bounds__(256) void k_map2(const unsigned short* __restrict__ aflatG,
    const unsigned short* __restrict__ m2wbT,
    const float* __restrict__ m2b, const float* __restrict__ m2g, const float* __restrict__ m2bb,
    float* __restrict__ a2)
{
    const int t = threadIdx.x, wv = t>>6, l = t&63, lg = l>>4, lr = l&15;
    const int s0 = blockIdx.x*64;
    f32x4 acc[8] = {};
    for (int ks = 0; ks < 18; ++ks) {
        bf16x8 a = *(const bf16x8*)(aflatG + (size_t)(s0 + wv*16 + lr)*576 + ks*32 + lg*8);
        #pragma unroll
        for (int nt = 0; nt < 8; ++nt) {
            bf16x8 b = *(const bf16x8*)(m2wbT + (size_t)(nt*16 + lr)*576 + ks*32 + lg*8);
            acc[nt] = __builtin_amdgcn_mfma_f32_16x16x32_bf16(a, b, acc[nt], 0,0,0);
        }
    }
    #pragma unroll
    for (int nt = 0; nt < 8; ++nt)
        #pragma unroll
        for (int r = 0; r < 4; ++r) {
            int s2 = s0 + wv*16 + lg*4 + r;
            int j = nt*16 + lr;
            a2[(size_t)s2*128 + j] = (acc[nt][r] + m2b[j]) * m2g[j] + m2bb[j];
        }
}

// ===== K2: build X + PE (validated r6) =====
__global__ __launch_bounds__(256) void k_buildx(const float* __restrict__ a2, float* __restrict__ X)
{
    __shared__ double dvt[64];
    const int t = threadIdx.x;
    if (t < 64) dvt[t] = exp((double)(2*t) * (-9.210340371976184/128.0));
    __syncthreads();
    int e = blockIdx.x*256 + t;
    int b = e >> 17;
    int r = e & 131071;
    int i = r >> 7, d = r & 127;
    int row = b*1024 + (d & 7)*128 + (i >> 3);
    int col = (i & 7)*16 + (d >> 3);
    float v = a2[row*128 + col];
    int per = b*1024 + (i & 7)*128 + d;
    int pc  = i >> 3;
    double ang = (double)per * dvt[pc >> 1];
    const double TWO_PI = 6.283185307179586476925287;
    double kk = floor(ang * (1.0/TWO_PI) + 0.5);
    float red = (float)(ang - kk * TWO_PI);
    float pe = (pc & 1) ? __cosf(red) : __sinf(red);
    X[e] = v + pe;
}

// ===== K3: H = X @ gw + gb -> bf16 hi/lo (validated) =====
__global__ __launch_bounds__(256) void k_hmat(const float* __restrict__ X,
    const float* __restrict__ g1w, const float* __restrict__ g1b,
    const float* __restrict__ g2w, const float* __restrict__ g2b,
    unsigned short* __restrict__ Hbhi1, unsigned short* __restrict__ Hblo1,
    unsigned short* __restrict__ Hbhi2, unsigned short* __restrict__ Hblo2)
{
    const int br = blockIdx.y;
    const float* gw = br ? g2w : g1w;
    const float* gb = br ? g2b : g1b;
    unsigned short* Hh = br ? Hbhi2 : Hbhi1;
    unsigned short* Hl = br ? Hblo2 : Hblo1;
    int e = blockIdx.x*256 + threadIdx.x;
    int srow = e >> 7, j = e & 127;
    const float* xr = X + (size_t)srow*128;
    float acc = gb[j];
    for (int k = 0; k < 128; ++k) acc += xr[k] * gw[k*128 + j];
    unsigned short hh = f2bf(acc);
    Hh[e] = hh;
    Hl[e] = f2bf(acc - bf2f(hh));
}

// ===== K4: S = lrelu(H H^T - 1e8*I) via bf16 hi/lo MFMA (validated r6) =====
__global__ __launch_bounds__(256) void k_scores(
    const unsigned short* __restrict__ Hbhi, const unsigned short* __restrict__ Hblo,
    float* __restrict__ S)
{
    __shared__ __align__(16) unsigned short HiH[64*64];
    __shared__ __align__(16) unsigned short HiL[64*64];
    __shared__ __align__(16) unsigned short HjH[64*64];
    __shared__ __align__(16) unsigned short HjL[64*64];
    const int b = blockIdx.z;
    const int i0 = blockIdx.y * 64, j0 = blockIdx.x * 64;
    const int t = threadIdx.x;
    const int w = t >> 6, l = t & 63, lr = l & 15, h = l >> 4;
    const size_t hb = (size_t)b * 1024 * 128;

    f32x4 acc[4] = {};
    for (int kh = 0; kh < 2; ++kh) {
        __syncthreads();
        #pragma unroll
        for (int it = 0; it < 4; ++it) {
            int g = it*256 + t;
            int mat = g >> 9;
            int gg = g & 511;
            int row = gg >> 3, ch = gg & 7;
            int base0 = mat ? j0 : i0;
            size_t src = hb + (size_t)(base0 + row)*128 + kh*64 + ch*8;
            uint4 vh = *(const uint4*)(Hbhi + src);
            uint4 vl = *(const uint4*)(Hblo + src);
            int sw = ch ^ (row & 7);
            unsigned short* dh = (mat ? HjH : HiH) + row*64 + sw*8;
            unsigned short* dl = (mat ? HjL : HiL) + row*64 + sw*8;
            *(uint4*)dh = vh;
            *(uint4*)dl = vl;
        }
        __syncthreads();
        #pragma unroll
        for (int kc = 0; kc < 2; ++kc) {
            int swA = (((kc*4 + h) ^ (lr & 7)) << 3);
            bf16x8 ah = *(const bf16x8*)&HiH[(w*16 + lr)*64 + swA];
            bf16x8 al = *(const bf16x8*)&HiL[(w*16 + lr)*64 + swA];
            #pragma unroll
            for (int jt = 0; jt < 4; ++jt) {
                bf16x8 bh = *(const bf16x8*)&HjH[(jt*16 + lr)*64 + swA];
                bf16x8 bl = *(const bf16x8*)&HjL[(jt*16 + lr)*64 + swA];
                acc[jt] = __builtin_amdgcn_mfma_f32_16x16x32_bf16(ah, bh, acc[jt], 0,0,0);
                acc[jt] = __builtin_amdgcn_mfma_f32_16x16x32_bf16(ah, bl, acc[jt], 0,0,0);
                acc[jt] = __builtin_amdgcn_mfma_f32_16x16x32_bf16(al, bh, acc[jt], 0,0,0);
            }
        }
    }
    float* Sb = S + (size_t)b*1024*1024;
    #pragma unroll
    for (int jt = 0; jt < 4; ++jt) {
        #pragma unroll
        for (int r = 0; r < 4; ++r) {
            int i = i0 + w*16 + h*4 + r;
            int j = j0 + jt*16 + lr;
            float x = acc[jt][r];
            if (i == j) x -= 1e8f;
            Sb[(size_t)i*1024 + j] = lrelu(x);
        }
    }
}

// ===== K5: row stats (validated r8) =====
__global__ __launch_bounds__(256) void k_rowstat(const float* __restrict__ S,
                                                 float* __restrict__ mrow, float* __restrict__ linv)
{
    __shared__ float red[256];
    const int b = blockIdx.y, i = blockIdx.x, t = threadIdx.x;
    const float* row = S + (size_t)b*1024*1024 + (size_t)i*1024;
    float4 v = *(const float4*)&row[t*4];
    float mx = fmaxf(fmaxf(v.x,v.y), fmaxf(v.z,v.w));
    red[t] = mx; __syncthreads();
    for (int s2 = 128; s2 > 0; s2 >>= 1) { if (t < s2) red[t] = fmaxf(red[t], red[t+s2]); __syncthreads(); }
    mx = red[0]; __syncthreads();
    float e = (__expf(v.x-mx) + __expf(v.y-mx)) + (__expf(v.z-mx) + __expf(v.w-mx));
    red[t] = e; __syncthreads();
    for (int s2 = 128; s2 > 0; s2 >>= 1) { if (t < s2) red[t] += red[t+s2]; __syncthreads(); }
    if (t == 0) { mrow[b*1024 + i] = mx; linv[b*1024 + i] = 1.f / red[0]; }
}

// ===== K5b: Xbb transpose -> XbbT hi/lo (validated r9) =====
__global__ __launch_bounds__(256) void k_xbbt(const float* __restrict__ X,
    const float* __restrict__ bng1, const float* __restrict__ bnb1,
    const float* __restrict__ bng2, const float* __restrict__ bnb2,
    unsigned short* __restrict__ XbbThi, unsigned short* __restrict__ XbbTlo)
{
    __shared__ float Xl[64][132];
    const int t = threadIdx.x;
    const int j0 = blockIdx.x*64, b = blockIdx.y, br = blockIdx.z;
    {
        int r2 = t >> 2, dseg = (t & 3)*32;
        const float* src = X + ((size_t)(b*1024 + j0 + r2))*128 + dseg;
        #pragma unroll
        for (int q = 0; q < 8; ++q) {
            float4 v = *(const float4*)(src + q*4);
            Xl[r2][dseg + q*4 + 0] = v.x;
            Xl[r2][dseg + q*4 + 1] = v.y;
            Xl[r2][dseg + q*4 + 2] = v.z;
            Xl[r2][dseg + q*4 + 3] = v.w;
        }
    }
    __syncthreads();
    const int d = t >> 1, seg = t & 1;
    const float g  = (br ? bng2 : bng1)[d];
    const float bb = (br ? bnb2 : bnb1)[d];
    unsigned short* dsth = XbbThi + (size_t)br*524288 + ((size_t)(b*128 + d))*1024 + j0 + seg*32;
    unsigned short* dstl = XbbTlo + (size_t)br*524288 + ((size_t)(b*128 + d))*1024 + j0 + seg*32;
    #pragma unroll
    for (int g8 = 0; g8 < 4; ++g8) {
        unsigned int hu[4], lu[4];
        #pragma unroll
        for (int q = 0; q < 4; ++q) {
            float v0 = Xl[seg*32 + g8*8 + 2*q    ][d]*g + bb;
            float v1 = Xl[seg*32 + g8*8 + 2*q + 1][d]*g + bb;
            unsigned short h0 = f2bf(v0), h1 = f2bf(v1);
            hu[q] = (unsigned int)h0 | ((unsigned int)h1 << 16);
            lu[q] = (unsigned int)f2bf(v0 - bf2f(h0)) | ((unsigned int)f2bf(v1 - bf2f(h1)) << 16);
        }
        *(uint4*)(dsth + g8*8) = make_uint4(hu[0],hu[1],hu[2],hu[3]);
        *(uint4*)(dstl + g8*8) = make_uint4(lu[0],lu[1],lu[2],lu[3]);
    }
}

// ===== K6-MFMA: P = (softmax(S)+I) @ Xbb via hi/lo MFMA (validated r9) =====
__global__ __launch_bounds__(256) void k_pvmm(
    const float* __restrict__ S1, const float* __restrict__ S2, const float* __restrict__ X,
    const float* __restrict__ bng1, const float* __restrict__ bnb1,
    const float* __restrict__ bng2, const float* __restrict__ bnb2,
    const float* __restrict__ mrow, const float* __restrict__ linv,
    const unsigned short* __restrict__ XbbThi, const unsigned short* __restrict__ XbbTlo,
    float* __restrict__ P)
{
    __shared__ __align__(16) unsigned short ElH[16*64];
    __shared__ __align__(16) unsigned short ElL[16*64];
    const int t = threadIdx.x;
    const int w = t >> 6, l = t & 63, lr = l & 15, h = l >> 4;
    const int i0 = blockIdx.x * 16;
    const int b = blockIdx.y;
    const int br = blockIdx.z;
    const float* S = br ? S2 : S1;
    const float* bng = br ? bng2 : bng1;
    const float* bnb = br ? bnb2 : bnb1;
    const float* mr = mrow + br*4096 + b*1024;
    const float* lv = linv + br*4096 + b*1024;
    const unsigned short* Bh = XbbThi + (size_t)br*524288 + (size_t)b*131072;
    const unsigned short* Bl = XbbTlo + (size_t)br*524288 + (size_t)b*131072;

    const int srow = t >> 4, jseg = t & 15;
    const float mi = mr[i0 + srow];
    const int j0s = jseg*4;
    const int eoff = srow*64 + (((j0s>>3) ^ (srow&7))<<3) + (j0s&7);

    f32x4 acc[2] = {};
    for (int ch = 0; ch < 16; ++ch) {
        const int jb = ch*64;
        __syncthreads();
        {
            float4 sv = *(const float4*)(S + ((size_t)(b*1024 + i0 + srow))*1024 + jb + j0s);
            float e0 = __expf(sv.x - mi), e1 = __expf(sv.y - mi);
            float e2 = __expf(sv.z - mi), e3 = __expf(sv.w - mi);
            unsigned short h0 = f2bf(e0), h1 = f2bf(e1), h2 = f2bf(e2), h3 = f2bf(e3);
            uint2 vh, vl;
            vh.x = (unsigned int)h0 | ((unsigned int)h1 << 16);
            vh.y = (unsigned int)h2 | ((unsigned int)h3 << 16);
            vl.x = (unsigned int)f2bf(e0 - bf2f(h0)) | ((unsigned int)f2bf(e1 - bf2f(h1)) << 16);
            vl.y = (unsigned int)f2bf(e2 - bf2f(h2)) | ((unsigned int)f2bf(e3 - bf2f(h3)) << 16);
            *(uint2*)(ElH + eoff) = vh;
            *(uint2*)(ElL + eoff) = vl;
        }
        __syncthreads();
        #pragma unroll
        for (int kc = 0; kc < 2; ++kc) {
            int swA = (((kc*4 + h) ^ (lr & 7)) << 3);
            bf16x8 ah = *(const bf16x8*)&ElH[lr*64 + swA];
            bf16x8 al = *(const bf16x8*)&ElL[lr*64 + swA];
            #pragma unroll
            for (int n2 = 0; n2 < 2; ++n2) {
                int nt = w*2 + n2;
                size_t boff = (size_t)(nt*16 + lr)*1024 + jb + kc*32 + h*8;
                bf16x8 bh = *(const bf16x8*)(Bh + boff);
                bf16x8 bl = *(const bf16x8*)(Bl + boff);
                acc[n2] = __builtin_amdgcn_mfma_f32_16x16x32_bf16(ah, bh, acc[n2], 0,0,0);
                acc[n2] = __builtin_amdgcn_mfma_f32_16x16x32_bf16(ah, bl, acc[n2], 0,0,0);
                acc[n2] = __builtin_amdgcn_mfma_f32_16x16x32_bf16(al, bh, acc[n2], 0,0,0);
            }
        }
    }
    #pragma unroll
    for (int r = 0; r < 4; ++r) {
        int i = i0 + h*4 + r;
        float inv = lv[i];
        #pragma unroll
        for (int n2 = 0; n2 < 2; ++n2) {
            int d = (w*2 + n2)*16 + lr;
            float xv = X[((size_t)(b*1024 + i))*128 + d] * bng[d] + bnb[d];
            P[((size_t)(br*4096 + b*1024 + i))*128 + d] = acc[n2][r]*inv + xv;
        }
    }
}

// ===== K6-fallback: f32 PV (validated r8) =====
__global__ __launch_bounds__(256) void k_pv(const float* __restrict__ S, const float* __restrict__ X,
                                            const float* __restrict__ bng, const float* __restrict__ bnb,
                                            const float* __restrict__ mrowG, const float* __restrict__ linvG,
                                            float* __restrict__ P)
{
    __shared__ __align__(16) float Sl[16*65];
    __shared__ __align__(16) float Xl[64*132];
    const int b = blockIdx.y, i0 = blockIdx.x*16, t = threadIdx.x;
    const int il = t >> 4, dg = t & 15;
    const int sj = t & 63, sil = t >> 6;
    const int xd = t & 127, xj = t >> 7;
    const float bg = bng[xd], bb = bnb[xd];
    float mr[4];
    #pragma unroll
    for (int m2 = 0; m2 < 4; ++m2) mr[m2] = mrowG[b*1024 + i0 + sil*4 + m2];
    float acc[8] = {};
    const float* Sb = S + (size_t)b*1024*1024;
    const float* Xb = X + (size_t)b*1024*128;
    for (int c = 0; c < 16; ++c) {
        int jb = c*64;
        __syncthreads();
        #pragma unroll
        for (int m2 = 0; m2 < 4; ++m2) {
            int r2 = sil*4 + m2;
            Sl[r2*65 + sj] = __expf(Sb[(size_t)(i0+r2)*1024 + jb + sj] - mr[m2]);
        }
        #pragma unroll
        for (int m2 = 0; m2 < 32; ++m2) {
            int jc = xj + 2*m2;
            Xl[jc*132 + xd] = Xb[(size_t)(jb+jc)*128 + xd] * bg + bb;
        }
        __syncthreads();
        for (int jc = 0; jc < 64; ++jc) {
            float sv = Sl[il*65 + jc];
            float4 x0 = *(const float4*)&Xl[jc*132 + dg*8];
            float4 x1 = *(const float4*)&Xl[jc*132 + dg*8 + 4];
            acc[0] += sv*x0.x; acc[1] += sv*x0.y; acc[2] += sv*x0.z; acc[3] += sv*x0.w;
            acc[4] += sv*x1.x; acc[5] += sv*x1.y; acc[6] += sv*x1.z; acc[7] += sv*x1.w;
        }
    }
    int i = i0 + il;
    float inv = linvG[b*1024 + i];
    const float* xr = Xb + (size_t)i*128 + dg*8;
    float* pr = P + (size_t)(b*1024 + i)*128 + dg*8;
    #pragma unroll
    for (int z = 0; z < 8; ++z) {
        float xv = xr[z] * bng[dg*8+z] + bnb[dg*8+z];
        pr[z] = acc[z]*inv + xv;
    }
}

// ===== K7: tproj single-branch (validated) =====
__global__ __launch_bounds__(256) void k_tproj(const float* __restrict__ P, const float* __restrict__ tw,
                                               const float* __restrict__ tb, float* __restrict__ O)
{
    int idx = blockIdx.x*256 + threadIdx.x;
    int srow = idx >> 6, e = idx & 63;
    const float* pr = P + (size_t)srow*128;
    float acc = tb[e];
    for (int d = 0; d < 128; ++d) acc += pr[d] * tw[d*64 + e];
    O[idx] = lrelu(acc);
}

// ===== K7b: tproj dual-branch (validated r9) =====
__global__ __launch_bounds__(256) void k_tproj2(const float* __restrict__ P,
    const float* __restrict__ t1w, const float* __restrict__ t1b,
    const float* __restrict__ t2w, const float* __restrict__ t2b,
    float* __restrict__ O)
{
    int idx = blockIdx.x*256 + threadIdx.x;
    int srow = idx >> 6, e = idx & 63;
    int br = srow >> 12;
    const float* tw = br ? t2w : t1w;
    const float* tb = br ? t2b : t1b;
    const float* pr = P + (size_t)srow*128;
    float acc = tb[e];
    for (int d = 0; d < 128; ++d) acc += pr[d] * tw[d*64 + e];
    O[idx] = lrelu(acc);
}

// ===== K8: fc1 partial sums (validated) =====
__global__ __launch_bounds__(256) void k_fc1(const float* __restrict__ O1, const float* __restrict__ O2,
                                             const float* __restrict__ w, float* __restrict__ pbuf)
{
    __shared__ float red[4*512];
    const int t = threadIdx.x;
    const int wv = t >> 6, l = t & 63;
    const int gwid = blockIdx.x*4 + wv;
    float acc[4][2] = {};
    int base = gwid*64;
    for (int tt = 0; tt < 64; ++tt) {
        int row = base + tt;
        float2 wvv = *(const float2*)&w[(size_t)row*128 + l*2];
        #pragma unroll
        for (int b = 0; b < 4; ++b) {
            float fb = (row < 65536) ? O1[b*65536 + row] : O2[b*65536 + row - 65536];
            acc[b][0] += fb * wvv.x;
            acc[b][1] += fb * wvv.y;
        }
    }
    #pragma unroll
    for (int b = 0; b < 4; ++b) {
        red[wv*512 + b*128 + l*2]   = acc[b][0];
        red[wv*512 + b*128 + l*2+1] = acc[b][1];
    }
    __syncthreads();
    for (int rep = 0; rep < 2; ++rep) {
        int col = rep*256 + t;
        pbuf[(size_t)blockIdx.x*512 + col] = red[col] + red[512+col] + red[1024+col] + red[1536+col];
    }
}

// ===== K8b: reduce fc1 partials (validated) =====
__global__ __launch_bounds__(256) void k_red(const float* __restrict__ pbuf, float* __restrict__ pbuf2)
{
    int col = blockIdx.x*8 + (threadIdx.x >> 5);
    int lane = threadIdx.x & 31;
    float acc = 0.f;
    for (int it = 0; it < 16; ++it)
        acc += pbuf[(size_t)(lane + it*32)*512 + col];
    #pragma unroll
    for (int s2 = 16; s2 >= 1; s2 >>= 1) acc += __shfl_xor(acc, s2, 32);
    if (lane == 0) pbuf2[col] = acc;
}

// ===== K9: MLP head (validated) =====
__global__ __launch_bounds__(256) void k_head2(const float* __restrict__ pbuf2,
    const float* __restrict__ fc1b, const float* __restrict__ fc2w, const float* __restrict__ fc2b,
    const float* __restrict__ fc3w, const float* __restrict__ fc3b,
    const float* __restrict__ fc4w, const float* __restrict__ fc4b,
    float* __restrict__ out)
{
    __shared__ float r1[512], r2[512], r3[256];
    const int t = threadIdx.x;
    for (int rep = 0; rep < 2; ++rep) {
        int idx = rep*256 + t;
        r1[idx] = frelu(pbuf2[idx] + fc1b[idx & 127]);
    }
    __syncthreads();
    for (int rep = 0; rep < 2; ++rep) {
        int idx = rep*256 + t;
        int b = idx >> 7, j = idx & 127;
        float acc = fc2b[j];
        for (int k = 0; k < 128; ++k) acc += r1[b*128+k]*fc2w[k*128+j];
        r2[idx] = frelu(acc);
    }
    __syncthreads();
    {
        int b = t >> 6, e2 = t & 63;
        float acc = fc3b[e2];
        for (int k = 0; k < 128; ++k) acc += r2[b*128+k]*fc3w[k*64+e2];
        r3[t] = frelu(acc);
    }
    __syncthreads();
    if (t < 24) {
        int b = t/6, c = t%6;
        float acc = fc4b[c];
        for (int k = 0; k < 64; ++k) acc += r3[b*64+k]*fc4w[k*6+c];
        out[b*6+c] = acc;
    }
}

extern "C" void kernel_launch(void* const* d_in, const int* in_sizes, int n_in,
                              void* d_out, int out_size, void* d_ws, size_t ws_size,
                              hipStream_t stream)
{
    (void)in_sizes; (void)n_in; (void)out_size;
    const float* xenc = (const float*)d_in[0];
    const float* w1   = (const float*)d_in[4];
    const float* g1   = (const float*)d_in[5];
    const float* b1   = (const float*)d_in[6];
    const float* w2   = (const float*)d_in[7];
    const float* g2   = (const float*)d_in[8];
    const float* b2   = (const float*)d_in[9];
    const float* w3   = (const float*)d_in[10];
    const float* g3   = (const float*)d_in[11];
    const float* b3   = (const float*)d_in[12];
    const float* m2w  = (const float*)d_in[13];
    const float* m2b  = (const float*)d_in[14];
    const float* m2g  = (const float*)d_in[15];
    const float* m2bb = (const float*)d_in[16];
    const float* g1w  = (const float*)d_in[17];
    const float* g1b  = (const float*)d_in[18];
    const float* m1g  = (const float*)d_in[19];
    const float* m1b  = (const float*)d_in[20];
    const float* t1w  = (const float*)d_in[21];
    const float* t1b  = (const float*)d_in[22];
    const float* g2w  = (const float*)d_in[23];
    const float* g2bv = (const float*)d_in[24];
    const float* mm2g = (const float*)d_in[25];
    const float* mm2b = (const float*)d_in[26];
    const float* t2w  = (const float*)d_in[27];
    const float* t2b  = (const float*)d_in[28];
    const float* fc1w = (const float*)d_in[29];
    const float* fc1b = (const float*)d_in[30];
    const float* fc2w = (const float*)d_in[31];
    const float* fc2b = (const float*)d_in[32];
    const float* fc3w = (const float*)d_in[33];
    const float* fc3b = (const float*)d_in[34];
    const float* fc4w = (const float*)d_in[35];
    const float* fc4b = (const float*)d_in[36];

    char* ws = (char*)d_ws;
    float* a2   = (float*)(ws);
    float* X    = (float*)(ws + (2u<<20));
    unsigned short* Hbhi1 = (unsigned short*)(ws + (4u<<20));
    unsigned short* Hblo1 = (unsigned short*)(ws + (5u<<20));
    unsigned short* Hbhi2 = (unsigned short*)(ws);
    unsigned short* Hblo2 = (unsigned short*)(ws + (1u<<20));
    float* S1   = (float*)(ws + (6u<<20));
    unsigned short* aflatG = (unsigned short*)(ws + (6u<<20));
    unsigned short* w2s    = (unsigned short*)(ws + (6u<<20) + 5242880);
    unsigned short* w3s    = (unsigned short*)(ws + (6u<<20) + 5242880 + 131072);
    unsigned short* m2wbT  = (unsigned short*)(ws + (6u<<20) + 5242880 + 196608);
    float* pbuf2 = (float*)(ws + (6u<<20));

    k_prep<<<288, 256, 0, stream>>>(w2, w3, m2w, w2s, w3s, m2wbT);
    k_conv<<<4096, 256, 0, stream>>>(xenc, w1,g1,b1, w2s,g2,b2, w3s,g3,b3, aflatG);
    k_map2<<<64, 256, 0, stream>>>(aflatG, m2wbT, m2b, m2g, m2bb, a2);
    k_buildx<<<2048, 256, 0, stream>>>(a2, X);
    k_hmat<<<dim3(2048,2), 256, 0, stream>>>(X, g1w, g1b, g2w, g2bv,
                                             Hbhi1, Hblo1, Hbhi2, Hblo2);

    if (ws_size >= ((size_t)49 << 20)) {
        float* S2   = (float*)(ws + (22u<<20));
        float* P    = (float*)(ws + (38u<<20));
        float* O    = (float*)(ws + (42u<<20));
        float* pbuf = (float*)(ws + (44u<<20));
        float* mrow = (float*)(ws + (44u<<20));
        float* linv = (float*)(ws + (44u<<20) + 65536);
        unsigned short* XbbThi = (unsigned short*)(ws + (45u<<20));
        unsigned short* XbbTlo = (unsigned short*)(ws + (47u<<20));
        float* O1 = O;
        float* O2 = O + 262144;

        k_xbbt<<<dim3(16,4,2), 256, 0, stream>>>(X, m1g, m1b, mm2g, mm2b, XbbThi, XbbTlo);
        k_scores <<<dim3(16,16,4), 256, 0, stream>>>(Hbhi1, Hblo1, S1);
        k_scores <<<dim3(16,16,4), 256, 0, stream>>>(Hbhi2, Hblo2, S2);
        k_rowstat<<<dim3(1024,4), 256, 0, stream>>>(S1, mrow, linv);
        k_rowstat<<<dim3(1024,4), 256, 0, stream>>>(S2, mrow + 4096, linv + 4096);
        k_pvmm<<<dim3(64,4,2), 256, 0, stream>>>(S1, S2, X, m1g, m1b, mm2g, mm2b,
                                                 mrow, linv, XbbThi, XbbTlo, P);
        k_tproj2<<<2048, 256, 0, stream>>>(P, t1w, t1b, t2w, t2b, O);
        k_fc1 <<<512, 256, 0, stream>>>(O1, O2, fc1w, pbuf);
        k_red <<<64, 256, 0, stream>>>(pbuf, pbuf2);
        k_head2<<<1, 256, 0, stream>>>(pbuf2, fc1b, fc2w, fc2b, fc3w, fc3b, fc4w, fc4b, (float*)d_out);
    } else {
        float* P    = (float*)(ws + (22u<<20));
        float* O1   = (float*)(ws + (24u<<20));
        float* O2   = (float*)(ws + (25u<<20));
        float* pbuf = (float*)(ws + (26u<<20));
        float* mrow = (float*)(ws + (26u<<20));
        float* linv = (float*)(ws + (26u<<20) + 65536);

        k_scores <<<dim3(16,16,4), 256, 0, stream>>>(Hbhi1, Hblo1, S1);
        k_rowstat<<<dim3(1024,4), 256, 0, stream>>>(S1, mrow, linv);
        k_pv     <<<dim3(64,4), 256, 0, stream>>>(S1, X, m1g, m1b, mrow, linv, P);
        k_tproj  <<<1024, 256, 0, stream>>>(P, t1w, t1b, O1);
        k_scores <<<dim3(16,16,4), 256, 0, stream>>>(Hbhi2, Hblo2, S1);
        k_rowstat<<<dim3(1024,4), 256, 0, stream>>>(S1, mrow, linv);
        k_pv     <<<dim3(64,4), 256, 0, stream>>>(S1, X, mm2g, mm2b, mrow, linv, P);
        k_tproj  <<<1024, 256, 0, stream>>>(P, t2w, t2b, O2);
        k_fc1 <<<512, 256, 0, stream>>>(O1, O2, fc1w, pbuf);
        k_red <<<64, 256, 0, stream>>>(pbuf, pbuf2);
        k_head2<<<1, 256, 0, stream>>>(pbuf2, fc1b, fc2w, fc2b, fc3w, fc3b, fc4w, fc4b, (float*)d_out);
    }
}

// Round 11
// 262.614 us; speedup vs baseline: 2.3882x; 1.0625x over previous
//
#include <hip/hip_runtime.h>
#include <hip/hip_bf16.h>
#include <math.h>

#define NEG 0.01f
__device__ __forceinline__ float lrelu(float v){ return v > 0.f ? v : NEG*v; }
__device__ __forceinline__ float frelu(float v){ return v > 0.f ? v : 0.f; }

typedef __attribute__((ext_vector_type(8))) short bf16x8;
typedef __attribute__((ext_vector_type(4))) float f32x4;

__device__ __forceinline__ unsigned short f2bf(float x){
    unsigned int u = __float_as_uint(x);
    unsigned int r = (u + 0x7FFFu + ((u>>16)&1u)) >> 16;
    return (unsigned short)r;
}
__device__ __forceinline__ float bf2f(unsigned short h){
    return __uint_as_float(((unsigned int)h) << 16);
}
__device__ __forceinline__ unsigned short F2B(float x){
    __hip_bfloat16 h = __float2bfloat16(x);
    return *reinterpret_cast<unsigned short*>(&h);
}

// ============ K0: weight repack (+ twT hi/lo) ============
__global__ __launch_bounds__(256) void k_prep(const float* __restrict__ w2, const float* __restrict__ w3,
    const float* __restrict__ m2w, const float* __restrict__ t1w, const float* __restrict__ t2w,
    unsigned short* __restrict__ w2s, unsigned short* __restrict__ w3s, unsigned short* __restrict__ m2wbT,
    unsigned short* __restrict__ twThi, unsigned short* __restrict__ twTlo)
{
    int gid = blockIdx.x*256 + threadIdx.x;
    if (gid < 73728) {
        int j = gid / 576, f = gid % 576;
        m2wbT[gid] = f2bf(m2w[f*128 + j]);
    }
    if (gid < 65536) {
        int jj = gid & 7, q = (gid>>3)&3, o = (gid>>5)&127, ks = (gid>>12)&1, k = gid>>13;
        int c = ks*32 + q*8 + jj;
        w2s[gid] = f2bf(w2[o*512 + c*8 + k]);
    }
    if (gid < 32768) {
        int jj = gid & 7, q = (gid>>3)&3, o = (gid>>5)&31, ks = (gid>>10)&3, k = gid>>12;
        int c = ks*32 + q*8 + jj;
        w3s[gid] = f2bf(w3[o*1024 + c*8 + k]);
    }
    if (gid < 16384) {   // twT: gid = (br*64+e)*128 + d
        int d = gid & 127, e = (gid>>7)&63, br = gid>>13;
        float x = (br ? t2w : t1w)[d*64 + e];
        unsigned short hh = f2bf(x);
        twThi[gid] = hh;
        twTlo[gid] = f2bf(x - bf2f(hh));
    }
}

// ============ K1: fused conv stack (validated r10, unchanged) ============
__global__ __launch_bounds__(256) void k_conv(
    const float* __restrict__ xenc,
    const float* __restrict__ w1, const float* __restrict__ g1, const float* __restrict__ b1,
    const unsigned short* __restrict__ w2s, const float* __restrict__ g2, const float* __restrict__ b2,
    const unsigned short* __restrict__ w3s, const float* __restrict__ g3, const float* __restrict__ b3,
    unsigned short* __restrict__ aflatG)
{
    __shared__ __align__(16) unsigned char smraw[22208];
    float* sigp = (float*)smraw;
    unsigned short* p1T = (unsigned short*)(smraw + 576);
    unsigned short* p2T = (unsigned short*)(smraw + 10304);
    unsigned short* astage = (unsigned short*)(smraw + 21056);

    const int t = threadIdx.x;
    const int s = blockIdx.x;

    {
        unsigned int* zz = (unsigned int*)(smraw + 576);
        for (int i = t; i < 5120; i += 256) zz[i] = 0u;
        if (t < 144) sigp[t] = 0.f;
    }
    __syncthreads();
    if (t < 128) sigp[4 + t] = xenc[(size_t)s*128 + t];
    __syncthreads();

    {   // conv1 f32 sliding window + pool -> p1T
        const int c = t & 63, qg = t >> 6;
        float wr[8];
        #pragma unroll
        for (int k = 0; k < 8; ++k) wr[k] = w1[c*8 + k];
        const float g = g1[c], b = b1[c];
        const int qs = qg*17;
        float win[9];
        {
            int base = 2*qs - 1;
            #pragma unroll
            for (int x = 0; x < 9; ++x) win[x] = (base + x >= 0) ? sigp[base + x] : 0.f;
        }
        #pragma unroll
        for (int j = 0; j < 17; ++j) {
            int q = qs + j;
            float s0 = 0.f, s1 = 0.f;
            #pragma unroll
            for (int k = 0; k < 8; ++k) { s0 += win[k]*wr[k]; s1 += win[k+1]*wr[k]; }
            float v = frelu(s1*g + b);
            if (q > 0) v = fmaxf(v, frelu(s0*g + b));
            if (q < 65) {
                int row = q + 4;
                p1T[row*64 + (((c>>3) ^ (row&7))<<3) + (c&7)] = F2B(v);
            }
            #pragma unroll
            for (int x = 0; x < 7; ++x) win[x] = win[x+2];
            win[7] = sigp[2*q + 8];
            win[8] = sigp[2*q + 9];
        }
    }
    __syncthreads();

    {   // conv2 MFMA + fused bn/relu/pool2 -> p2T
        const int wv = t >> 6, l = t & 63, lg = l >> 4, lr = l & 15;
        const int pbase = ((lr & 7) << 1) + (lr >> 3) - 1;
        f32x4 acc[2][5] = {};
        for (int k = 0; k < 8; ++k) {
            for (int ks = 0; ks < 2; ++ks) {
                bf16x8 af[2];
                #pragma unroll
                for (int oi = 0; oi < 2; ++oi) {
                    int o = (wv*2 + oi)*16 + lr;
                    af[oi] = *(const bf16x8*)(w2s + ((((k*2 + ks)*128 + o)*4 + lg)<<3));
                }
                const int q = ks*4 + lg;
                #pragma unroll
                for (int nt = 0; nt < 5; ++nt) {
                    int row = nt*16 + pbase + k; row = row > 75 ? 75 : row;
                    bf16x8 bfv = *(const bf16x8*)(p1T + row*64 + ((q ^ (row&7))<<3));
                    acc[0][nt] = __builtin_amdgcn_mfma_f32_16x16x32_bf16(af[0], bfv, acc[0][nt], 0,0,0);
                    acc[1][nt] = __builtin_amdgcn_mfma_f32_16x16x32_bf16(af[1], bfv, acc[1][nt], 0,0,0);
                }
            }
        }
        float ga[2][4], ba[2][4];
        #pragma unroll
        for (int oi = 0; oi < 2; ++oi)
            #pragma unroll
            for (int r = 0; r < 4; ++r) {
                int o = (wv*2 + oi)*16 + lg*4 + r;
                ga[oi][r] = g2[o]; ba[oi][r] = b2[o];
            }
        #pragma unroll
        for (int oi = 0; oi < 2; ++oi)
            #pragma unroll
            for (int nt = 0; nt < 5; ++nt) {
                int p = nt*16 + pbase;
                bool valid = (p >= 0) && (p <= 65);
                float vv[4];
                #pragma unroll
                for (int r = 0; r < 4; ++r) {
                    float v = frelu(acc[oi][nt][r]*ga[oi][r] + ba[oi][r]);
                    vv[r] = valid ? v : -3.0e38f;
                }
                float pv[4];
                #pragma unroll
                for (int r = 0; r < 4; ++r) pv[r] = fmaxf(vv[r], __shfl_xor(vv[r], 8));
                int q = nt*8 + (lr & 7);
                if ((lr >> 3) == 0 && q < 34) {
                    int row2 = q + 4;
                    int o0 = (wv*2 + oi)*16 + lg*4;
                    uint2 pk;
                    pk.x = (unsigned int)F2B(pv[0]) | ((unsigned int)F2B(pv[1]) << 16);
                    pk.y = (unsigned int)F2B(pv[2]) | ((unsigned int)F2B(pv[3]) << 16);
                    *(uint2*)&p2T[row2*128 + (((o0>>3) ^ (row2&15))<<3) + (o0&7)] = pk;
                }
            }
    }
    __syncthreads();

    {   // conv3 MFMA + fused bn/relu/pool3 -> astage
        const int wv = t >> 6, l = t & 63, lg = l >> 4, lr = l & 15;
        const int ot = wv & 1, ntb = (wv >> 1) * 2;
        const int ncnt = (wv < 2) ? 2 : 1;
        const int pbase = ((lr & 7) << 1) + (lr >> 3) - 1;
        f32x4 acc[2] = {};
        for (int k = 0; k < 8; ++k) {
            for (int ks = 0; ks < 4; ++ks) {
                int o = ot*16 + lr;
                bf16x8 af = *(const bf16x8*)(w3s + ((((k*4 + ks)*32 + o)*4 + lg)<<3));
                const int q = ks*4 + lg;
                #pragma unroll
                for (int ni = 0; ni < 2; ++ni) {
                    if (ni < ncnt) {
                        int row = (ntb + ni)*16 + pbase + k; row = row > 41 ? 41 : row;
                        bf16x8 bfv = *(const bf16x8*)(p2T + row*128 + ((q ^ (row&15))<<3));
                        acc[ni] = __builtin_amdgcn_mfma_f32_16x16x32_bf16(af, bfv, acc[ni], 0,0,0);
                    }
                }
            }
        }
        float g3v[4], b3v[4];
        #pragma unroll
        for (int r = 0; r < 4; ++r) {
            int o = ot*16 + lg*4 + r;
            g3v[r] = g3[o]; b3v[r] = b3[o];
        }
        #pragma unroll
        for (int ni = 0; ni < 2; ++ni) if (ni < ncnt) {
            int p = (ntb + ni)*16 + pbase;
            bool valid = (p >= 0) && (p <= 34);
            float vv[4];
            #pragma unroll
            for (int r = 0; r < 4; ++r) {
                float v = frelu(acc[ni][r]*g3v[r] + b3v[r]);
                vv[r] = valid ? v : -3.0e38f;
            }
            float pv[4];
            #pragma unroll
            for (int r = 0; r < 4; ++r) pv[r] = fmaxf(vv[r], __shfl_xor(vv[r], 8));
            int q = (ntb + ni)*8 + (lr & 7);
            if ((lr >> 3) == 0 && q < 18) {
                #pragma unroll
                for (int r = 0; r < 4; ++r)
                    astage[(ot*16 + lg*4 + r)*18 + q] = F2B(pv[r]);
            }
        }
    }
    __syncthreads();

    for (int idx = t; idx < 576; idx += 256)
        aflatG[(size_t)s*576 + idx] = astage[idx];
}

// ============ K1b: map2 GEMM (validated) ============
__global__ __launch_bounds__(256) void k_map2(const unsigned short* __restrict__ aflatG,
    const unsigned short* __restrict__ m2wbT,
    const float* __restrict__ m2b, const float* __restrict__ m2g, const float* __restrict__ m2bb,
    float* __restrict__ a2)
{
    const int t = threadIdx.x, wv = t>>6, l = t&63, lg = l>>4, lr = l&15;
    const int s0 = blockIdx.x*64;
    f32x4 acc[8] = {};
    for (int ks = 0; ks < 18; ++ks) {
        bf16x8 a = *(const bf16x8*)(aflatG + (size_t)(s0 + wv*16 + lr)*576 + ks*32 + lg*8);
        #pragma unroll
        for (int nt = 0; nt < 8; ++nt) {
            bf16x8 b = *(const bf16x8*)(m2wbT + (size_t)(nt*16 + lr)*576 + ks*32 + lg*8);
            acc[nt] = __builtin_amdgcn_mfma_f32_16x16x32_bf16(a, b, acc[nt], 0,0,0);
        }
    }
    #pragma unroll
    for (int nt = 0; nt < 8; ++nt)
        #pragma unroll
        for (int r = 0; r < 4; ++r) {
            int s2 = s0 + wv*16 + lg*4 + r;
            int j = nt*16 + lr;
            a2[(size_t)s2*128 + j] = (acc[nt][r] + m2b[j]) * m2g[j] + m2bb[j];
        }
}

// ===== K2: build X + PE (validated r6) =====
__global__ __launch_bounds__(256) void k_buildx(const float* __restrict__ a2, float* __restrict__ X)
{
    __shared__ double dvt[64];
    const int t = threadIdx.x;
    if (t < 64) dvt[t] = exp((double)(2*t) * (-9.210340371976184/128.0));
    __syncthreads();
    int e = blockIdx.x*256 + t;
    int b = e >> 17;
    int r = e & 131071;
    int i = r >> 7, d = r & 127;
    int row = b*1024 + (d & 7)*128 + (i >> 3);
    int col = (i & 7)*16 + (d >> 3);
    float v = a2[row*128 + col];
    int per = b*1024 + (i & 7)*128 + d;
    int pc  = i >> 3;
    double ang = (double)per * dvt[pc >> 1];
    const double TWO_PI = 6.283185307179586476925287;
    double kk = floor(ang * (1.0/TWO_PI) + 0.5);
    float red = (float)(ang - kk * TWO_PI);
    float pe = (pc & 1) ? __cosf(red) : __sinf(red);
    X[e] = v + pe;
}

// ===== K3: H = X @ gw + gb -> bf16 hi/lo (validated) =====
__global__ __launch_bounds__(256) void k_hmat(const float* __restrict__ X,
    const float* __restrict__ g1w, const float* __restrict__ g1b,
    const float* __restrict__ g2w, const float* __restrict__ g2b,
    unsigned short* __restrict__ Hbhi1, unsigned short* __restrict__ Hblo1,
    unsigned short* __restrict__ Hbhi2, unsigned short* __restrict__ Hblo2)
{
    const int br = blockIdx.y;
    const float* gw = br ? g2w : g1w;
    const float* gb = br ? g2b : g1b;
    unsigned short* Hh = br ? Hbhi2 : Hbhi1;
    unsigned short* Hl = br ? Hblo2 : Hblo1;
    int e = blockIdx.x*256 + threadIdx.x;
    int srow = e >> 7, j = e & 127;
    const float* xr = X + (size_t)srow*128;
    float acc = gb[j];
    for (int k = 0; k < 128; ++k) acc += xr[k] * gw[k*128 + j];
    unsigned short hh = f2bf(acc);
    Hh[e] = hh;
    Hl[e] = f2bf(acc - bf2f(hh));
}

// ===== K4: S = lrelu(H H^T - 1e8*I), merged branches (z = br*4 + b) =====
__global__ __launch_bounds__(256) void k_scores(
    const unsigned short* __restrict__ Hbhi1, const unsigned short* __restrict__ Hblo1,
    const unsigned short* __restrict__ Hbhi2, const unsigned short* __restrict__ Hblo2,
    float* __restrict__ S1, float* __restrict__ S2)
{
    __shared__ __align__(16) unsigned short HiH[64*64];
    __shared__ __align__(16) unsigned short HiL[64*64];
    __shared__ __align__(16) unsigned short HjH[64*64];
    __shared__ __align__(16) unsigned short HjL[64*64];
    const int z = blockIdx.z;
    const int b = z & 3, br = z >> 2;
    const unsigned short* Hbhi = br ? Hbhi2 : Hbhi1;
    const unsigned short* Hblo = br ? Hblo2 : Hblo1;
    float* S = br ? S2 : S1;
    const int i0 = blockIdx.y * 64, j0 = blockIdx.x * 64;
    const int t = threadIdx.x;
    const int w = t >> 6, l = t & 63, lr = l & 15, h = l >> 4;
    const size_t hb = (size_t)b * 1024 * 128;

    f32x4 acc[4] = {};
    for (int kh = 0; kh < 2; ++kh) {
        __syncthreads();
        #pragma unroll
        for (int it = 0; it < 4; ++it) {
            int g = it*256 + t;
            int mat = g >> 9;
            int gg = g & 511;
            int row = gg >> 3, ch = gg & 7;
            int base0 = mat ? j0 : i0;
            size_t src = hb + (size_t)(base0 + row)*128 + kh*64 + ch*8;
            uint4 vh = *(const uint4*)(Hbhi + src);
            uint4 vl = *(const uint4*)(Hblo + src);
            int sw = ch ^ (row & 7);
            unsigned short* dh = (mat ? HjH : HiH) + row*64 + sw*8;
            unsigned short* dl = (mat ? HjL : HiL) + row*64 + sw*8;
            *(uint4*)dh = vh;
            *(uint4*)dl = vl;
        }
        __syncthreads();
        #pragma unroll
        for (int kc = 0; kc < 2; ++kc) {
            int swA = (((kc*4 + h) ^ (lr & 7)) << 3);
            bf16x8 ah = *(const bf16x8*)&HiH[(w*16 + lr)*64 + swA];
            bf16x8 al = *(const bf16x8*)&HiL[(w*16 + lr)*64 + swA];
            #pragma unroll
            for (int jt = 0; jt < 4; ++jt) {
                bf16x8 bh = *(const bf16x8*)&HjH[(jt*16 + lr)*64 + swA];
                bf16x8 bl = *(const bf16x8*)&HjL[(jt*16 + lr)*64 + swA];
                acc[jt] = __builtin_amdgcn_mfma_f32_16x16x32_bf16(ah, bh, acc[jt], 0,0,0);
                acc[jt] = __builtin_amdgcn_mfma_f32_16x16x32_bf16(ah, bl, acc[jt], 0,0,0);
                acc[jt] = __builtin_amdgcn_mfma_f32_16x16x32_bf16(al, bh, acc[jt], 0,0,0);
            }
        }
    }
    float* Sb = S + (size_t)b*1024*1024;
    #pragma unroll
    for (int jt = 0; jt < 4; ++jt) {
        #pragma unroll
        for (int r = 0; r < 4; ++r) {
            int i = i0 + w*16 + h*4 + r;
            int j = j0 + jt*16 + lr;
            float x = acc[jt][r];
            if (i == j) x -= 1e8f;
            Sb[(size_t)i*1024 + j] = lrelu(x);
        }
    }
}

// ===== K5: row stats, merged branches (y = br*4 + b) =====
__global__ __launch_bounds__(256) void k_rowstat(const float* __restrict__ S1, const float* __restrict__ S2,
                                                 float* __restrict__ mrow, float* __restrict__ linv)
{
    __shared__ float red[256];
    const int y = blockIdx.y, i = blockIdx.x, t = threadIdx.x;
    const int b = y & 3, br = y >> 2;
    const float* row = (br ? S2 : S1) + (size_t)b*1024*1024 + (size_t)i*1024;
    float4 v = *(const float4*)&row[t*4];
    float mx = fmaxf(fmaxf(v.x,v.y), fmaxf(v.z,v.w));
    red[t] = mx; __syncthreads();
    for (int s2 = 128; s2 > 0; s2 >>= 1) { if (t < s2) red[t] = fmaxf(red[t], red[t+s2]); __syncthreads(); }
    mx = red[0]; __syncthreads();
    float e = (__expf(v.x-mx) + __expf(v.y-mx)) + (__expf(v.z-mx) + __expf(v.w-mx));
    red[t] = e; __syncthreads();
    for (int s2 = 128; s2 > 0; s2 >>= 1) { if (t < s2) red[t] += red[t+s2]; __syncthreads(); }
    if (t == 0) { mrow[y*1024 + i] = mx; linv[y*1024 + i] = 1.f / red[0]; }
}

// ===== K5b: Xbb transpose -> XbbT hi/lo (validated r9) =====
__global__ __launch_bounds__(256) void k_xbbt(const float* __restrict__ X,
    const float* __restrict__ bng1, const float* __restrict__ bnb1,
    const float* __restrict__ bng2, const float* __restrict__ bnb2,
    unsigned short* __restrict__ XbbThi, unsigned short* __restrict__ XbbTlo)
{
    __shared__ float Xl[64][132];
    const int t = threadIdx.x;
    const int j0 = blockIdx.x*64, b = blockIdx.y, br = blockIdx.z;
    {
        int r2 = t >> 2, dseg = (t & 3)*32;
        const float* src = X + ((size_t)(b*1024 + j0 + r2))*128 + dseg;
        #pragma unroll
        for (int q = 0; q < 8; ++q) {
            float4 v = *(const float4*)(src + q*4);
            Xl[r2][dseg + q*4 + 0] = v.x;
            Xl[r2][dseg + q*4 + 1] = v.y;
            Xl[r2][dseg + q*4 + 2] = v.z;
            Xl[r2][dseg + q*4 + 3] = v.w;
        }
    }
    __syncthreads();
    const int d = t >> 1, seg = t & 1;
    const float g  = (br ? bng2 : bng1)[d];
    const float bb = (br ? bnb2 : bnb1)[d];
    unsigned short* dsth = XbbThi + (size_t)br*524288 + ((size_t)(b*128 + d))*1024 + j0 + seg*32;
    unsigned short* dstl = XbbTlo + (size_t)br*524288 + ((size_t)(b*128 + d))*1024 + j0 + seg*32;
    #pragma unroll
    for (int g8 = 0; g8 < 4; ++g8) {
        unsigned int hu[4], lu[4];
        #pragma unroll
        for (int q = 0; q < 4; ++q) {
            float v0 = Xl[seg*32 + g8*8 + 2*q    ][d]*g + bb;
            float v1 = Xl[seg*32 + g8*8 + 2*q + 1][d]*g + bb;
            unsigned short h0 = f2bf(v0), h1 = f2bf(v1);
            hu[q] = (unsigned int)h0 | ((unsigned int)h1 << 16);
            lu[q] = (unsigned int)f2bf(v0 - bf2f(h0)) | ((unsigned int)f2bf(v1 - bf2f(h1)) << 16);
        }
        *(uint4*)(dsth + g8*8) = make_uint4(hu[0],hu[1],hu[2],hu[3]);
        *(uint4*)(dstl + g8*8) = make_uint4(lu[0],lu[1],lu[2],lu[3]);
    }
}

// ===== K6-MFMA: P = (softmax(S)+I) @ Xbb -> P bf16 hi/lo (k_map2 convention) =====
__global__ __launch_bounds__(256) void k_pvmm(
    const float* __restrict__ S1, const float* __restrict__ S2, const float* __restrict__ X,
    const float* __restrict__ bng1, const float* __restrict__ bnb1,
    const float* __restrict__ bng2, const float* __restrict__ bnb2,
    const float* __restrict__ mrow, const float* __restrict__ linv,
    const unsigned short* __restrict__ XbbThi, const unsigned short* __restrict__ XbbTlo,
    unsigned short* __restrict__ Phi, unsigned short* __restrict__ Plo)
{
    __shared__ __align__(16) unsigned short ElH[16*64];
    __shared__ __align__(16) unsigned short ElL[16*64];
    const int t = threadIdx.x;
    const int w = t >> 6, l = t & 63, lr = l & 15, h = l >> 4;
    const int i0 = blockIdx.x * 16;
    const int b = blockIdx.y;
    const int br = blockIdx.z;
    const float* S = br ? S2 : S1;
    const float* bng = br ? bng2 : bng1;
    const float* bnb = br ? bnb2 : bnb1;
    const float* mr = mrow + br*4096 + b*1024;
    const float* lv = linv + br*4096 + b*1024;
    const unsigned short* Bh = XbbThi + (size_t)br*524288 + (size_t)b*131072;
    const unsigned short* Bl = XbbTlo + (size_t)br*524288 + (size_t)b*131072;

    const int srow = t >> 4, jseg = t & 15;
    const float mi = mr[i0 + srow];
    const int j0s = jseg*4;
    const int eoff = srow*64 + (((j0s>>3) ^ (srow&7))<<3) + (j0s&7);

    f32x4 acc[2] = {};
    for (int ch = 0; ch < 16; ++ch) {
        const int jb = ch*64;
        __syncthreads();
        {
            float4 sv = *(const float4*)(S + ((size_t)(b*1024 + i0 + srow))*1024 + jb + j0s);
            float e0 = __expf(sv.x - mi), e1 = __expf(sv.y - mi);
            float e2 = __expf(sv.z - mi), e3 = __expf(sv.w - mi);
            unsigned short h0 = f2bf(e0), h1 = f2bf(e1), h2 = f2bf(e2), h3 = f2bf(e3);
            uint2 vh, vl;
            vh.x = (unsigned int)h0 | ((unsigned int)h1 << 16);
            vh.y = (unsigned int)h2 | ((unsigned int)h3 << 16);
            vl.x = (unsigned int)f2bf(e0 - bf2f(h0)) | ((unsigned int)f2bf(e1 - bf2f(h1)) << 16);
            vl.y = (unsigned int)f2bf(e2 - bf2f(h2)) | ((unsigned int)f2bf(e3 - bf2f(h3)) << 16);
            *(uint2*)(ElH + eoff) = vh;
            *(uint2*)(ElL + eoff) = vl;
        }
        __syncthreads();
        #pragma unroll
        for (int kc = 0; kc < 2; ++kc) {
            int swA = (((kc*4 + h) ^ (lr & 7)) << 3);
            bf16x8 ah = *(const bf16x8*)&ElH[lr*64 + swA];
            bf16x8 al = *(const bf16x8*)&ElL[lr*64 + swA];
            #pragma unroll
            for (int n2 = 0; n2 < 2; ++n2) {
                int nt = w*2 + n2;
                size_t boff = (size_t)(nt*16 + lr)*1024 + jb + kc*32 + h*8;
                bf16x8 bh = *(const bf16x8*)(Bh + boff);
                bf16x8 bl = *(const bf16x8*)(Bl + boff);
                acc[n2] = __builtin_amdgcn_mfma_f32_16x16x32_bf16(ah, bh, acc[n2], 0,0,0);
                acc[n2] = __builtin_amdgcn_mfma_f32_16x16x32_bf16(ah, bl, acc[n2], 0,0,0);
                acc[n2] = __builtin_amdgcn_mfma_f32_16x16x32_bf16(al, bh, acc[n2], 0,0,0);
            }
        }
    }
    #pragma unroll
    for (int r = 0; r < 4; ++r) {
        int i = i0 + h*4 + r;
        float inv = lv[i];
        #pragma unroll
        for (int n2 = 0; n2 < 2; ++n2) {
            int d = (w*2 + n2)*16 + lr;
            float xv = X[((size_t)(b*1024 + i))*128 + d] * bng[d] + bnb[d];
            float pv = acc[n2][r]*inv + xv;
            size_t off = ((size_t)(br*4096 + b*1024 + i))*128 + d;
            unsigned short hh = f2bf(pv);
            Phi[off] = hh;
            Plo[off] = f2bf(pv - bf2f(hh));
        }
    }
}

// ===== K7-MFMA: O = lrelu(P @ tw + tb), dual branch, 16 rows/block =====
__global__ __launch_bounds__(256) void k_tprojmm(
    const unsigned short* __restrict__ Phi, const unsigned short* __restrict__ Plo,
    const unsigned short* __restrict__ twThi, const unsigned short* __restrict__ twTlo,
    const float* __restrict__ t1b, const float* __restrict__ t2b,
    float* __restrict__ O)
{
    const int t = threadIdx.x, w = t>>6, l = t&63, lr = l&15, h = l>>4;
    const int r0 = blockIdx.x*16;          // global row 0..8191 (br*4096 + local)
    const int br = r0 >> 12;
    f32x4 acc = {};
    #pragma unroll
    for (int kc = 0; kc < 4; ++kc) {
        size_t aoff = (size_t)(r0 + lr)*128 + kc*32 + h*8;
        bf16x8 ah = *(const bf16x8*)(Phi + aoff);
        bf16x8 al = *(const bf16x8*)(Plo + aoff);
        size_t boff = (size_t)(br*64 + w*16 + lr)*128 + kc*32 + h*8;
        bf16x8 bh = *(const bf16x8*)(twThi + boff);
        bf16x8 bl = *(const bf16x8*)(twTlo + boff);
        acc = __builtin_amdgcn_mfma_f32_16x16x32_bf16(ah, bh, acc, 0,0,0);
        acc = __builtin_amdgcn_mfma_f32_16x16x32_bf16(ah, bl, acc, 0,0,0);
        acc = __builtin_amdgcn_mfma_f32_16x16x32_bf16(al, bh, acc, 0,0,0);
    }
    const float* tb = br ? t2b : t1b;
    float tbe = tb[w*16 + lr];
    int rowLocal0 = r0 & 4095;
    #pragma unroll
    for (int r = 0; r < 4; ++r) {
        int row = rowLocal0 + h*4 + r;
        O[(size_t)br*262144 + (size_t)row*64 + w*16 + lr] = lrelu(acc[r] + tbe);
    }
}

// ===== K6-fallback: f32 PV (validated r8) =====
__global__ __launch_bounds__(256) void k_pv(const float* __restrict__ S, const float* __restrict__ X,
                                            const float* __restrict__ bng, const float* __restrict__ bnb,
                                            const float* __restrict__ mrowG, const float* __restrict__ linvG,
                                            float* __restrict__ P)
{
    __shared__ __align__(16) float Sl[16*65];
    __shared__ __align__(16) float Xl[64*132];
    const int b = blockIdx.y, i0 = blockIdx.x*16, t = threadIdx.x;
    const int il = t >> 4, dg = t & 15;
    const int sj = t & 63, sil = t >> 6;
    const int xd = t & 127, xj = t >> 7;
    const float bg = bng[xd], bb = bnb[xd];
    float mr[4];
    #pragma unroll
    for (int m2 = 0; m2 < 4; ++m2) mr[m2] = mrowG[b*1024 + i0 + sil*4 + m2];
    float acc[8] = {};
    const float* Sb = S + (size_t)b*1024*1024;
    const float* Xb = X + (size_t)b*1024*128;
    for (int c = 0; c < 16; ++c) {
        int jb = c*64;
        __syncthreads();
        #pragma unroll
        for (int m2 = 0; m2 < 4; ++m2) {
            int r2 = sil*4 + m2;
            Sl[r2*65 + sj] = __expf(Sb[(size_t)(i0+r2)*1024 + jb + sj] - mr[m2]);
        }
        #pragma unroll
        for (int m2 = 0; m2 < 32; ++m2) {
            int jc = xj + 2*m2;
            Xl[jc*132 + xd] = Xb[(size_t)(jb+jc)*128 + xd] * bg + bb;
        }
        __syncthreads();
        for (int jc = 0; jc < 64; ++jc) {
            float sv = Sl[il*65 + jc];
            float4 x0 = *(const float4*)&Xl[jc*132 + dg*8];
            float4 x1 = *(const float4*)&Xl[jc*132 + dg*8 + 4];
            acc[0] += sv*x0.x; acc[1] += sv*x0.y; acc[2] += sv*x0.z; acc[3] += sv*x0.w;
            acc[4] += sv*x1.x; acc[5] += sv*x1.y; acc[6] += sv*x1.z; acc[7] += sv*x1.w;
        }
    }
    int i = i0 + il;
    float inv = linvG[b*1024 + i];
    const float* xr = Xb + (size_t)i*128 + dg*8;
    float* pr = P + (size_t)(b*1024 + i)*128 + dg*8;
    #pragma unroll
    for (int z = 0; z < 8; ++z) {
        float xv = xr[z] * bng[dg*8+z] + bnb[dg*8+z];
        pr[z] = acc[z]*inv + xv;
    }
}

// ===== K7: tproj single-branch f32 (fallback) =====
__global__ __launch_bounds__(256) void k_tproj(const float* __restrict__ P, const float* __restrict__ tw,
                                               const float* __restrict__ tb, float* __restrict__ O)
{
    int idx = blockIdx.x*256 + threadIdx.x;
    int srow = idx >> 6, e = idx & 63;
    const float* pr = P + (size_t)srow*128;
    float acc = tb[e];
    for (int d = 0; d < 128; ++d) acc += pr[d] * tw[d*64 + e];
    O[idx] = lrelu(acc);
}

// ===== K8: fc1 partial sums (validated) =====
__global__ __launch_bounds__(256) void k_fc1(const float* __restrict__ O1, const float* __restrict__ O2,
                                             const float* __restrict__ w, float* __restrict__ pbuf)
{
    __shared__ float red[4*512];
    const int t = threadIdx.x;
    const int wv = t >> 6, l = t & 63;
    const int gwid = blockIdx.x*4 + wv;
    float acc[4][2] = {};
    int base = gwid*64;
    for (int tt = 0; tt < 64; ++tt) {
        int row = base + tt;
        float2 wvv = *(const float2*)&w[(size_t)row*128 + l*2];
        #pragma unroll
        for (int b = 0; b < 4; ++b) {
            float fb = (row < 65536) ? O1[b*65536 + row] : O2[b*65536 + row - 65536];
            acc[b][0] += fb * wvv.x;
            acc[b][1] += fb * wvv.y;
        }
    }
    #pragma unroll
    for (int b = 0; b < 4; ++b) {
        red[wv*512 + b*128 + l*2]   = acc[b][0];
        red[wv*512 + b*128 + l*2+1] = acc[b][1];
    }
    __syncthreads();
    for (int rep = 0; rep < 2; ++rep) {
        int col = rep*256 + t;
        pbuf[(size_t)blockIdx.x*512 + col] = red[col] + red[512+col] + red[1024+col] + red[1536+col];
    }
}

// ===== K8b: reduce fc1 partials (validated) =====
__global__ __launch_bounds__(256) void k_red(const float* __restrict__ pbuf, float* __restrict__ pbuf2)
{
    int col = blockIdx.x*8 + (threadIdx.x >> 5);
    int lane = threadIdx.x & 31;
    float acc = 0.f;
    for (int it = 0; it < 16; ++it)
        acc += pbuf[(size_t)(lane + it*32)*512 + col];
    #pragma unroll
    for (int s2 = 16; s2 >= 1; s2 >>= 1) acc += __shfl_xor(acc, s2, 32);
    if (lane == 0) pbuf2[col] = acc;
}

// ===== K9: MLP head (validated) =====
__global__ __launch_bounds__(256) void k_head2(const float* __restrict__ pbuf2,
    const float* __restrict__ fc1b, const float* __restrict__ fc2w, const float* __restrict__ fc2b,
    const float* __restrict__ fc3w, const float* __restrict__ fc3b,
    const float* __restrict__ fc4w, const float* __restrict__ fc4b,
    float* __restrict__ out)
{
    __shared__ float r1[512], r2[512], r3[256];
    const int t = threadIdx.x;
    for (int rep = 0; rep < 2; ++rep) {
        int idx = rep*256 + t;
        r1[idx] = frelu(pbuf2[idx] + fc1b[idx & 127]);
    }
    __syncthreads();
    for (int rep = 0; rep < 2; ++rep) {
        int idx = rep*256 + t;
        int b = idx >> 7, j = idx & 127;
        float acc = fc2b[j];
        for (int k = 0; k < 128; ++k) acc += r1[b*128+k]*fc2w[k*128+j];
        r2[idx] = frelu(acc);
    }
    __syncthreads();
    {
        int b = t >> 6, e2 = t & 63;
        float acc = fc3b[e2];
        for (int k = 0; k < 128; ++k) acc += r2[b*128+k]*fc3w[k*64+e2];
        r3[t] = frelu(acc);
    }
    __syncthreads();
    if (t < 24) {
        int b = t/6, c = t%6;
        float acc = fc4b[c];
        for (int k = 0; k < 64; ++k) acc += r3[b*64+k]*fc4w[k*6+c];
        out[b*6+c] = acc;
    }
}

extern "C" void kernel_launch(void* const* d_in, const int* in_sizes, int n_in,
                              void* d_out, int out_size, void* d_ws, size_t ws_size,
                              hipStream_t stream)
{
    (void)in_sizes; (void)n_in; (void)out_size;
    const float* xenc = (const float*)d_in[0];
    const float* w1   = (const float*)d_in[4];
    const float* g1   = (const float*)d_in[5];
    const float* b1   = (const float*)d_in[6];
    const float* w2   = (const float*)d_in[7];
    const float* g2   = (const float*)d_in[8];
    const float* b2   = (const float*)d_in[9];
    const float* w3   = (const float*)d_in[10];
    const float* g3   = (const float*)d_in[11];
    const float* b3   = (const float*)d_in[12];
    const float* m2w  = (const float*)d_in[13];
    const float* m2b  = (const float*)d_in[14];
    const float* m2g  = (const float*)d_in[15];
    const float* m2bb = (const float*)d_in[16];
    const float* g1w  = (const float*)d_in[17];
    const float* g1b  = (const float*)d_in[18];
    const float* m1g  = (const float*)d_in[19];
    const float* m1b  = (const float*)d_in[20];
    const float* t1w  = (const float*)d_in[21];
    const float* t1b  = (const float*)d_in[22];
    const float* g2w  = (const float*)d_in[23];
    const float* g2bv = (const float*)d_in[24];
    const float* mm2g = (const float*)d_in[25];
    const float* mm2b = (const float*)d_in[26];
    const float* t2w  = (const float*)d_in[27];
    const float* t2b  = (const float*)d_in[28];
    const float* fc1w = (const float*)d_in[29];
    const float* fc1b = (const float*)d_in[30];
    const float* fc2w = (const float*)d_in[31];
    const float* fc2b = (const float*)d_in[32];
    const float* fc3w = (const float*)d_in[33];
    const float* fc3b = (const float*)d_in[34];
    const float* fc4w = (const float*)d_in[35];
    const float* fc4b = (const float*)d_in[36];

    char* ws = (char*)d_ws;
    float* a2   = (float*)(ws);
    float* X    = (float*)(ws + (2u<<20));
    unsigned short* Hbhi1 = (unsigned short*)(ws + (4u<<20));
    unsigned short* Hblo1 = (unsigned short*)(ws + (5u<<20));
    unsigned short* Hbhi2 = (unsigned short*)(ws);
    unsigned short* Hblo2 = (unsigned short*)(ws + (1u<<20));
    float* S1   = (float*)(ws + (6u<<20));
    unsigned short* aflatG = (unsigned short*)(ws + (6u<<20));
    unsigned short* w2s    = (unsigned short*)(ws + (6u<<20) + 5242880);
    unsigned short* w3s    = (unsigned short*)(ws + (6u<<20) + 5242880 + 131072);
    unsigned short* m2wbT  = (unsigned short*)(ws + (6u<<20) + 5242880 + 196608);
    float* pbuf2 = (float*)(ws + (6u<<20));

    if (ws_size >= ((size_t)49 << 20)) {
        float* S2   = (float*)(ws + (22u<<20));
        unsigned short* Phi = (unsigned short*)(ws + (38u<<20));   // 2 MB [8192][128]
        unsigned short* Plo = (unsigned short*)(ws + (40u<<20));   // 2 MB
        float* O    = (float*)(ws + (42u<<20));                    // 2 MB (O1|O2)
        float* pbuf = (float*)(ws + (44u<<20));                    // 1 MB
        float* mrow = (float*)(ws + (44u<<20));                    // 32 KB (alias pbuf)
        float* linv = (float*)(ws + (44u<<20) + 65536);            // 32 KB
        unsigned short* twThi = (unsigned short*)(ws + (44u<<20) + 131072); // 32 KB
        unsigned short* twTlo = (unsigned short*)(ws + (44u<<20) + 196608); // 32 KB
        unsigned short* XbbThi = (unsigned short*)(ws + (45u<<20));
        unsigned short* XbbTlo = (unsigned short*)(ws + (47u<<20));
        float* O1 = O;
        float* O2 = O + 262144;

        k_prep<<<288, 256, 0, stream>>>(w2, w3, m2w, t1w, t2w, w2s, w3s, m2wbT, twThi, twTlo);
        k_conv<<<4096, 256, 0, stream>>>(xenc, w1,g1,b1, w2s,g2,b2, w3s,g3,b3, aflatG);
        k_map2<<<64, 256, 0, stream>>>(aflatG, m2wbT, m2b, m2g, m2bb, a2);
        k_buildx<<<2048, 256, 0, stream>>>(a2, X);
        k_hmat<<<dim3(2048,2), 256, 0, stream>>>(X, g1w, g1b, g2w, g2bv,
                                                 Hbhi1, Hblo1, Hbhi2, Hblo2);
        k_xbbt<<<dim3(16,4,2), 256, 0, stream>>>(X, m1g, m1b, mm2g, mm2b, XbbThi, XbbTlo);
        k_scores <<<dim3(16,16,8), 256, 0, stream>>>(Hbhi1, Hblo1, Hbhi2, Hblo2, S1, S2);
        k_rowstat<<<dim3(1024,8), 256, 0, stream>>>(S1, S2, mrow, linv);
        k_pvmm<<<dim3(64,4,2), 256, 0, stream>>>(S1, S2, X, m1g, m1b, mm2g, mm2b,
                                                 mrow, linv, XbbThi, XbbTlo, Phi, Plo);
        k_tprojmm<<<512, 256, 0, stream>>>(Phi, Plo, twThi, twTlo, t1b, t2b, O);
        k_fc1 <<<512, 256, 0, stream>>>(O1, O2, fc1w, pbuf);
        k_red <<<64, 256, 0, stream>>>(pbuf, pbuf2);
        k_head2<<<1, 256, 0, stream>>>(pbuf2, fc1b, fc2w, fc2b, fc3w, fc3b, fc4w, fc4b, (float*)d_out);
    } else {
        // ---- fallback: r8-style f32 MPNN tail (27 MB) ----
        float* P    = (float*)(ws + (22u<<20));
        float* O1   = (float*)(ws + (24u<<20));
        float* O2   = (float*)(ws + (25u<<20));
        float* pbuf = (float*)(ws + (26u<<20));
        float* mrow = (float*)(ws + (26u<<20));
        float* linv = (float*)(ws + (26u<<20) + 65536);
        unsigned short* twThi = (unsigned short*)(ws + (26u<<20) + 131072);
        unsigned short* twTlo = (unsigned short*)(ws + (26u<<20) + 196608);

        k_prep<<<288, 256, 0, stream>>>(w2, w3, m2w, t1w, t2w, w2s, w3s, m2wbT, twThi, twTlo);
        k_conv<<<4096, 256, 0, stream>>>(xenc, w1,g1,b1, w2s,g2,b2, w3s,g3,b3, aflatG);
        k_map2<<<64, 256, 0, stream>>>(aflatG, m2wbT, m2b, m2g, m2bb, a2);
        k_buildx<<<2048, 256, 0, stream>>>(a2, X);
        k_hmat<<<dim3(2048,2), 256, 0, stream>>>(X, g1w, g1b, g2w, g2bv,
                                                 Hbhi1, Hblo1, Hbhi2, Hblo2);
        k_scores <<<dim3(16,16,4), 256, 0, stream>>>(Hbhi1, Hblo1, Hbhi1, Hblo1, S1, S1);
        k_rowstat<<<dim3(1024,4), 256, 0, stream>>>(S1, S1, mrow, linv);
        k_pv     <<<dim3(64,4), 256, 0, stream>>>(S1, X, m1g, m1b, mrow, linv, P);
        k_tproj  <<<1024, 256, 0, stream>>>(P, t1w, t1b, O1);
        k_scores <<<dim3(16,16,4), 256, 0, stream>>>(Hbhi2, Hblo2, Hbhi2, Hblo2, S1, S1);
        k_rowstat<<<dim3(1024,4), 256, 0, stream>>>(S1, S1, mrow, linv);
        k_pv     <<<dim3(64,4), 256, 0, stream>>>(S1, X, mm2g, mm2b, mrow, linv, P);
        k_tproj  <<<1024, 256, 0, stream>>>(P, t2w, t2b, O2);
        k_fc1 <<<512, 256, 0, stream>>>(O1, O2, fc1w, pbuf);
        k_red <<<64, 256, 0, stream>>>(pbuf, pbuf2);
        k_head2<<<1, 256, 0, stream>>>(pbuf2, fc1b, fc2w, fc2b, fc3w, fc3b, fc4w, fc4b, (float*)d_out);
    }
}

// Round 12
// 260.543 us; speedup vs baseline: 2.4071x; 1.0079x over previous
//
#include <hip/hip_runtime.h>
#include <hip/hip_bf16.h>
#include <math.h>

#define NEG 0.01f
__device__ __forceinline__ float lrelu(float v){ return v > 0.f ? v : NEG*v; }
__device__ __forceinline__ float frelu(float v){ return v > 0.f ? v : 0.f; }

typedef __attribute__((ext_vector_type(8))) short bf16x8;
typedef __attribute__((ext_vector_type(4))) float f32x4;

__device__ __forceinline__ unsigned short f2bf(float x){
    unsigned int u = __float_as_uint(x);
    unsigned int r = (u + 0x7FFFu + ((u>>16)&1u)) >> 16;
    return (unsigned short)r;
}
__device__ __forceinline__ float bf2f(unsigned short h){
    return __uint_as_float(((unsigned int)h) << 16);
}
__device__ __forceinline__ unsigned short F2B(float x){
    __hip_bfloat16 h = __float2bfloat16(x);
    return *reinterpret_cast<unsigned short*>(&h);
}

// ============ K0: weight repack (+ twT hi/lo) (validated r11) ============
__global__ __launch_bounds__(256) void k_prep(const float* __restrict__ w2, const float* __restrict__ w3,
    const float* __restrict__ m2w, const float* __restrict__ t1w, const float* __restrict__ t2w,
    unsigned short* __restrict__ w2s, unsigned short* __restrict__ w3s, unsigned short* __restrict__ m2wbT,
    unsigned short* __restrict__ twThi, unsigned short* __restrict__ twTlo)
{
    int gid = blockIdx.x*256 + threadIdx.x;
    if (gid < 73728) {
        int j = gid / 576, f = gid % 576;
        m2wbT[gid] = f2bf(m2w[f*128 + j]);
    }
    if (gid < 65536) {
        int jj = gid & 7, q = (gid>>3)&3, o = (gid>>5)&127, ks = (gid>>12)&1, k = gid>>13;
        int c = ks*32 + q*8 + jj;
        w2s[gid] = f2bf(w2[o*512 + c*8 + k]);
    }
    if (gid < 32768) {
        int jj = gid & 7, q = (gid>>3)&3, o = (gid>>5)&31, ks = (gid>>10)&3, k = gid>>12;
        int c = ks*32 + q*8 + jj;
        w3s[gid] = f2bf(w3[o*1024 + c*8 + k]);
    }
    if (gid < 16384) {
        int d = gid & 127, e = (gid>>7)&63, br = gid>>13;
        float x = (br ? t2w : t1w)[d*64 + e];
        unsigned short hh = f2bf(x);
        twThi[gid] = hh;
        twTlo[gid] = f2bf(x - bf2f(hh));
    }
}

// ============ K1: fused conv stack (validated r10, unchanged) ============
__global__ __launch_bounds__(256) void k_conv(
    const float* __restrict__ xenc,
    const float* __restrict__ w1, const float* __restrict__ g1, const float* __restrict__ b1,
    const unsigned short* __restrict__ w2s, const float* __restrict__ g2, const float* __restrict__ b2,
    const unsigned short* __restrict__ w3s, const float* __restrict__ g3, const float* __restrict__ b3,
    unsigned short* __restrict__ aflatG)
{
    __shared__ __align__(16) unsigned char smraw[22208];
    float* sigp = (float*)smraw;
    unsigned short* p1T = (unsigned short*)(smraw + 576);
    unsigned short* p2T = (unsigned short*)(smraw + 10304);
    unsigned short* astage = (unsigned short*)(smraw + 21056);

    const int t = threadIdx.x;
    const int s = blockIdx.x;

    {
        unsigned int* zz = (unsigned int*)(smraw + 576);
        for (int i = t; i < 5120; i += 256) zz[i] = 0u;
        if (t < 144) sigp[t] = 0.f;
    }
    __syncthreads();
    if (t < 128) sigp[4 + t] = xenc[(size_t)s*128 + t];
    __syncthreads();

    {   // conv1 f32 sliding window + pool -> p1T
        const int c = t & 63, qg = t >> 6;
        float wr[8];
        #pragma unroll
        for (int k = 0; k < 8; ++k) wr[k] = w1[c*8 + k];
        const float g = g1[c], b = b1[c];
        const int qs = qg*17;
        float win[9];
        {
            int base = 2*qs - 1;
            #pragma unroll
            for (int x = 0; x < 9; ++x) win[x] = (base + x >= 0) ? sigp[base + x] : 0.f;
        }
        #pragma unroll
        for (int j = 0; j < 17; ++j) {
            int q = qs + j;
            float s0 = 0.f, s1 = 0.f;
            #pragma unroll
            for (int k = 0; k < 8; ++k) { s0 += win[k]*wr[k]; s1 += win[k+1]*wr[k]; }
            float v = frelu(s1*g + b);
            if (q > 0) v = fmaxf(v, frelu(s0*g + b));
            if (q < 65) {
                int row = q + 4;
                p1T[row*64 + (((c>>3) ^ (row&7))<<3) + (c&7)] = F2B(v);
            }
            #pragma unroll
            for (int x = 0; x < 7; ++x) win[x] = win[x+2];
            win[7] = sigp[2*q + 8];
            win[8] = sigp[2*q + 9];
        }
    }
    __syncthreads();

    {   // conv2 MFMA + fused bn/relu/pool2 -> p2T
        const int wv = t >> 6, l = t & 63, lg = l >> 4, lr = l & 15;
        const int pbase = ((lr & 7) << 1) + (lr >> 3) - 1;
        f32x4 acc[2][5] = {};
        for (int k = 0; k < 8; ++k) {
            for (int ks = 0; ks < 2; ++ks) {
                bf16x8 af[2];
                #pragma unroll
                for (int oi = 0; oi < 2; ++oi) {
                    int o = (wv*2 + oi)*16 + lr;
                    af[oi] = *(const bf16x8*)(w2s + ((((k*2 + ks)*128 + o)*4 + lg)<<3));
                }
                const int q = ks*4 + lg;
                #pragma unroll
                for (int nt = 0; nt < 5; ++nt) {
                    int row = nt*16 + pbase + k; row = row > 75 ? 75 : row;
                    bf16x8 bfv = *(const bf16x8*)(p1T + row*64 + ((q ^ (row&7))<<3));
                    acc[0][nt] = __builtin_amdgcn_mfma_f32_16x16x32_bf16(af[0], bfv, acc[0][nt], 0,0,0);
                    acc[1][nt] = __builtin_amdgcn_mfma_f32_16x16x32_bf16(af[1], bfv, acc[1][nt], 0,0,0);
                }
            }
        }
        float ga[2][4], ba[2][4];
        #pragma unroll
        for (int oi = 0; oi < 2; ++oi)
            #pragma unroll
            for (int r = 0; r < 4; ++r) {
                int o = (wv*2 + oi)*16 + lg*4 + r;
                ga[oi][r] = g2[o]; ba[oi][r] = b2[o];
            }
        #pragma unroll
        for (int oi = 0; oi < 2; ++oi)
            #pragma unroll
            for (int nt = 0; nt < 5; ++nt) {
                int p = nt*16 + pbase;
                bool valid = (p >= 0) && (p <= 65);
                float vv[4];
                #pragma unroll
                for (int r = 0; r < 4; ++r) {
                    float v = frelu(acc[oi][nt][r]*ga[oi][r] + ba[oi][r]);
                    vv[r] = valid ? v : -3.0e38f;
                }
                float pv[4];
                #pragma unroll
                for (int r = 0; r < 4; ++r) pv[r] = fmaxf(vv[r], __shfl_xor(vv[r], 8));
                int q = nt*8 + (lr & 7);
                if ((lr >> 3) == 0 && q < 34) {
                    int row2 = q + 4;
                    int o0 = (wv*2 + oi)*16 + lg*4;
                    uint2 pk;
                    pk.x = (unsigned int)F2B(pv[0]) | ((unsigned int)F2B(pv[1]) << 16);
                    pk.y = (unsigned int)F2B(pv[2]) | ((unsigned int)F2B(pv[3]) << 16);
                    *(uint2*)&p2T[row2*128 + (((o0>>3) ^ (row2&15))<<3) + (o0&7)] = pk;
                }
            }
    }
    __syncthreads();

    {   // conv3 MFMA + fused bn/relu/pool3 -> astage
        const int wv = t >> 6, l = t & 63, lg = l >> 4, lr = l & 15;
        const int ot = wv & 1, ntb = (wv >> 1) * 2;
        const int ncnt = (wv < 2) ? 2 : 1;
        const int pbase = ((lr & 7) << 1) + (lr >> 3) - 1;
        f32x4 acc[2] = {};
        for (int k = 0; k < 8; ++k) {
            for (int ks = 0; ks < 4; ++ks) {
                int o = ot*16 + lr;
                bf16x8 af = *(const bf16x8*)(w3s + ((((k*4 + ks)*32 + o)*4 + lg)<<3));
                const int q = ks*4 + lg;
                #pragma unroll
                for (int ni = 0; ni < 2; ++ni) {
                    if (ni < ncnt) {
                        int row = (ntb + ni)*16 + pbase + k; row = row > 41 ? 41 : row;
                        bf16x8 bfv = *(const bf16x8*)(p2T + row*128 + ((q ^ (row&15))<<3));
                        acc[ni] = __builtin_amdgcn_mfma_f32_16x16x32_bf16(af, bfv, acc[ni], 0,0,0);
                    }
                }
            }
        }
        float g3v[4], b3v[4];
        #pragma unroll
        for (int r = 0; r < 4; ++r) {
            int o = ot*16 + lg*4 + r;
            g3v[r] = g3[o]; b3v[r] = b3[o];
        }
        #pragma unroll
        for (int ni = 0; ni < 2; ++ni) if (ni < ncnt) {
            int p = (ntb + ni)*16 + pbase;
            bool valid = (p >= 0) && (p <= 34);
            float vv[4];
            #pragma unroll
            for (int r = 0; r < 4; ++r) {
                float v = frelu(acc[ni][r]*g3v[r] + b3v[r]);
                vv[r] = valid ? v : -3.0e38f;
            }
            float pv[4];
            #pragma unroll
            for (int r = 0; r < 4; ++r) pv[r] = fmaxf(vv[r], __shfl_xor(vv[r], 8));
            int q = (ntb + ni)*8 + (lr & 7);
            if ((lr >> 3) == 0 && q < 18) {
                #pragma unroll
                for (int r = 0; r < 4; ++r)
                    astage[(ot*16 + lg*4 + r)*18 + q] = F2B(pv[r]);
            }
        }
    }
    __syncthreads();

    for (int idx = t; idx < 576; idx += 256)
        aflatG[(size_t)s*576 + idx] = astage[idx];
}

// ============ K1b: map2 GEMM (validated) ============
__global__ __launch_bounds__(256) void k_map2(const unsigned short* __restrict__ aflatG,
    const unsigned short* __restrict__ m2wbT,
    const float* __restrict__ m2b, const float* __restrict__ m2g, const float* __restrict__ m2bb,
    float* __restrict__ a2)
{
    const int t = threadIdx.x, wv = t>>6, l = t&63, lg = l>>4, lr = l&15;
    const int s0 = blockIdx.x*64;
    f32x4 acc[8] = {};
    for (int ks = 0; ks < 18; ++ks) {
        bf16x8 a = *(const bf16x8*)(aflatG + (size_t)(s0 + wv*16 + lr)*576 + ks*32 + lg*8);
        #pragma unroll
        for (int nt = 0; nt < 8; ++nt) {
            bf16x8 b = *(const bf16x8*)(m2wbT + (size_t)(nt*16 + lr)*576 + ks*32 + lg*8);
            acc[nt] = __builtin_amdgcn_mfma_f32_16x16x32_bf16(a, b, acc[nt], 0,0,0);
        }
    }
    #pragma unroll
    for (int nt = 0; nt < 8; ++nt)
        #pragma unroll
        for (int r = 0; r < 4; ++r) {
            int s2 = s0 + wv*16 + lg*4 + r;
            int j = nt*16 + lr;
            a2[(size_t)s2*128 + j] = (acc[nt][r] + m2b[j]) * m2g[j] + m2bb[j];
        }
}

// ===== K2: build X + PE (validated r6) =====
__global__ __launch_bounds__(256) void k_buildx(const float* __restrict__ a2, float* __restrict__ X)
{
    __shared__ double dvt[64];
    const int t = threadIdx.x;
    if (t < 64) dvt[t] = exp((double)(2*t) * (-9.210340371976184/128.0));
    __syncthreads();
    int e = blockIdx.x*256 + t;
    int b = e >> 17;
    int r = e & 131071;
    int i = r >> 7, d = r & 127;
    int row = b*1024 + (d & 7)*128 + (i >> 3);
    int col = (i & 7)*16 + (d >> 3);
    float v = a2[row*128 + col];
    int per = b*1024 + (i & 7)*128 + d;
    int pc  = i >> 3;
    double ang = (double)per * dvt[pc >> 1];
    const double TWO_PI = 6.283185307179586476925287;
    double kk = floor(ang * (1.0/TWO_PI) + 0.5);
    float red = (float)(ang - kk * TWO_PI);
    float pe = (pc & 1) ? __cosf(red) : __sinf(red);
    X[e] = v + pe;
}

// ===== K3: H = X @ gw + gb -> bf16 hi/lo (validated) =====
__global__ __launch_bounds__(256) void k_hmat(const float* __restrict__ X,
    const float* __restrict__ g1w, const float* __restrict__ g1b,
    const float* __restrict__ g2w, const float* __restrict__ g2b,
    unsigned short* __restrict__ Hbhi1, unsigned short* __restrict__ Hblo1,
    unsigned short* __restrict__ Hbhi2, unsigned short* __restrict__ Hblo2)
{
    const int br = blockIdx.y;
    const float* gw = br ? g2w : g1w;
    const float* gb = br ? g2b : g1b;
    unsigned short* Hh = br ? Hbhi2 : Hbhi1;
    unsigned short* Hl = br ? Hblo2 : Hblo1;
    int e = blockIdx.x*256 + threadIdx.x;
    int srow = e >> 7, j = e & 127;
    const float* xr = X + (size_t)srow*128;
    float acc = gb[j];
    for (int k = 0; k < 128; ++k) acc += xr[k] * gw[k*128 + j];
    unsigned short hh = f2bf(acc);
    Hh[e] = hh;
    Hl[e] = f2bf(acc - bf2f(hh));
}

// ===== K4 (fallback path only): S = lrelu(H H^T - 1e8*I) (validated r6/r11) =====
__global__ __launch_bounds__(256) void k_scores(
    const unsigned short* __restrict__ Hbhi1, const unsigned short* __restrict__ Hblo1,
    const unsigned short* __restrict__ Hbhi2, const unsigned short* __restrict__ Hblo2,
    float* __restrict__ S1, float* __restrict__ S2)
{
    __shared__ __align__(16) unsigned short HiH[64*64];
    __shared__ __align__(16) unsigned short HiL[64*64];
    __shared__ __align__(16) unsigned short HjH[64*64];
    __shared__ __align__(16) unsigned short HjL[64*64];
    const int z = blockIdx.z;
    const int b = z & 3, br = z >> 2;
    const unsigned short* Hbhi = br ? Hbhi2 : Hbhi1;
    const unsigned short* Hblo = br ? Hblo2 : Hblo1;
    float* S = br ? S2 : S1;
    const int i0 = blockIdx.y * 64, j0 = blockIdx.x * 64;
    const int t = threadIdx.x;
    const int w = t >> 6, l = t & 63, lr = l & 15, h = l >> 4;
    const size_t hb = (size_t)b * 1024 * 128;

    f32x4 acc[4] = {};
    for (int kh = 0; kh < 2; ++kh) {
        __syncthreads();
        #pragma unroll
        for (int it = 0; it < 4; ++it) {
            int g = it*256 + t;
            int mat = g >> 9;
            int gg = g & 511;
            int row = gg >> 3, ch = gg & 7;
            int base0 = mat ? j0 : i0;
            size_t src = hb + (size_t)(base0 + row)*128 + kh*64 + ch*8;
            uint4 vh = *(const uint4*)(Hbhi + src);
            uint4 vl = *(const uint4*)(Hblo + src);
            int sw = ch ^ (row & 7);
            unsigned short* dh = (mat ? HjH : HiH) + row*64 + sw*8;
            unsigned short* dl = (mat ? HjL : HiL) + row*64 + sw*8;
            *(uint4*)dh = vh;
            *(uint4*)dl = vl;
        }
        __syncthreads();
        #pragma unroll
        for (int kc = 0; kc < 2; ++kc) {
            int swA = (((kc*4 + h) ^ (lr & 7)) << 3);
            bf16x8 ah = *(const bf16x8*)&HiH[(w*16 + lr)*64 + swA];
            bf16x8 al = *(const bf16x8*)&HiL[(w*16 + lr)*64 + swA];
            #pragma unroll
            for (int jt = 0; jt < 4; ++jt) {
                bf16x8 bh = *(const bf16x8*)&HjH[(jt*16 + lr)*64 + swA];
                bf16x8 bl = *(const bf16x8*)&HjL[(jt*16 + lr)*64 + swA];
                acc[jt] = __builtin_amdgcn_mfma_f32_16x16x32_bf16(ah, bh, acc[jt], 0,0,0);
                acc[jt] = __builtin_amdgcn_mfma_f32_16x16x32_bf16(ah, bl, acc[jt], 0,0,0);
                acc[jt] = __builtin_amdgcn_mfma_f32_16x16x32_bf16(al, bh, acc[jt], 0,0,0);
            }
        }
    }
    float* Sb = S + (size_t)b*1024*1024;
    #pragma unroll
    for (int jt = 0; jt < 4; ++jt) {
        #pragma unroll
        for (int r = 0; r < 4; ++r) {
            int i = i0 + w*16 + h*4 + r;
            int j = j0 + jt*16 + lr;
            float x = acc[jt][r];
            if (i == j) x -= 1e8f;
            Sb[(size_t)i*1024 + j] = lrelu(x);
        }
    }
}

// ===== K5 (fallback): row stats (validated r11) =====
__global__ __launch_bounds__(256) void k_rowstat(const float* __restrict__ S1, const float* __restrict__ S2,
                                                 float* __restrict__ mrow, float* __restrict__ linv)
{
    __shared__ float red[256];
    const int y = blockIdx.y, i = blockIdx.x, t = threadIdx.x;
    const int b = y & 3, br = y >> 2;
    const float* row = (br ? S2 : S1) + (size_t)b*1024*1024 + (size_t)i*1024;
    float4 v = *(const float4*)&row[t*4];
    float mx = fmaxf(fmaxf(v.x,v.y), fmaxf(v.z,v.w));
    red[t] = mx; __syncthreads();
    for (int s2 = 128; s2 > 0; s2 >>= 1) { if (t < s2) red[t] = fmaxf(red[t], red[t+s2]); __syncthreads(); }
    mx = red[0]; __syncthreads();
    float e = (__expf(v.x-mx) + __expf(v.y-mx)) + (__expf(v.z-mx) + __expf(v.w-mx));
    red[t] = e; __syncthreads();
    for (int s2 = 128; s2 > 0; s2 >>= 1) { if (t < s2) red[t] += red[t+s2]; __syncthreads(); }
    if (t == 0) { mrow[y*1024 + i] = mx; linv[y*1024 + i] = 1.f / red[0]; }
}

// ===== K5b: Xbb transpose -> XbbT hi/lo (validated r9) =====
__global__ __launch_bounds__(256) void k_xbbt(const float* __restrict__ X,
    const float* __restrict__ bng1, const float* __restrict__ bnb1,
    const float* __restrict__ bng2, const float* __restrict__ bnb2,
    unsigned short* __restrict__ XbbThi, unsigned short* __restrict__ XbbTlo)
{
    __shared__ float Xl[64][132];
    const int t = threadIdx.x;
    const int j0 = blockIdx.x*64, b = blockIdx.y, br = blockIdx.z;
    {
        int r2 = t >> 2, dseg = (t & 3)*32;
        const float* src = X + ((size_t)(b*1024 + j0 + r2))*128 + dseg;
        #pragma unroll
        for (int q = 0; q < 8; ++q) {
            float4 v = *(const float4*)(src + q*4);
            Xl[r2][dseg + q*4 + 0] = v.x;
            Xl[r2][dseg + q*4 + 1] = v.y;
            Xl[r2][dseg + q*4 + 2] = v.z;
            Xl[r2][dseg + q*4 + 3] = v.w;
        }
    }
    __syncthreads();
    const int d = t >> 1, seg = t & 1;
    const float g  = (br ? bng2 : bng1)[d];
    const float bb = (br ? bnb2 : bnb1)[d];
    unsigned short* dsth = XbbThi + (size_t)br*524288 + ((size_t)(b*128 + d))*1024 + j0 + seg*32;
    unsigned short* dstl = XbbTlo + (size_t)br*524288 + ((size_t)(b*128 + d))*1024 + j0 + seg*32;
    #pragma unroll
    for (int g8 = 0; g8 < 4; ++g8) {
        unsigned int hu[4], lu[4];
        #pragma unroll
        for (int q = 0; q < 4; ++q) {
            float v0 = Xl[seg*32 + g8*8 + 2*q    ][d]*g + bb;
            float v1 = Xl[seg*32 + g8*8 + 2*q + 1][d]*g + bb;
            unsigned short h0 = f2bf(v0), h1 = f2bf(v1);
            hu[q] = (unsigned int)h0 | ((unsigned int)h1 << 16);
            lu[q] = (unsigned int)f2bf(v0 - bf2f(h0)) | ((unsigned int)f2bf(v1 - bf2f(h1)) << 16);
        }
        *(uint4*)(dsth + g8*8) = make_uint4(hu[0],hu[1],hu[2],hu[3]);
        *(uint4*)(dstl + g8*8) = make_uint4(lu[0],lu[1],lu[2],lu[3]);
    }
}

// ===== K6-FUSED: flash-style scores+softmax+PV -> P bf16 hi/lo =====
// block = (16-row i-tile, batch, branch), 4 independent waves each owning a
// 256-wide j-range with private online-softmax state; LDS flash-merge at end.
// All MFMA fragment patterns identical to validated k_scores/k_pvmm/k_tprojmm.
__global__ __launch_bounds__(256) void k_attn(
    const unsigned short* __restrict__ Hbhi1, const unsigned short* __restrict__ Hblo1,
    const unsigned short* __restrict__ Hbhi2, const unsigned short* __restrict__ Hblo2,
    const float* __restrict__ X,
    const float* __restrict__ bng1, const float* __restrict__ bnb1,
    const float* __restrict__ bng2, const float* __restrict__ bnb2,
    const unsigned short* __restrict__ XbbThi, const unsigned short* __restrict__ XbbTlo,
    unsigned short* __restrict__ Phi, unsigned short* __restrict__ Plo)
{
    // lbuf: during chunks: El per wave (4KB each: hi 2KB + lo 2KB) in first 16KB
    //       after barrier: Pred f32[4][16][128] (32KB) + mW/lW f32[4][16]
    __shared__ __align__(16) unsigned char lbuf[33280];
    const int t = threadIdx.x, w = t >> 6, l = t & 63, lr = l & 15, h = l >> 4;
    unsigned short* ElH = (unsigned short*)(lbuf + w*4096);
    unsigned short* ElL = (unsigned short*)(lbuf + w*4096 + 2048);
    float* Pred = (float*)lbuf;
    float* mW = (float*)(lbuf + 32768);
    float* lW = (float*)(lbuf + 32768 + 256);

    const int i0 = blockIdx.x * 16;
    const int b  = blockIdx.y;
    const int br = blockIdx.z;
    const unsigned short* Hh = br ? Hbhi2 : Hbhi1;
    const unsigned short* Hl = br ? Hblo2 : Hblo1;
    const unsigned short* Bh = XbbThi + (size_t)br*524288 + (size_t)b*131072;
    const unsigned short* Bl = XbbTlo + (size_t)br*524288 + (size_t)b*131072;
    const float* bng = br ? bng2 : bng1;
    const float* bnb = br ? bnb2 : bnb1;
    const size_t hb = (size_t)b * 1024 * 128;

    // A-operand (rows i0..i0+15) direct from global (k_tprojmm pattern)
    bf16x8 ahi[4], alo[4];
    #pragma unroll
    for (int kc = 0; kc < 4; ++kc) {
        size_t aoff = hb + (size_t)(i0 + lr)*128 + kc*32 + h*8;
        ahi[kc] = *(const bf16x8*)(Hh + aoff);
        alo[kc] = *(const bf16x8*)(Hl + aoff);
    }

    float m[4] = {-3.0e38f,-3.0e38f,-3.0e38f,-3.0e38f};
    float lsum[4] = {};
    f32x4 pacc[8] = {};

    for (int ch = 0; ch < 4; ++ch) {
        const int jbase = w*256 + ch*64;
        // --- scores tile 16 x 64 (4 jt tiles), k_scores MFMA sequence, B from global
        float sv[4][4];
        float cmax[4] = {-3.0e38f,-3.0e38f,-3.0e38f,-3.0e38f};
        #pragma unroll
        for (int jt = 0; jt < 4; ++jt) {
            f32x4 c = {};
            #pragma unroll
            for (int kc = 0; kc < 4; ++kc) {
                size_t boff = hb + (size_t)(jbase + jt*16 + lr)*128 + kc*32 + h*8;
                bf16x8 bh_ = *(const bf16x8*)(Hh + boff);
                bf16x8 bl_ = *(const bf16x8*)(Hl + boff);
                c = __builtin_amdgcn_mfma_f32_16x16x32_bf16(ahi[kc], bh_, c, 0,0,0);
                c = __builtin_amdgcn_mfma_f32_16x16x32_bf16(ahi[kc], bl_, c, 0,0,0);
                c = __builtin_amdgcn_mfma_f32_16x16x32_bf16(alo[kc], bh_, c, 0,0,0);
            }
            #pragma unroll
            for (int r = 0; r < 4; ++r) {
                float x = c[r];
                int ig = i0 + h*4 + r;
                int jg = jbase + jt*16 + lr;
                if (ig == jg) x -= 1e8f;
                x = lrelu(x);
                sv[jt][r] = x;
                cmax[r] = fmaxf(cmax[r], x);
            }
        }
        // row-max across the 16-lane lr group
        #pragma unroll
        for (int r = 0; r < 4; ++r) {
            cmax[r] = fmaxf(cmax[r], __shfl_xor(cmax[r], 1));
            cmax[r] = fmaxf(cmax[r], __shfl_xor(cmax[r], 2));
            cmax[r] = fmaxf(cmax[r], __shfl_xor(cmax[r], 4));
            cmax[r] = fmaxf(cmax[r], __shfl_xor(cmax[r], 8));
        }
        // online-softmax update
        float scale[4];
        #pragma unroll
        for (int r = 0; r < 4; ++r) {
            float mn = fmaxf(m[r], cmax[r]);
            scale[r] = __expf(m[r] - mn);
            m[r] = mn;
        }
        float csum[4] = {};
        #pragma unroll
        for (int jt = 0; jt < 4; ++jt)
            #pragma unroll
            for (int r = 0; r < 4; ++r) {
                float e = __expf(sv[jt][r] - m[r]);
                csum[r] += e;
                unsigned short eh = f2bf(e);
                unsigned short el = f2bf(e - bf2f(eh));
                int ip = h*4 + r;
                int jp = jt*16 + lr;
                int addr = ip*64 + (((jp>>3) ^ (ip&7))<<3) + (jp&7);
                ElH[addr] = eh;
                ElL[addr] = el;
            }
        #pragma unroll
        for (int r = 0; r < 4; ++r) {
            csum[r] += __shfl_xor(csum[r], 1);
            csum[r] += __shfl_xor(csum[r], 2);
            csum[r] += __shfl_xor(csum[r], 4);
            csum[r] += __shfl_xor(csum[r], 8);
            lsum[r] = lsum[r]*scale[r] + csum[r];
        }
        // rescale accumulated PV
        #pragma unroll
        for (int dt = 0; dt < 8; ++dt)
            #pragma unroll
            for (int r = 0; r < 4; ++r) pacc[dt][r] *= scale[r];
        // PV: A = E tile (wave-private LDS, k_pvmm reader pattern), B = XbbT global
        #pragma unroll
        for (int kc = 0; kc < 2; ++kc) {
            int swA = (((kc*4 + h) ^ (lr & 7)) << 3);
            bf16x8 eh8 = *(const bf16x8*)&ElH[lr*64 + swA];
            bf16x8 el8 = *(const bf16x8*)&ElL[lr*64 + swA];
            #pragma unroll
            for (int dt = 0; dt < 8; ++dt) {
                size_t boff = (size_t)(dt*16 + lr)*1024 + jbase + kc*32 + h*8;
                bf16x8 bh_ = *(const bf16x8*)(Bh + boff);
                bf16x8 bl_ = *(const bf16x8*)(Bl + boff);
                pacc[dt] = __builtin_amdgcn_mfma_f32_16x16x32_bf16(eh8, bh_, pacc[dt], 0,0,0);
                pacc[dt] = __builtin_amdgcn_mfma_f32_16x16x32_bf16(eh8, bl_, pacc[dt], 0,0,0);
                pacc[dt] = __builtin_amdgcn_mfma_f32_16x16x32_bf16(el8, bh_, pacc[dt], 0,0,0);
            }
        }
    }

    __syncthreads();   // all waves done with El before Pred overlays it
    #pragma unroll
    for (int dt = 0; dt < 8; ++dt)
        #pragma unroll
        for (int r = 0; r < 4; ++r)
            Pred[w*2048 + (h*4 + r)*128 + dt*16 + lr] = pacc[dt][r];
    if (lr == 0) {
        #pragma unroll
        for (int r = 0; r < 4; ++r) {
            mW[w*16 + h*4 + r] = m[r];
            lW[w*16 + h*4 + r] = lsum[r];
        }
    }
    __syncthreads();

    // flash-merge + Xbb epilogue (k_pvmm epilogue semantics)
    {
        int i = t >> 4, d0 = (t & 15) * 8;
        float m0 = mW[i], m1 = mW[16 + i], m2 = mW[32 + i], m3 = mW[48 + i];
        float ms = fmaxf(fmaxf(m0, m1), fmaxf(m2, m3));
        float e0 = __expf(m0 - ms), e1 = __expf(m1 - ms);
        float e2 = __expf(m2 - ms), e3 = __expf(m3 - ms);
        float ls = lW[i]*e0 + lW[16+i]*e1 + lW[32+i]*e2 + lW[48+i]*e3;
        float inv = 1.f / ls;
        unsigned int ph[4], pl[4];
        #pragma unroll
        for (int q2 = 0; q2 < 4; ++q2) {
            unsigned short hh0, hh1, ll0, ll1;
            #pragma unroll
            for (int half = 0; half < 2; ++half) {
                int d = d0 + 2*q2 + half;
                float P = Pred[i*128 + d]*e0 + Pred[2048 + i*128 + d]*e1
                        + Pred[4096 + i*128 + d]*e2 + Pred[6144 + i*128 + d]*e3;
                float xv = X[((size_t)(b*1024 + i0 + i))*128 + d] * bng[d] + bnb[d];
                float pv = P*inv + xv;
                unsigned short hh = f2bf(pv);
                unsigned short ll = f2bf(pv - bf2f(hh));
                if (half == 0) { hh0 = hh; ll0 = ll; } else { hh1 = hh; ll1 = ll; }
            }
            ph[q2] = (unsigned int)hh0 | ((unsigned int)hh1 << 16);
            pl[q2] = (unsigned int)ll0 | ((unsigned int)ll1 << 16);
        }
        size_t off = ((size_t)(br*4096 + b*1024 + i0 + i))*128 + d0;
        *(uint4*)(Phi + off) = make_uint4(ph[0],ph[1],ph[2],ph[3]);
        *(uint4*)(Plo + off) = make_uint4(pl[0],pl[1],pl[2],pl[3]);
    }
}

// ===== K6-fallback: f32 PV (validated r8) =====
__global__ __launch_bounds__(256) void k_pv(const float* __restrict__ S, const float* __restrict__ X,
                                            const float* __restrict__ bng, const float* __restrict__ bnb,
                                            const float* __restrict__ mrowG, const float* __restrict__ linvG,
                                            float* __restrict__ P)
{
    __shared__ __align__(16) float Sl[16*65];
    __shared__ __align__(16) float Xl[64*132];
    const int b = blockIdx.y, i0 = blockIdx.x*16, t = threadIdx.x;
    const int il = t >> 4, dg = t & 15;
    const int sj = t & 63, sil = t >> 6;
    const int xd = t & 127, xj = t >> 7;
    const float bg = bng[xd], bb = bnb[xd];
    float mr[4];
    #pragma unroll
    for (int m2 = 0; m2 < 4; ++m2) mr[m2] = mrowG[b*1024 + i0 + sil*4 + m2];
    float acc[8] = {};
    const float* Sb = S + (size_t)b*1024*1024;
    const float* Xb = X + (size_t)b*1024*128;
    for (int c = 0; c < 16; ++c) {
        int jb = c*64;
        __syncthreads();
        #pragma unroll
        for (int m2 = 0; m2 < 4; ++m2) {
            int r2 = sil*4 + m2;
            Sl[r2*65 + sj] = __expf(Sb[(size_t)(i0+r2)*1024 + jb + sj] - mr[m2]);
        }
        #pragma unroll
        for (int m2 = 0; m2 < 32; ++m2) {
            int jc = xj + 2*m2;
            Xl[jc*132 + xd] = Xb[(size_t)(jb+jc)*128 + xd] * bg + bb;
        }
        __syncthreads();
        for (int jc = 0; jc < 64; ++jc) {
            float sv = Sl[il*65 + jc];
            float4 x0 = *(const float4*)&Xl[jc*132 + dg*8];
            float4 x1 = *(const float4*)&Xl[jc*132 + dg*8 + 4];
            acc[0] += sv*x0.x; acc[1] += sv*x0.y; acc[2] += sv*x0.z; acc[3] += sv*x0.w;
            acc[4] += sv*x1.x; acc[5] += sv*x1.y; acc[6] += sv*x1.z; acc[7] += sv*x1.w;
        }
    }
    int i = i0 + il;
    float inv = linvG[b*1024 + i];
    const float* xr = Xb + (size_t)i*128 + dg*8;
    float* pr = P + (size_t)(b*1024 + i)*128 + dg*8;
    #pragma unroll
    for (int z = 0; z < 8; ++z) {
        float xv = xr[z] * bng[dg*8+z] + bnb[dg*8+z];
        pr[z] = acc[z]*inv + xv;
    }
}

// ===== K7-MFMA: O = lrelu(P @ tw + tb) (validated r11) =====
__global__ __launch_bounds__(256) void k_tprojmm(
    const unsigned short* __restrict__ Phi, const unsigned short* __restrict__ Plo,
    const unsigned short* __restrict__ twThi, const unsigned short* __restrict__ twTlo,
    const float* __restrict__ t1b, const float* __restrict__ t2b,
    float* __restrict__ O)
{
    const int t = threadIdx.x, w = t>>6, l = t&63, lr = l&15, h = l>>4;
    const int r0 = blockIdx.x*16;
    const int br = r0 >> 12;
    f32x4 acc = {};
    #pragma unroll
    for (int kc = 0; kc < 4; ++kc) {
        size_t aoff = (size_t)(r0 + lr)*128 + kc*32 + h*8;
        bf16x8 ah = *(const bf16x8*)(Phi + aoff);
        bf16x8 al = *(const bf16x8*)(Plo + aoff);
        size_t boff = (size_t)(br*64 + w*16 + lr)*128 + kc*32 + h*8;
        bf16x8 bh = *(const bf16x8*)(twThi + boff);
        bf16x8 bl = *(const bf16x8*)(twTlo + boff);
        acc = __builtin_amdgcn_mfma_f32_16x16x32_bf16(ah, bh, acc, 0,0,0);
        acc = __builtin_amdgcn_mfma_f32_16x16x32_bf16(ah, bl, acc, 0,0,0);
        acc = __builtin_amdgcn_mfma_f32_16x16x32_bf16(al, bh, acc, 0,0,0);
    }
    const float* tb = br ? t2b : t1b;
    float tbe = tb[w*16 + lr];
    int rowLocal0 = r0 & 4095;
    #pragma unroll
    for (int r = 0; r < 4; ++r) {
        int row = rowLocal0 + h*4 + r;
        O[(size_t)br*262144 + (size_t)row*64 + w*16 + lr] = lrelu(acc[r] + tbe);
    }
}

// ===== K7: tproj single-branch f32 (fallback) =====
__global__ __launch_bounds__(256) void k_tproj(const float* __restrict__ P, const float* __restrict__ tw,
                                               const float* __restrict__ tb, float* __restrict__ O)
{
    int idx = blockIdx.x*256 + threadIdx.x;
    int srow = idx >> 6, e = idx & 63;
    const float* pr = P + (size_t)srow*128;
    float acc = tb[e];
    for (int d = 0; d < 128; ++d) acc += pr[d] * tw[d*64 + e];
    O[idx] = lrelu(acc);
}

// ===== K8: fc1 partial sums (validated) =====
__global__ __launch_bounds__(256) void k_fc1(const float* __restrict__ O1, const float* __restrict__ O2,
                                             const float* __restrict__ w, float* __restrict__ pbuf)
{
    __shared__ float red[4*512];
    const int t = threadIdx.x;
    const int wv = t >> 6, l = t & 63;
    const int gwid = blockIdx.x*4 + wv;
    float acc[4][2] = {};
    int base = gwid*64;
    for (int tt = 0; tt < 64; ++tt) {
        int row = base + tt;
        float2 wvv = *(const float2*)&w[(size_t)row*128 + l*2];
        #pragma unroll
        for (int b = 0; b < 4; ++b) {
            float fb = (row < 65536) ? O1[b*65536 + row] : O2[b*65536 + row - 65536];
            acc[b][0] += fb * wvv.x;
            acc[b][1] += fb * wvv.y;
        }
    }
    #pragma unroll
    for (int b = 0; b < 4; ++b) {
        red[wv*512 + b*128 + l*2]   = acc[b][0];
        red[wv*512 + b*128 + l*2+1] = acc[b][1];
    }
    __syncthreads();
    for (int rep = 0; rep < 2; ++rep) {
        int col = rep*256 + t;
        pbuf[(size_t)blockIdx.x*512 + col] = red[col] + red[512+col] + red[1024+col] + red[1536+col];
    }
}

// ===== K8b: reduce fc1 partials (validated) =====
__global__ __launch_bounds__(256) void k_red(const float* __restrict__ pbuf, float* __restrict__ pbuf2)
{
    int col = blockIdx.x*8 + (threadIdx.x >> 5);
    int lane = threadIdx.x & 31;
    float acc = 0.f;
    for (int it = 0; it < 16; ++it)
        acc += pbuf[(size_t)(lane + it*32)*512 + col];
    #pragma unroll
    for (int s2 = 16; s2 >= 1; s2 >>= 1) acc += __shfl_xor(acc, s2, 32);
    if (lane == 0) pbuf2[col] = acc;
}

// ===== K9: MLP head (validated) =====
__global__ __launch_bounds__(256) void k_head2(const float* __restrict__ pbuf2,
    const float* __restrict__ fc1b, const float* __restrict__ fc2w, const float* __restrict__ fc2b,
    const float* __restrict__ fc3w, const float* __restrict__ fc3b,
    const float* __restrict__ fc4w, const float* __restrict__ fc4b,
    float* __restrict__ out)
{
    __shared__ float r1[512], r2[512], r3[256];
    const int t = threadIdx.x;
    for (int rep = 0; rep < 2; ++rep) {
        int idx = rep*256 + t;
        r1[idx] = frelu(pbuf2[idx] + fc1b[idx & 127]);
    }
    __syncthreads();
    for (int rep = 0; rep < 2; ++rep) {
        int idx = rep*256 + t;
        int b = idx >> 7, j = idx & 127;
        float acc = fc2b[j];
        for (int k = 0; k < 128; ++k) acc += r1[b*128+k]*fc2w[k*128+j];
        r2[idx] = frelu(acc);
    }
    __syncthreads();
    {
        int b = t >> 6, e2 = t & 63;
        float acc = fc3b[e2];
        for (int k = 0; k < 128; ++k) acc += r2[b*128+k]*fc3w[k*64+e2];
        r3[t] = frelu(acc);
    }
    __syncthreads();
    if (t < 24) {
        int b = t/6, c = t%6;
        float acc = fc4b[c];
        for (int k = 0; k < 64; ++k) acc += r3[b*64+k]*fc4w[k*6+c];
        out[b*6+c] = acc;
    }
}

extern "C" void kernel_launch(void* const* d_in, const int* in_sizes, int n_in,
                              void* d_out, int out_size, void* d_ws, size_t ws_size,
                              hipStream_t stream)
{
    (void)in_sizes; (void)n_in; (void)out_size;
    const float* xenc = (const float*)d_in[0];
    const float* w1   = (const float*)d_in[4];
    const float* g1   = (const float*)d_in[5];
    const float* b1   = (const float*)d_in[6];
    const float* w2   = (const float*)d_in[7];
    const float* g2   = (const float*)d_in[8];
    const float* b2   = (const float*)d_in[9];
    const float* w3   = (const float*)d_in[10];
    const float* g3   = (const float*)d_in[11];
    const float* b3   = (const float*)d_in[12];
    const float* m2w  = (const float*)d_in[13];
    const float* m2b  = (const float*)d_in[14];
    const float* m2g  = (const float*)d_in[15];
    const float* m2bb = (const float*)d_in[16];
    const float* g1w  = (const float*)d_in[17];
    const float* g1b  = (const float*)d_in[18];
    const float* m1g  = (const float*)d_in[19];
    const float* m1b  = (const float*)d_in[20];
    const float* t1w  = (const float*)d_in[21];
    const float* t1b  = (const float*)d_in[22];
    const float* g2w  = (const float*)d_in[23];
    const float* g2bv = (const float*)d_in[24];
    const float* mm2g = (const float*)d_in[25];
    const float* mm2b = (const float*)d_in[26];
    const float* t2w  = (const float*)d_in[27];
    const float* t2b  = (const float*)d_in[28];
    const float* fc1w = (const float*)d_in[29];
    const float* fc1b = (const float*)d_in[30];
    const float* fc2w = (const float*)d_in[31];
    const float* fc2b = (const float*)d_in[32];
    const float* fc3w = (const float*)d_in[33];
    const float* fc3b = (const float*)d_in[34];
    const float* fc4w = (const float*)d_in[35];
    const float* fc4b = (const float*)d_in[36];

    char* ws = (char*)d_ws;
    float* a2   = (float*)(ws);
    float* X    = (float*)(ws + (2u<<20));
    unsigned short* Hbhi1 = (unsigned short*)(ws + (4u<<20));
    unsigned short* Hblo1 = (unsigned short*)(ws + (5u<<20));
    unsigned short* Hbhi2 = (unsigned short*)(ws);
    unsigned short* Hblo2 = (unsigned short*)(ws + (1u<<20));
    float* S1   = (float*)(ws + (6u<<20));
    unsigned short* aflatG = (unsigned short*)(ws + (6u<<20));
    unsigned short* w2s    = (unsigned short*)(ws + (6u<<20) + 5242880);
    unsigned short* w3s    = (unsigned short*)(ws + (6u<<20) + 5242880 + 131072);
    unsigned short* m2wbT  = (unsigned short*)(ws + (6u<<20) + 5242880 + 196608);
    float* pbuf2 = (float*)(ws + (6u<<20));

    if (ws_size >= ((size_t)49 << 20)) {
        unsigned short* Phi = (unsigned short*)(ws + (38u<<20));   // 2 MB [8192][128]
        unsigned short* Plo = (unsigned short*)(ws + (40u<<20));   // 2 MB
        float* O    = (float*)(ws + (42u<<20));                    // 2 MB (O1|O2)
        float* pbuf = (float*)(ws + (44u<<20));                    // 1 MB
        unsigned short* twThi = (unsigned short*)(ws + (44u<<20) + 131072); // 32 KB
        unsigned short* twTlo = (unsigned short*)(ws + (44u<<20) + 196608); // 32 KB
        unsigned short* XbbThi = (unsigned short*)(ws + (45u<<20));
        unsigned short* XbbTlo = (unsigned short*)(ws + (47u<<20));
        float* O1 = O;
        float* O2 = O + 262144;

        k_prep<<<288, 256, 0, stream>>>(w2, w3, m2w, t1w, t2w, w2s, w3s, m2wbT, twThi, twTlo);
        k_conv<<<4096, 256, 0, stream>>>(xenc, w1,g1,b1, w2s,g2,b2, w3s,g3,b3, aflatG);
        k_map2<<<64, 256, 0, stream>>>(aflatG, m2wbT, m2b, m2g, m2bb, a2);
        k_buildx<<<2048, 256, 0, stream>>>(a2, X);
        k_hmat<<<dim3(2048,2), 256, 0, stream>>>(X, g1w, g1b, g2w, g2bv,
                                                 Hbhi1, Hblo1, Hbhi2, Hblo2);
        k_xbbt<<<dim3(16,4,2), 256, 0, stream>>>(X, m1g, m1b, mm2g, mm2b, XbbThi, XbbTlo);
        k_attn<<<dim3(64,4,2), 256, 0, stream>>>(Hbhi1, Hblo1, Hbhi2, Hblo2, X,
                                                 m1g, m1b, mm2g, mm2b,
                                                 XbbThi, XbbTlo, Phi, Plo);
        k_tprojmm<<<512, 256, 0, stream>>>(Phi, Plo, twThi, twTlo, t1b, t2b, O);
        k_fc1 <<<512, 256, 0, stream>>>(O1, O2, fc1w, pbuf);
        k_red <<<64, 256, 0, stream>>>(pbuf, pbuf2);
        k_head2<<<1, 256, 0, stream>>>(pbuf2, fc1b, fc2w, fc2b, fc3w, fc3b, fc4w, fc4b, (float*)d_out);
    } else {
        // ---- fallback: r8-style f32 MPNN tail (27 MB) ----
        float* P    = (float*)(ws + (22u<<20));
        float* O1   = (float*)(ws + (24u<<20));
        float* O2   = (float*)(ws + (25u<<20));
        float* pbuf = (float*)(ws + (26u<<20));
        float* mrow = (float*)(ws + (26u<<20));
        float* linv = (float*)(ws + (26u<<20) + 65536);
        unsigned short* twThi = (unsigned short*)(ws + (26u<<20) + 131072);
        unsigned short* twTlo = (unsigned short*)(ws + (26u<<20) + 196608);

        k_prep<<<288, 256, 0, stream>>>(w2, w3, m2w, t1w, t2w, w2s, w3s, m2wbT, twThi, twTlo);
        k_conv<<<4096, 256, 0, stream>>>(xenc, w1,g1,b1, w2s,g2,b2, w3s,g3,b3, aflatG);
        k_map2<<<64, 256, 0, stream>>>(aflatG, m2wbT, m2b, m2g, m2bb, a2);
        k_buildx<<<2048, 256, 0, stream>>>(a2, X);
        k_hmat<<<dim3(2048,2), 256, 0, stream>>>(X, g1w, g1b, g2w, g2bv,
                                                 Hbhi1, Hblo1, Hbhi2, Hblo2);
        k_scores <<<dim3(16,16,4), 256, 0, stream>>>(Hbhi1, Hblo1, Hbhi1, Hblo1, S1, S1);
        k_rowstat<<<dim3(1024,4), 256, 0, stream>>>(S1, S1, mrow, linv);
        k_pv     <<<dim3(64,4), 256, 0, stream>>>(S1, X, m1g, m1b, mrow, linv, P);
        k_tproj  <<<1024, 256, 0, stream>>>(P, t1w, t1b, O1);
        k_scores <<<dim3(16,16,4), 256, 0, stream>>>(Hbhi2, Hblo2, Hbhi2, Hblo2, S1, S1);
        k_rowstat<<<dim3(1024,4), 256, 0, stream>>>(S1, S1, mrow, linv);
        k_pv     <<<dim3(64,4), 256, 0, stream>>>(S1, X, mm2g, mm2b, mrow, linv, P);
        k_tproj  <<<1024, 256, 0, stream>>>(P, t2w, t2b, O2);
        k_fc1 <<<512, 256, 0, stream>>>(O1, O2, fc1w, pbuf);
        k_red <<<64, 256, 0, stream>>>(pbuf, pbuf2);
        k_head2<<<1, 256, 0, stream>>>(pbuf2, fc1b, fc2w, fc2b, fc3w, fc3b, fc4w, fc4b, (float*)d_out);
    }
}